// Round 7
// baseline (1576.041 us; speedup 1.0000x reference)
//
#include <hip/hip_runtime.h>
#include <hip/hip_bf16.h>
#include <math.h>

// ---- problem constants ----
#define BATCH  2
#define S_TOK  2046
#define NCOND  2
#define SEQ    2048
#define DMODEL 512
#define DINNER 2048
#define NHEAD  8
#define DHEAD  64
#define NLAYER 6
#define VOCAB  512
#define MROWS  (BATCH*SEQ)   // 4096 rows

typedef unsigned short bf16u;
typedef __attribute__((ext_vector_type(8))) short s8frag;   // 8 bf16 (4 VGPRs)
typedef __attribute__((ext_vector_type(4))) float f4frag;   // 4 fp32 acc

__device__ __forceinline__ float b2f(bf16u u) {
  union { unsigned int i; float f; } v; v.i = ((unsigned int)u) << 16; return v.f;
}
__device__ __forceinline__ bf16u f2b(float f) {
  union { float f; unsigned int i; } v; v.f = f;
  unsigned int x = v.i;
  return (bf16u)((x + 0x7fffu + ((x >> 16) & 1u)) >> 16);
}
__device__ __forceinline__ unsigned int pack2(float a, float b) {
  return (unsigned int)f2b(a) | ((unsigned int)f2b(b) << 16);
}

// async global->LDS, 16B per lane. LDS dest must be wave-uniform base +
// lane*16 (we pass per-lane ptrs that satisfy exactly that).
__device__ __forceinline__ void gld16(const bf16u* g, bf16u* l) {
  __builtin_amdgcn_global_load_lds(
      (const __attribute__((address_space(1))) unsigned int*)g,
      (__attribute__((address_space(3))) unsigned int*)l,
      16, 0, 0);
}

// DPP row-rotate (within 16-lane row) — VALU-pipe lane exchange, not LDS.
#define DPP_ROR(dst, src, N)                                              \
  dst = __int_as_float(__builtin_amdgcn_update_dpp(                       \
      0, __float_as_int(src), 0x120 + (N), 0xF, 0xF, true))

// ---------------------------------------------------------------------------
// All-layer weight transpose + bf16: dst[N][K] = src[K][N]. One launch.
// blocks: 6 layers x 768 (q64|k64|v64|o64|W1 256|W2 256) + 64 (fc) = 4672.
// ---------------------------------------------------------------------------
__global__ __launch_bounds__(256) void wt_all_kernel(
    const float* __restrict__ Wq, const float* __restrict__ Wk,
    const float* __restrict__ Wv, const float* __restrict__ Wo,
    const float* __restrict__ W1, const float* __restrict__ W2,
    const float* __restrict__ fcW,
    bf16u* __restrict__ qkvT, bf16u* __restrict__ oT,
    bf16u* __restrict__ w1T, bf16u* __restrict__ w2T, bf16u* __restrict__ fcT)
{
  int bid = blockIdx.x;
  const float* src; bf16u* dst; int N, K, kt, nt;
  if (bid < 6 * 768) {
    int L = bid / 768, t = bid - L * 768;
    if (t < 256) {
      int mat = t >> 6, tt = t & 63;
      const float* s4[4] = {Wq, Wk, Wv, Wo};
      src = s4[mat] + (size_t)L * DMODEL * DMODEL;
      dst = (mat < 3) ? (qkvT + (size_t)L * 786432 + (size_t)mat * 262144)
                      : (oT + (size_t)L * 262144);
      K = DMODEL; N = DMODEL; kt = tt >> 3; nt = tt & 7;
    } else if (t < 512) {
      int tt = t - 256;
      src = W1 + (size_t)L * DMODEL * DINNER; dst = w1T + (size_t)L * 1048576;
      K = DMODEL; N = DINNER; kt = tt >> 5; nt = tt & 31;
    } else {
      int tt = t - 512;
      src = W2 + (size_t)L * DINNER * DMODEL; dst = w2T + (size_t)L * 1048576;
      K = DINNER; N = DMODEL; kt = tt >> 3; nt = tt & 7;
    }
  } else {
    int tt = bid - 6 * 768;
    src = fcW; dst = fcT;
    K = DMODEL; N = VOCAB; kt = tt >> 3; nt = tt & 7;
  }
  __shared__ bf16u Ls[64][66];
  int tid = threadIdx.x;
  int c = tid & 63, r4 = tid >> 6;
#pragma unroll
  for (int i = 0; i < 16; i++) {
    int r = i * 4 + r4;
    Ls[r][c] = f2b(src[(size_t)(kt * 64 + r) * N + nt * 64 + c]);
  }
  __syncthreads();
#pragma unroll
  for (int i = 0; i < 16; i++) {
    int rr = i * 4 + r4;
    dst[(size_t)(nt * 64 + rr) * K + kt * 64 + c] = Ls[c][rr];
  }
}

// ---------------------------------------------------------------------------
// V transpose (bf16): vb[(b,i)][h*64+d] -> vbt[(b*8+h)*64+d][i]. 512 blocks.
// ---------------------------------------------------------------------------
__global__ __launch_bounds__(256) void vt_kernel(
    const bf16u* __restrict__ vb, bf16u* __restrict__ vbt)
{
  int bid = blockIdx.x;
  int b = bid >> 8, t = bid & 255;
  int it = t >> 3, h = t & 7;
  __shared__ bf16u Ls[64][66];
  int tid = threadIdx.x;
  int c = tid & 63, r4 = tid >> 6;
#pragma unroll
  for (int i = 0; i < 16; i++) {
    int r = i * 4 + r4;
    Ls[r][c] = vb[(size_t)(b * SEQ + it * 64 + r) * DMODEL + h * DHEAD + c];
  }
  __syncthreads();
#pragma unroll
  for (int i = 0; i < 16; i++) {
    int rr = i * 4 + r4;
    vbt[(size_t)((b * 8 + h) * DHEAD + rr) * SEQ + it * 64 + c] = Ls[c][rr];
  }
}

// ---------------------------------------------------------------------------
// MFMA GEMM, RB m-tiles/wave (4 -> 128x128, 2 -> 64x128, 1 -> 32x128).
// Staging via global_load_lds; LINEAR LDS tiles (lane i dest = base+i*16B);
// fragment reads bank-balanced (8 bank-cycles = minimum) in linear layout.
// modes: 0 +bias->bf16 ; 1 +bias+Rb(bf16)->bf16 ; 2 relu(+bias)+chord->bf16 ;
//        3 +bias->fp32 ; 4 fused-QKV routing -> bf16 (3 slices)
// ---------------------------------------------------------------------------
template <int RB>
__global__ __launch_bounds__(256) void mgemm(
    const bf16u* __restrict__ A, const bf16u* __restrict__ Wt,
    const float* __restrict__ b0, const float* __restrict__ b1,
    const float* __restrict__ b2, const bf16u* __restrict__ Rb,
    float* __restrict__ Cf, bf16u* __restrict__ Cb,
    int M, int N, int K, int mode,
    const float* __restrict__ ttc, const float* __restrict__ ttcW,
    const float* __restrict__ ttcb)
{
  __shared__ bf16u Ab[RB * 32][32];
  __shared__ bf16u Bb[128][32];
  const int tid = threadIdx.x;
  const int lane = tid & 63, wave = tid >> 6;
  const int quad = lane >> 4, l16 = lane & 15;
  const int wm = wave >> 1, wn = wave & 1;
  const int row0 = blockIdx.x * (RB * 32), col0 = blockIdx.y * 128;

  f4frag acc[RB][4];
#pragma unroll
  for (int i = 0; i < RB; i++)
#pragma unroll
    for (int j = 0; j < 4; j++) acc[i][j] = (f4frag){0.f, 0.f, 0.f, 0.f};

  for (int k0 = 0; k0 < K; k0 += 32) {
    if (k0) __syncthreads();
    if constexpr (RB >= 2) {
#pragma unroll
      for (int i = 0; i < RB / 2; i++) {
        int chunk = i * 256 + tid;
        int r = chunk >> 2, q = chunk & 3;
        gld16(&A[(size_t)(row0 + r) * K + k0 + q * 8], &Ab[0][0] + chunk * 8);
      }
    } else {
      if (tid < 128) {
        int r = tid >> 2, q = tid & 3;
        gld16(&A[(size_t)(row0 + r) * K + k0 + q * 8], &Ab[0][0] + tid * 8);
      }
    }
#pragma unroll
    for (int i = 0; i < 2; i++) {
      int chunk = i * 256 + tid;
      int r = chunk >> 2, q = chunk & 3;
      gld16(&Wt[(size_t)(col0 + r) * K + k0 + q * 8], &Bb[0][0] + chunk * 8);
    }
    __syncthreads();   // compiler drains vmcnt before s_barrier
    s8frag af[RB], bfr[4];
#pragma unroll
    for (int t = 0; t < RB; t++)
      af[t] = *(const s8frag*)&Ab[wm * (RB * 16) + t * 16 + l16][quad * 8];
#pragma unroll
    for (int t = 0; t < 4; t++)
      bfr[t] = *(const s8frag*)&Bb[wn * 64 + t * 16 + l16][quad * 8];
#pragma unroll
    for (int mt = 0; mt < RB; mt++)
#pragma unroll
      for (int nt = 0; nt < 4; nt++)
        acc[mt][nt] = __builtin_amdgcn_mfma_f32_16x16x32_bf16(
            af[mt], bfr[nt], acc[mt][nt], 0, 0, 0);
  }

#pragma unroll
  for (int mt = 0; mt < RB; mt++) {
#pragma unroll
    for (int r = 0; r < 4; r++) {
      int m = row0 + wm * (RB * 16) + mt * 16 + quad * 4 + r;
      float tval = 0.f;
      if (mode == 2) {
        int bb = m >> 11, s = m & (SEQ - 1);
        int sp = (s < NCOND) ? 0 : (s - NCOND);
        tval = 8.0f - ttc[bb * S_TOK + sp];
      }
#pragma unroll
      for (int nt = 0; nt < 4; nt++) {
        int n = col0 + wn * 64 + nt * 16 + l16;
        if (mode == 4) {
          int sel = n >> 9, nn = n & 511;
          float bv = (sel == 0) ? b0[nn] : ((sel == 1) ? b1[nn] : b2[nn]);
          Cb[(size_t)sel * MROWS * DMODEL + (size_t)m * DMODEL + nn]
              = f2b(acc[mt][nt][r] + bv);
        } else {
          float v = acc[mt][nt][r] + b0[n];
          if (mode == 1)      v += b2f(Rb[(size_t)m * N + n]);
          else if (mode == 2) v = fmaxf(v, 0.f) + tval * ttcW[n] + ttcb[n];
          if (mode == 3) Cf[(size_t)m * N + n] = v;
          else           Cb[(size_t)m * N + n] = f2b(v);
        }
      }
    }
  }
}

// ---------------------------------------------------------------------------
// Fused GEMM(M x 512) + bias + residual + LayerNorm -> bf16.
// Block: 16 rows x ALL 512 cols (so LN has the full row). Grid 256, 4 waves;
// wave w owns cols [w*128, w*128+128). Two-pass LN (exact ln_kernel math):
// DPP 16-lane reduce -> redS/redQ[16][4] in LDS -> mu, then var, eps 1e-6.
// ---------------------------------------------------------------------------
__global__ __launch_bounds__(256) void mgemm_ln(
    const bf16u* __restrict__ A, const bf16u* __restrict__ Wt,
    const float* __restrict__ b0, const bf16u* __restrict__ Rb,
    const float* __restrict__ g, const float* __restrict__ bt,
    bf16u* __restrict__ Y, int K)
{
  __shared__ bf16u Ab[16][32];     // 1KB
  __shared__ bf16u Bb[512][32];    // 32KB
  __shared__ float redS[16][4];
  __shared__ float redQ[16][4];
  const int tid = threadIdx.x;
  const int lane = tid & 63, wave = tid >> 6;
  const int quad = lane >> 4, l16 = lane & 15;
  const int row0 = blockIdx.x * 16;

  f4frag acc[8];
#pragma unroll
  for (int nt = 0; nt < 8; nt++) acc[nt] = (f4frag){0.f, 0.f, 0.f, 0.f};

  for (int k0 = 0; k0 < K; k0 += 32) {
    if (k0) __syncthreads();
    // A tile: 16x32 = 64 chunks of 16B (wave 0 only; dest = lane*16B, linear)
    if (tid < 64)
      gld16(&A[(size_t)(row0 + (tid >> 2)) * K + k0 + (tid & 3) * 8],
            &Ab[0][0] + tid * 8);
    // B tile: 512x32 = 2048 chunks
#pragma unroll
    for (int i = 0; i < 8; i++) {
      int chunk = i * 256 + tid;
      gld16(&Wt[(size_t)(chunk >> 2) * K + k0 + (chunk & 3) * 8],
            &Bb[0][0] + chunk * 8);
    }
    __syncthreads();
    s8frag af = *(const s8frag*)&Ab[l16][quad * 8];
#pragma unroll
    for (int nt = 0; nt < 8; nt++) {
      s8frag bf = *(const s8frag*)&Bb[wave * 128 + nt * 16 + l16][quad * 8];
      acc[nt] = __builtin_amdgcn_mfma_f32_16x16x32_bf16(af, bf, acc[nt], 0, 0, 0);
    }
  }

  // epilogue: v = acc + bias + residual; two-pass LN over 512 cols
  float val[8][4], mu[4], rstd[4];
  {
    float sr[4] = {0.f, 0.f, 0.f, 0.f};
#pragma unroll
    for (int nt = 0; nt < 8; nt++) {
      int n = wave * 128 + nt * 16 + l16;
      float bb = b0[n];
#pragma unroll
      for (int r = 0; r < 4; r++) {
        int m = row0 + quad * 4 + r;
        float v = acc[nt][r] + bb + b2f(Rb[(size_t)m * DMODEL + n]);
        val[nt][r] = v;
        sr[r] += v;
      }
    }
#pragma unroll
    for (int r = 0; r < 4; r++) {
      float tr;
      DPP_ROR(tr, sr[r], 1); sr[r] += tr;
      DPP_ROR(tr, sr[r], 2); sr[r] += tr;
      DPP_ROR(tr, sr[r], 4); sr[r] += tr;
      DPP_ROR(tr, sr[r], 8); sr[r] += tr;
      if (l16 == 0) redS[quad * 4 + r][wave] = sr[r];
    }
    __syncthreads();
#pragma unroll
    for (int r = 0; r < 4; r++) {
      int row = quad * 4 + r;
      mu[r] = (redS[row][0] + redS[row][1] + redS[row][2] + redS[row][3])
              * (1.0f / DMODEL);
    }
    float qr[4] = {0.f, 0.f, 0.f, 0.f};
#pragma unroll
    for (int nt = 0; nt < 8; nt++)
#pragma unroll
      for (int r = 0; r < 4; r++) {
        float d = val[nt][r] - mu[r];
        qr[r] += d * d;
      }
#pragma unroll
    for (int r = 0; r < 4; r++) {
      float tr;
      DPP_ROR(tr, qr[r], 1); qr[r] += tr;
      DPP_ROR(tr, qr[r], 2); qr[r] += tr;
      DPP_ROR(tr, qr[r], 4); qr[r] += tr;
      DPP_ROR(tr, qr[r], 8); qr[r] += tr;
      if (l16 == 0) redQ[quad * 4 + r][wave] = qr[r];
    }
    __syncthreads();
#pragma unroll
    for (int r = 0; r < 4; r++) {
      int row = quad * 4 + r;
      float var = (redQ[row][0] + redQ[row][1] + redQ[row][2] + redQ[row][3])
                  * (1.0f / DMODEL);
      rstd[r] = rsqrtf(var + 1e-6f);
    }
  }
#pragma unroll
  for (int nt = 0; nt < 8; nt++) {
    int n = wave * 128 + nt * 16 + l16;
    float gg = g[n], bb = bt[n];
#pragma unroll
    for (int r = 0; r < 4; r++) {
      int m = row0 + quad * 4 + r;
      Y[(size_t)m * DMODEL + n] = f2b((val[nt][r] - mu[r]) * rstd[r] * gg + bb);
    }
  }
}

// ---------------------------------------------------------------------------
__global__ __launch_bounds__(256) void tok_embed_kernel(
    const int* __restrict__ toks, const float* __restrict__ emb,
    const float* __restrict__ pos, bf16u* __restrict__ xb)
{
  int sp = blockIdx.x, b = blockIdx.y;
  int s = sp + NCOND;
  int tok = toks[b * S_TOK + sp];
  const float* er = emb + (size_t)tok * DMODEL;
  const float* pr = pos + (size_t)s * DMODEL;
  size_t ro = ((size_t)b * SEQ + s) * DMODEL;
  int d = threadIdx.x * 2;
  float v0 = er[d]     * 22.62741699796952f + pr[d];
  float v1 = er[d + 1] * 22.62741699796952f + pr[d + 1];
  *(unsigned int*)&xb[ro + d] = pack2(v0, v1);
}

// ---------------------------------------------------------------------------
__global__ __launch_bounds__(256) void cond_embed_kernel(
    const float* __restrict__ conds, const float* __restrict__ W1,
    const float* __restrict__ b1, const float* __restrict__ W2w,
    const float* __restrict__ b2, const float* __restrict__ nullc,
    const float* __restrict__ pos, bf16u* __restrict__ xb)
{
  int ci = blockIdx.x, b = blockIdx.y, tid = threadIdx.x;
  float c = conds[b * NCOND + ci];
  bool cn = isnan(c);
  float cm = cn ? 0.f : c;
  __shared__ float h1[DMODEL / 2];
  h1[tid] = fmaxf(cm * W1[ci * (DMODEL/2) + tid] + b1[ci * (DMODEL/2) + tid], 0.f);
  __syncthreads();
  for (int d = tid; d < DMODEL; d += 256) {
    float acc = b2[ci * DMODEL + d];
    for (int i = 0; i < DMODEL / 2; i++)
      acc = fmaf(h1[i], W2w[((size_t)ci * (DMODEL/2) + i) * DMODEL + d], acc);
    float ce = cn ? nullc[ci * DMODEL + d] : acc;
    xb[((size_t)b * SEQ + ci) * DMODEL + d] = f2b(ce + pos[(size_t)ci * DMODEL + d]);
  }
}

// ---------------------------------------------------------------------------
// E (fp32, all 6 layers) -> bf16.
// ---------------------------------------------------------------------------
__global__ __launch_bounds__(256) void e_conv_kernel(
    const float* __restrict__ E, bf16u* __restrict__ Eb)
{
  int i = (blockIdx.x * 256 + threadIdx.x) * 4;
  float4 v = *(const float4*)&E[i];
  ushort4 o;
  o.x = f2b(v.x); o.y = f2b(v.y); o.z = f2b(v.z); o.w = f2b(v.w);
  *(ushort4*)&Eb[i] = o;
}

// ---------------------------------------------------------------------------
// Split-K MFMA flash attention (v4 structure, measured ~84us; left alone).
// ---------------------------------------------------------------------------
#define PS_SWZ(row) ((((row) >> 2) & 7) << 3)

__global__ __launch_bounds__(256) void attn_part(
    const bf16u* __restrict__ Q, const bf16u* __restrict__ K,
    const bf16u* __restrict__ Vt_g, const bf16u* __restrict__ Eb16,
    const int* __restrict__ toks, bf16u* __restrict__ pacc,
    float* __restrict__ pstat)
{
  const int bid = blockIdx.x;
  const int g  = bid >> 7;              // (b,h)
  const int it = 31 - ((bid >> 2) & 31);// q-tile, heavy-first (LPT)
  const int c  = bid & 3;               // key chunk
  if (8 * c > it) return;
  const int slot = (g << 7) | (it << 2) | c;   // logical index for partials
  const int b = g >> 3, h = g & 7;
  const int i0 = it * 64;

  __shared__ bf16u Kb[64][72];          // K tile; becomes P after mid barrier
  __shared__ bf16u Vt[64][72];
  __shared__ bf16u Ebs[128][72];
  __shared__ float padv[64];
  bf16u (*Ps)[72] = Kb;                 // alias: disjoint lifetimes per step

  const int tid  = threadIdx.x;
  const int lane = tid & 63;
  const int wave = tid >> 6;
  const int quad = lane >> 4;
  const int l16  = lane & 15;

  const bf16u* qr = Q + ((size_t)(b * SEQ + i0 + wave * 16 + l16)) * DMODEL + h * DHEAD;
  s8frag q0 = *(const s8frag*)&qr[quad * 8];
  s8frag q1 = *(const s8frag*)&qr[32 + quad * 8];

  float m_run[4], l_run[4];
  f4frag acc[4];
#pragma unroll
  for (int r = 0; r < 4; r++) { m_run[r] = -1e30f; l_run[r] = 0.f; }
#pragma unroll
  for (int dt = 0; dt < 4; dt++) acc[dt] = (f4frag){0.f, 0.f, 0.f, 0.f};

  const int js0 = 8 * c;
  const int jsE = min(8 * c + 8, it + 1);
  const size_t vtbase = (size_t)(g * DHEAD) * SEQ;

  for (int js = js0; js < jsE; js++) {
    const int j0 = js * 64;
    const int m0 = 1984 - i0 + j0;   // E row of band col 0
    __syncthreads();

    // K tile (2 x uint4 / thread)
#pragma unroll
    for (int e = 0; e < 2; e++) {
      int cc = e * 256 + tid;
      int jr = cc >> 3, doff = (cc & 7) * 8;
      *(uint4*)&Kb[jr][doff] =
          *(const uint4*)&K[((size_t)(b * SEQ + j0 + jr)) * DMODEL + h * DHEAD + doff];
    }
    // V^T tile from pre-transposed global (2 x uint4 / thread)
#pragma unroll
    for (int e = 0; e < 2; e++) {
      int cc = e * 256 + tid;
      int dr = cc >> 3, joff = (cc & 7) * 8;
      *(uint4*)&Vt[dr][joff] =
          *(const uint4*)&Vt_g[vtbase + (size_t)dr * SEQ + j0 + joff];
    }
    // E ring: first step fill 128 rows, then 64 new rows
    if (js == js0) {
#pragma unroll
      for (int e = 0; e < 4; e++) {
        int cc = e * 256 + tid;
        int er = cc >> 3, doff = (cc & 7) * 8;
        int m = m0 + er; int row = m > SEQ - 1 ? SEQ - 1 : m;
        *(uint4*)&Ebs[m & 127][doff] = *(const uint4*)&Eb16[(size_t)row * DHEAD + doff];
      }
    } else {
#pragma unroll
      for (int e = 0; e < 2; e++) {
        int cc = e * 256 + tid;
        int er = 64 + (cc >> 3), doff = (cc & 7) * 8;
        int m = m0 + er; int row = m > SEQ - 1 ? SEQ - 1 : m;
        *(uint4*)&Ebs[m & 127][doff] = *(const uint4*)&Eb16[(size_t)row * DHEAD + doff];
      }
    }
    if (tid < 64) {
      int j = j0 + tid;
      bool pad = (j >= NCOND) && (toks[b * S_TOK + j - NCOND] == 0);
      padv[tid] = pad ? -1e30f : 0.f;
    }
    __syncthreads();

    // QK^T (reads Kb)
    f4frag sc[4];
#pragma unroll
    for (int nt = 0; nt < 4; nt++) {
      s8frag k0 = *(const s8frag*)&Kb[nt * 16 + l16][quad * 8];
      s8frag k1 = *(const s8frag*)&Kb[nt * 16 + l16][32 + quad * 8];
      f4frag cc = (f4frag){0.f, 0.f, 0.f, 0.f};
      cc = __builtin_amdgcn_mfma_f32_16x16x32_bf16(q0, k0, cc, 0, 0, 0);
      cc = __builtin_amdgcn_mfma_f32_16x16x32_bf16(q1, k1, cc, 0, 0, 0);
      sc[nt] = cc;
    }

    // QE: 5 frags covering band cols [(3-wave)*16, (8-wave)*16)  (reads Ebs)
    f4frag qef[5];
#pragma unroll
    for (int f = 0; f < 5; f++) {
      int ct = f + 3 - wave;
      int m = m0 + ct * 16 + l16;
      const bf16u* erow = &Ebs[m & 127][0];
      s8frag e0 = *(const s8frag*)&erow[quad * 8];
      s8frag e1 = *(const s8frag*)&erow[32 + quad * 8];
      f4frag cc = (f4frag){0.f, 0.f, 0.f, 0.f};
      cc = __builtin_amdgcn_mfma_f32_16x16x32_bf16(q0, e0, cc, 0, 0, 0);
      cc = __builtin_amdgcn_mfma_f32_16x16x32_bf16(q1, e1, cc, 0, 0, 0);
      qef[f] = cc;
    }

    // All Kb/Ebs reads are drained by this barrier; Kb becomes the P buffer.
    __syncthreads();

    float pvv[4];
#pragma unroll
    for (int nt = 0; nt < 4; nt++) pvv[nt] = padv[nt * 16 + l16];

    // scores + online softmax; QE gathered by ONE shuffle (select at source).
    float s[4][4], mx[4];
#pragma unroll
    for (int r = 0; r < 4; r++) {
      int rloc = wave * 16 + quad * 4 + r;
      int ig = i0 + rloc;
      int t = quad * 4 + r;
      int v = 63 - 16 * wave + l16 - t;
      int srcl = (lane & 48) | (v & 15);
      bool hiSrc = (l16 < 15 - t);     // target hi <=> this at source lane
#pragma unroll
      for (int nt = 0; nt < 4; nt++) {
        float pre = hiSrc ? qef[nt + 1][r] : qef[nt][r];
        float qe = __shfl(pre, srcl);
        int jl = nt * 16 + l16;
        float sv = (sc[nt][r] + qe) * 0.125f + pvv[nt];
        if (j0 + jl > ig) sv = -1e30f;
        s[nt][r] = sv;
      }
      float m = fmaxf(fmaxf(s[0][r], s[1][r]), fmaxf(s[2][r], s[3][r]));
      float tr;
      DPP_ROR(tr, m, 1); m = fmaxf(m, tr);
      DPP_ROR(tr, m, 2); m = fmaxf(m, tr);
      DPP_ROR(tr, m, 4); m = fmaxf(m, tr);
      DPP_ROR(tr, m, 8); m = fmaxf(m, tr);
      mx[r] = m;
    }
    float alpha[4];
#pragma unroll
    for (int r = 0; r < 4; r++) {
      float m_new = fmaxf(m_run[r], mx[r]);
      alpha[r] = __expf(m_run[r] - m_new);
      float psum = 0.f;
      int rloc = wave * 16 + quad * 4 + r;
#pragma unroll
      for (int nt = 0; nt < 4; nt++) {
        float p = __expf(s[nt][r] - m_new);
        Ps[rloc][(nt * 16 + l16) ^ PS_SWZ(rloc)] = f2b(p);
        psum += p;
      }
      float tr;
      DPP_ROR(tr, psum, 1); psum += tr;
      DPP_ROR(tr, psum, 2); psum += tr;
      DPP_ROR(tr, psum, 4); psum += tr;
      DPP_ROR(tr, psum, 8); psum += tr;
      l_run[r] = l_run[r] * alpha[r] + psum;
      m_run[r] = m_new;
    }
#pragma unroll
    for (int dt = 0; dt < 4; dt++)
#pragma unroll
      for (int r = 0; r < 4; r++) acc[dt][r] *= alpha[r];

    // P @ V  (Ps rows are wave-local; swizzled reads match swizzled writes)
    {
      int prow = wave * 16 + l16;
      int psw = PS_SWZ(prow);
      s8frag p0 = *(const s8frag*)&Ps[prow][(quad * 8) ^ psw];
      s8frag p1 = *(const s8frag*)&Ps[prow][(32 + quad * 8) ^ psw];
#pragma unroll
      for (int dt = 0; dt < 4; dt++) {
        s8frag v0 = *(const s8frag*)&Vt[dt * 16 + l16][quad * 8];
        s8frag v1 = *(const s8frag*)&Vt[dt * 16 + l16][32 + quad * 8];
        acc[dt] = __builtin_amdgcn_mfma_f32_16x16x32_bf16(p0, v0, acc[dt], 0, 0, 0);
        acc[dt] = __builtin_amdgcn_mfma_f32_16x16x32_bf16(p1, v1, acc[dt], 0, 0, 0);
      }
    }
  }

  // write partials (indexed by logical slot, not blockIdx)
#pragma unroll
  for (int r = 0; r < 4; r++) {
    int rloc = wave * 16 + quad * 4 + r;
    if (l16 == 0) {
      pstat[(size_t)slot * 128 + rloc]      = m_run[r];
      pstat[(size_t)slot * 128 + 64 + rloc] = l_run[r];
    }
#pragma unroll
    for (int dt = 0; dt < 4; dt++)
      pacc[(size_t)slot * 4096 + rloc * 64 + dt * 16 + l16] = f2b(acc[dt][r]);
  }
}

// ---------------------------------------------------------------------------
// Merge <=4 chunk partials per (b,h,q-tile); write O (bf16) into qb.
// ---------------------------------------------------------------------------
__global__ __launch_bounds__(256) void attn_combine(
    const bf16u* __restrict__ pacc, const float* __restrict__ pstat,
    bf16u* __restrict__ O)
{
  int bid = blockIdx.x;             // g*32 + it
  int g = bid >> 5, it = bid & 31;
  int b = g >> 3, h = g & 7;
  int i0 = it * 64;
  int nc = (it >> 3) + 1;
  int tid = threadIdx.x;
  int row = tid >> 2, ql = tid & 3;

  float m_tot = -1e30f;
  float mc[4], lc[4];
#pragma unroll
  for (int c = 0; c < 4; c++) {
    if (c < nc) {
      size_t pb = (size_t)(bid * 4 + c) * 128;
      mc[c] = pstat[pb + row];
      lc[c] = pstat[pb + 64 + row];
      m_tot = fmaxf(m_tot, mc[c]);
    }
  }
  float l_tot = 0.f, w[4];
#pragma unroll
  for (int c = 0; c < 4; c++) {
    if (c < nc) { w[c] = __expf(mc[c] - m_tot); l_tot += w[c] * lc[c]; }
    else w[c] = 0.f;
  }
  float inv = 1.0f / l_tot;

  float out[16];
#pragma unroll
  for (int k = 0; k < 16; k++) out[k] = 0.f;
#pragma unroll
  for (int c = 0; c < 4; c++) {
    if (c >= nc) break;
    const bf16u* pa = pacc + (size_t)(bid * 4 + c) * 4096 + row * 64 + ql * 16;
#pragma unroll
    for (int k = 0; k < 16; k++) out[k] += w[c] * b2f(pa[k]);
  }
  bf16u* ob = O + ((size_t)(b * SEQ + i0 + row)) * DMODEL + h * DHEAD + ql * 16;
#pragma unroll
  for (int k = 0; k < 16; k++) ob[k] = f2b(out[k] * inv);
}

// ---------------------------------------------------------------------------
extern "C" void kernel_launch(void* const* d_in, const int* in_sizes, int n_in,
                              void* d_out, int out_size, void* d_ws, size_t ws_size,
                              hipStream_t stream) {
  const int*   toks  = (const int*)  d_in[0];
  const float* conds = (const float*)d_in[1];
  const float* ttc   = (const float*)d_in[2];
  const float* emb   = (const float*)d_in[3];
  const float* pos   = (const float*)d_in[4];
  const float* cW1   = (const float*)d_in[5];
  const float* cb1   = (const float*)d_in[6];
  const float* cW2   = (const float*)d_in[7];
  const float* cb2   = (const float*)d_in[8];
  const float* nullc = (const float*)d_in[9];
  const float* ttcW  = (const float*)d_in[10];
  const float* ttcb  = (const float*)d_in[11];
  const float* Wq    = (const float*)d_in[12];
  const float* Wk    = (const float*)d_in[13];
  const float* Wv    = (const float*)d_in[14];
  const float* Wo    = (const float*)d_in[15];
  const float* bq    = (const float*)d_in[16];
  const float* bk    = (const float*)d_in[17];
  const float* bv    = (const float*)d_in[18];
  const float* bo    = (const float*)d_in[19];
  const float* E     = (const float*)d_in[20];
  const float* fW1   = (const float*)d_in[21];
  const float* fb1   = (const float*)d_in[22];
  const float* fW2   = (const float*)d_in[23];
  const float* fb2   = (const float*)d_in[24];
  const float* ln1g  = (const float*)d_in[25];
  const float* ln1b  = (const float*)d_in[26];
  const float* ln2g  = (const float*)d_in[27];
  const float* ln2b  = (const float*)d_in[28];
  const float* fcW   = (const float*)d_in[29];
  const float* fcb   = (const float*)d_in[30];

  const size_t MB1 = 1024 * 1024;
  const size_t MD = (size_t)MROWS * DMODEL;
  char* p = (char*)d_ws;
  bf16u* xb    = (bf16u*)p; p += 4 * MB1;
  bf16u* qkvb  = (bf16u*)p; p += 12 * MB1;   // qb | kb | vb
  bf16u* hidb  = (bf16u*)p; p += 16 * MB1;   // FFN hidden / pacc alias
  float* pstat = (float*)p; p += 1 * MB1;
  bf16u* vbt   = (bf16u*)p; p += 4 * MB1;    // V transposed
  bf16u* ebf   = (bf16u*)p; p += 1536 * 1024;   // E bf16, 6 layers
  bf16u* WqkvT = (bf16u*)p; p += 9 * MB1;
  bf16u* WoT   = (bf16u*)p; p += 3 * MB1;
  bf16u* W1T   = (bf16u*)p; p += 12 * MB1;
  bf16u* W2T   = (bf16u*)p; p += 12 * MB1;
  bf16u* fcT   = (bf16u*)p; p += 512 * 1024;    // total 75 MB
  bf16u* qb = qkvb;
  bf16u* kb = qkvb + MD;        // out1b aliases kb (disjoint lifetimes)
  bf16u* vb = qkvb + 2 * MD;
  bf16u* out1b = kb;
  bf16u* pacc  = hidb;

  // ---- setup: embeds + all-layer weight transposes + E conversion ----
  cond_embed_kernel<<<dim3(NCOND, BATCH), 256, 0, stream>>>(
      conds, cW1, cb1, cW2, cb2, nullc, pos, xb);
  tok_embed_kernel<<<dim3(S_TOK, BATCH), 256, 0, stream>>>(toks, emb, pos, xb);
  wt_all_kernel<<<6 * 768 + 64, 256, 0, stream>>>(Wq, Wk, Wv, Wo, fW1, fW2, fcW,
      WqkvT, WoT, W1T, W2T, fcT);
  e_conv_kernel<<<(NLAYER * SEQ * DHEAD) / 1024, 256, 0, stream>>>(E, ebf);

  dim3 gQKV(MROWS / 128, 1536 / 128);      // (32,12)
  dim3 gFF1(MROWS / 128, DINNER / 128);    // (32,16)
  dim3 gN512(MROWS / 32, DMODEL / 128);    // (128,4): fc only

  for (int l = 0; l < NLAYER; l++) {
    // fused QKV
    mgemm<4><<<gQKV, 256, 0, stream>>>(xb, WqkvT + (size_t)l * 786432,
        bq + l * DMODEL, bk + l * DMODEL, bv + l * DMODEL, nullptr,
        nullptr, qkvb, MROWS, 1536, DMODEL, 4, nullptr, nullptr, nullptr);

    vt_kernel<<<512, 256, 0, stream>>>(vb, vbt);
    attn_part<<<2048, 256, 0, stream>>>(qb, kb, vbt,
        ebf + (size_t)l * SEQ * DHEAD, toks, pacc, pstat);
    attn_combine<<<512, 256, 0, stream>>>(pacc, pstat, qb);

    // out1 = LN1(attn @ Wo + bo + x)   [fused GEMM+residual+LN]
    mgemm_ln<<<MROWS / 16, 256, 0, stream>>>(qb, WoT + (size_t)l * 262144,
        bo + l * DMODEL, xb, ln1g + l * DMODEL, ln1b + l * DMODEL,
        out1b, DMODEL);

    // hid = relu(out1 @ W1 + b1) + chord
    mgemm<4><<<gFF1, 256, 0, stream>>>(out1b, W1T + (size_t)l * 1048576,
        fb1 + l * DINNER, nullptr, nullptr, nullptr,
        nullptr, hidb, MROWS, DINNER, DMODEL, 2, ttc, ttcW, ttcb);

    // x = LN2(hid @ W2 + b2 + out1)   [fused GEMM+residual+LN]
    mgemm_ln<<<MROWS / 16, 256, 0, stream>>>(hidb, W2T + (size_t)l * 1048576,
        fb2 + l * DMODEL, out1b, ln2g + l * DMODEL, ln2b + l * DMODEL,
        xb, DINNER);
  }

  // logits = x @ fc_W + fc_b (fp32 out)
  mgemm<1><<<gN512, 256, 0, stream>>>(xb, fcT,
      fcb, nullptr, nullptr, nullptr,
      (float*)d_out, nullptr, MROWS, VOCAB, DMODEL, 3, nullptr, nullptr, nullptr);
}

// Round 8
// 1386.345 us; speedup vs baseline: 1.1368x; 1.1368x over previous
//
#include <hip/hip_runtime.h>
#include <hip/hip_bf16.h>
#include <math.h>

// ---- problem constants ----
#define BATCH  2
#define S_TOK  2046
#define NCOND  2
#define SEQ    2048
#define DMODEL 512
#define DINNER 2048
#define NHEAD  8
#define DHEAD  64
#define NLAYER 6
#define VOCAB  512
#define MROWS  (BATCH*SEQ)   // 4096 rows

typedef unsigned short bf16u;
typedef __attribute__((ext_vector_type(8))) short s8frag;   // 8 bf16 (4 VGPRs)
typedef __attribute__((ext_vector_type(4))) float f4frag;   // 4 fp32 acc

__device__ __forceinline__ float b2f(bf16u u) {
  union { unsigned int i; float f; } v; v.i = ((unsigned int)u) << 16; return v.f;
}
__device__ __forceinline__ bf16u f2b(float f) {
  union { float f; unsigned int i; } v; v.f = f;
  unsigned int x = v.i;
  return (bf16u)((x + 0x7fffu + ((x >> 16) & 1u)) >> 16);
}
__device__ __forceinline__ unsigned int pack2(float a, float b) {
  return (unsigned int)f2b(a) | ((unsigned int)f2b(b) << 16);
}

// async global->LDS, 16B per lane. LDS dest must be wave-uniform base +
// lane*16 (we pass per-lane ptrs that satisfy exactly that).
__device__ __forceinline__ void gld16(const bf16u* g, bf16u* l) {
  __builtin_amdgcn_global_load_lds(
      (const __attribute__((address_space(1))) unsigned int*)g,
      (__attribute__((address_space(3))) unsigned int*)l,
      16, 0, 0);
}

// DPP row-rotate (within 16-lane row) — VALU-pipe lane exchange, not LDS.
#define DPP_ROR(dst, src, N)                                              \
  dst = __int_as_float(__builtin_amdgcn_update_dpp(                       \
      0, __float_as_int(src), 0x120 + (N), 0xF, 0xF, true))

// ---------------------------------------------------------------------------
// All-layer weight transpose + bf16: dst[N][K] = src[K][N]. One launch.
// blocks: 6 layers x 768 (q64|k64|v64|o64|W1 256|W2 256) + 64 (fc) = 4672.
// ---------------------------------------------------------------------------
__global__ __launch_bounds__(256) void wt_all_kernel(
    const float* __restrict__ Wq, const float* __restrict__ Wk,
    const float* __restrict__ Wv, const float* __restrict__ Wo,
    const float* __restrict__ W1, const float* __restrict__ W2,
    const float* __restrict__ fcW,
    bf16u* __restrict__ qkvT, bf16u* __restrict__ oT,
    bf16u* __restrict__ w1T, bf16u* __restrict__ w2T, bf16u* __restrict__ fcT)
{
  int bid = blockIdx.x;
  const float* src; bf16u* dst; int N, K, kt, nt;
  if (bid < 6 * 768) {
    int L = bid / 768, t = bid - L * 768;
    if (t < 256) {
      int mat = t >> 6, tt = t & 63;
      const float* s4[4] = {Wq, Wk, Wv, Wo};
      src = s4[mat] + (size_t)L * DMODEL * DMODEL;
      dst = (mat < 3) ? (qkvT + (size_t)L * 786432 + (size_t)mat * 262144)
                      : (oT + (size_t)L * 262144);
      K = DMODEL; N = DMODEL; kt = tt >> 3; nt = tt & 7;
    } else if (t < 512) {
      int tt = t - 256;
      src = W1 + (size_t)L * DMODEL * DINNER; dst = w1T + (size_t)L * 1048576;
      K = DMODEL; N = DINNER; kt = tt >> 5; nt = tt & 31;
    } else {
      int tt = t - 512;
      src = W2 + (size_t)L * DINNER * DMODEL; dst = w2T + (size_t)L * 1048576;
      K = DINNER; N = DMODEL; kt = tt >> 3; nt = tt & 7;
    }
  } else {
    int tt = bid - 6 * 768;
    src = fcW; dst = fcT;
    K = DMODEL; N = VOCAB; kt = tt >> 3; nt = tt & 7;
  }
  __shared__ bf16u Ls[64][66];
  int tid = threadIdx.x;
  int c = tid & 63, r4 = tid >> 6;
#pragma unroll
  for (int i = 0; i < 16; i++) {
    int r = i * 4 + r4;
    Ls[r][c] = f2b(src[(size_t)(kt * 64 + r) * N + nt * 64 + c]);
  }
  __syncthreads();
#pragma unroll
  for (int i = 0; i < 16; i++) {
    int rr = i * 4 + r4;
    dst[(size_t)(nt * 64 + rr) * K + kt * 64 + c] = Ls[c][rr];
  }
}

// ---------------------------------------------------------------------------
// V transpose (bf16): vb[(b,i)][h*64+d] -> vbt[(b*8+h)*64+d][i]. 512 blocks.
// ---------------------------------------------------------------------------
__global__ __launch_bounds__(256) void vt_kernel(
    const bf16u* __restrict__ vb, bf16u* __restrict__ vbt)
{
  int bid = blockIdx.x;
  int b = bid >> 8, t = bid & 255;
  int it = t >> 3, h = t & 7;
  __shared__ bf16u Ls[64][66];
  int tid = threadIdx.x;
  int c = tid & 63, r4 = tid >> 6;
#pragma unroll
  for (int i = 0; i < 16; i++) {
    int r = i * 4 + r4;
    Ls[r][c] = vb[(size_t)(b * SEQ + it * 64 + r) * DMODEL + h * DHEAD + c];
  }
  __syncthreads();
#pragma unroll
  for (int i = 0; i < 16; i++) {
    int rr = i * 4 + r4;
    vbt[(size_t)((b * 8 + h) * DHEAD + rr) * SEQ + it * 64 + c] = Ls[c][rr];
  }
}

// ---------------------------------------------------------------------------
// MFMA GEMM, RB m-tiles/wave (4 -> 128x128, 2 -> 64x128, 1 -> 32x128).
// Staging via global_load_lds; LINEAR LDS tiles (lane i dest = base+i*16B);
// fragment reads bank-balanced (8 bank-cycles = minimum) in linear layout.
// XCD-aware tile swizzle (T1): chunked bijective remap of the linearized
// block id so each XCD's L2 sees a contiguous x-major span of tiles
// (fewer distinct B panels per XCD). Grids must be multiples of 8 (all are).
// modes: 0 +bias->bf16 ; 1 +bias+Rb(bf16)->bf16 ; 2 relu(+bias)+chord->bf16 ;
//        3 +bias->fp32 ; 4 fused-QKV routing -> bf16 (3 slices)
// ---------------------------------------------------------------------------
template <int RB>
__global__ __launch_bounds__(256) void mgemm(
    const bf16u* __restrict__ A, const bf16u* __restrict__ Wt,
    const float* __restrict__ b0, const float* __restrict__ b1,
    const float* __restrict__ b2, const bf16u* __restrict__ Rb,
    float* __restrict__ Cf, bf16u* __restrict__ Cb,
    int M, int N, int K, int mode,
    const float* __restrict__ ttc, const float* __restrict__ ttcW,
    const float* __restrict__ ttcb)
{
  __shared__ bf16u Ab[RB * 32][32];
  __shared__ bf16u Bb[128][32];
  const int tid = threadIdx.x;
  const int lane = tid & 63, wave = tid >> 6;
  const int quad = lane >> 4, l16 = lane & 15;
  const int wm = wave >> 1, wn = wave & 1;

  // XCD-chunked swizzle (bijective; nwg % 8 == 0 for all launches)
  const int nwg = gridDim.x * gridDim.y;
  const int lin = blockIdx.y * gridDim.x + blockIdx.x;
  const int swz = (lin & 7) * (nwg >> 3) + (lin >> 3);
  const int bx = swz % gridDim.x, by = swz / gridDim.x;
  const int row0 = bx * (RB * 32), col0 = by * 128;

  f4frag acc[RB][4];
#pragma unroll
  for (int i = 0; i < RB; i++)
#pragma unroll
    for (int j = 0; j < 4; j++) acc[i][j] = (f4frag){0.f, 0.f, 0.f, 0.f};

  for (int k0 = 0; k0 < K; k0 += 32) {
    if (k0) __syncthreads();
    if constexpr (RB >= 2) {
#pragma unroll
      for (int i = 0; i < RB / 2; i++) {
        int chunk = i * 256 + tid;
        int r = chunk >> 2, q = chunk & 3;
        gld16(&A[(size_t)(row0 + r) * K + k0 + q * 8], &Ab[0][0] + chunk * 8);
      }
    } else {
      if (tid < 128) {
        int r = tid >> 2, q = tid & 3;
        gld16(&A[(size_t)(row0 + r) * K + k0 + q * 8], &Ab[0][0] + tid * 8);
      }
    }
#pragma unroll
    for (int i = 0; i < 2; i++) {
      int chunk = i * 256 + tid;
      int r = chunk >> 2, q = chunk & 3;
      gld16(&Wt[(size_t)(col0 + r) * K + k0 + q * 8], &Bb[0][0] + chunk * 8);
    }
    __syncthreads();   // compiler drains vmcnt before s_barrier
    s8frag af[RB], bfr[4];
#pragma unroll
    for (int t = 0; t < RB; t++)
      af[t] = *(const s8frag*)&Ab[wm * (RB * 16) + t * 16 + l16][quad * 8];
#pragma unroll
    for (int t = 0; t < 4; t++)
      bfr[t] = *(const s8frag*)&Bb[wn * 64 + t * 16 + l16][quad * 8];
#pragma unroll
    for (int mt = 0; mt < RB; mt++)
#pragma unroll
      for (int nt = 0; nt < 4; nt++)
        acc[mt][nt] = __builtin_amdgcn_mfma_f32_16x16x32_bf16(
            af[mt], bfr[nt], acc[mt][nt], 0, 0, 0);
  }

#pragma unroll
  for (int mt = 0; mt < RB; mt++) {
#pragma unroll
    for (int r = 0; r < 4; r++) {
      int m = row0 + wm * (RB * 16) + mt * 16 + quad * 4 + r;
      float tval = 0.f;
      if (mode == 2) {
        int bb = m >> 11, s = m & (SEQ - 1);
        int sp = (s < NCOND) ? 0 : (s - NCOND);
        tval = 8.0f - ttc[bb * S_TOK + sp];
      }
#pragma unroll
      for (int nt = 0; nt < 4; nt++) {
        int n = col0 + wn * 64 + nt * 16 + l16;
        if (mode == 4) {
          int sel = n >> 9, nn = n & 511;
          float bv = (sel == 0) ? b0[nn] : ((sel == 1) ? b1[nn] : b2[nn]);
          Cb[(size_t)sel * MROWS * DMODEL + (size_t)m * DMODEL + nn]
              = f2b(acc[mt][nt][r] + bv);
        } else {
          float v = acc[mt][nt][r] + b0[n];
          if (mode == 1)      v += b2f(Rb[(size_t)m * N + n]);
          else if (mode == 2) v = fmaxf(v, 0.f) + tval * ttcW[n] + ttcb[n];
          if (mode == 3) Cf[(size_t)m * N + n] = v;
          else           Cb[(size_t)m * N + n] = f2b(v);
        }
      }
    }
  }
}

// ---------------------------------------------------------------------------
// LayerNorm over D=512 (bf16 in -> bf16 out), one row per block.
// ---------------------------------------------------------------------------
__global__ __launch_bounds__(256) void ln_kernel(
    const bf16u* __restrict__ X, const float* __restrict__ g,
    const float* __restrict__ bta, bf16u* __restrict__ Y)
{
  int row = blockIdx.x, tid = threadIdx.x;
  unsigned int pr = *(const unsigned int*)&X[(size_t)row * DMODEL + 2 * tid];
  float x0 = b2f((bf16u)(pr & 0xffff)), x1 = b2f((bf16u)(pr >> 16));
  __shared__ float red[8];
  int wv = tid >> 6, ln = tid & 63;
  float s = x0 + x1;
  for (int off = 32; off; off >>= 1) s += __shfl_xor(s, off);
  if (ln == 0) red[wv] = s;
  __syncthreads();
  float mu = (red[0] + red[1] + red[2] + red[3]) * (1.0f / DMODEL);
  float d0 = x0 - mu, d1 = x1 - mu;
  float vs = d0 * d0 + d1 * d1;
  for (int off = 32; off; off >>= 1) vs += __shfl_xor(vs, off);
  if (ln == 0) red[4 + wv] = vs;
  __syncthreads();
  float var = (red[4] + red[5] + red[6] + red[7]) * (1.0f / DMODEL);
  float rstd = rsqrtf(var + 1e-6f);
  float y0 = d0 * rstd * g[2 * tid]     + bta[2 * tid];
  float y1 = d1 * rstd * g[2 * tid + 1] + bta[2 * tid + 1];
  *(unsigned int*)&Y[(size_t)row * DMODEL + 2 * tid] = pack2(y0, y1);
}

// ---------------------------------------------------------------------------
__global__ __launch_bounds__(256) void tok_embed_kernel(
    const int* __restrict__ toks, const float* __restrict__ emb,
    const float* __restrict__ pos, bf16u* __restrict__ xb)
{
  int sp = blockIdx.x, b = blockIdx.y;
  int s = sp + NCOND;
  int tok = toks[b * S_TOK + sp];
  const float* er = emb + (size_t)tok * DMODEL;
  const float* pr = pos + (size_t)s * DMODEL;
  size_t ro = ((size_t)b * SEQ + s) * DMODEL;
  int d = threadIdx.x * 2;
  float v0 = er[d]     * 22.62741699796952f + pr[d];
  float v1 = er[d + 1] * 22.62741699796952f + pr[d + 1];
  *(unsigned int*)&xb[ro + d] = pack2(v0, v1);
}

// ---------------------------------------------------------------------------
__global__ __launch_bounds__(256) void cond_embed_kernel(
    const float* __restrict__ conds, const float* __restrict__ W1,
    const float* __restrict__ b1, const float* __restrict__ W2w,
    const float* __restrict__ b2, const float* __restrict__ nullc,
    const float* __restrict__ pos, bf16u* __restrict__ xb)
{
  int ci = blockIdx.x, b = blockIdx.y, tid = threadIdx.x;
  float c = conds[b * NCOND + ci];
  bool cn = isnan(c);
  float cm = cn ? 0.f : c;
  __shared__ float h1[DMODEL / 2];
  h1[tid] = fmaxf(cm * W1[ci * (DMODEL/2) + tid] + b1[ci * (DMODEL/2) + tid], 0.f);
  __syncthreads();
  for (int d = tid; d < DMODEL; d += 256) {
    float acc = b2[ci * DMODEL + d];
    for (int i = 0; i < DMODEL / 2; i++)
      acc = fmaf(h1[i], W2w[((size_t)ci * (DMODEL/2) + i) * DMODEL + d], acc);
    float ce = cn ? nullc[ci * DMODEL + d] : acc;
    xb[((size_t)b * SEQ + ci) * DMODEL + d] = f2b(ce + pos[(size_t)ci * DMODEL + d]);
  }
}

// ---------------------------------------------------------------------------
// E (fp32, all 6 layers) -> bf16.
// ---------------------------------------------------------------------------
__global__ __launch_bounds__(256) void e_conv_kernel(
    const float* __restrict__ E, bf16u* __restrict__ Eb)
{
  int i = (blockIdx.x * 256 + threadIdx.x) * 4;
  float4 v = *(const float4*)&E[i];
  ushort4 o;
  o.x = f2b(v.x); o.y = f2b(v.y); o.z = f2b(v.z); o.w = f2b(v.w);
  *(ushort4*)&Eb[i] = o;
}

// ---------------------------------------------------------------------------
// Split-K MFMA flash attention (v4 structure, measured ~84us) + XCD-clustered
// block mapping: d -> (xcd = d&7, rank = d>>3); g = xcd*2 + (rank>>7),
// t = rank&127 -> (it,c). Each XCD serves exactly 2 (b,h) groups, so its
// private L2 holds just those K/V panels (+ shared E). LPT preserved: rank
// ascending -> it descending within each XCD's dispatch stream. Bijective.
// ---------------------------------------------------------------------------
#define PS_SWZ(row) ((((row) >> 2) & 7) << 3)

__global__ __launch_bounds__(256) void attn_part(
    const bf16u* __restrict__ Q, const bf16u* __restrict__ K,
    const bf16u* __restrict__ Vt_g, const bf16u* __restrict__ Eb16,
    const int* __restrict__ toks, bf16u* __restrict__ pacc,
    float* __restrict__ pstat)
{
  const int d = blockIdx.x;
  const int xcd = d & 7, rank = d >> 3;
  const int g  = xcd * 2 + (rank >> 7);   // (b,h) group, clustered per XCD
  const int t  = rank & 127;
  const int it = 31 - (t >> 2);           // q-tile, heavy-first (LPT)
  const int c  = t & 3;                   // key chunk
  if (8 * c > it) return;
  const int slot = (g << 7) | (it << 2) | c;   // logical index for partials
  const int b = g >> 3, h = g & 7;
  const int i0 = it * 64;

  __shared__ bf16u Kb[64][72];          // K tile; becomes P after mid barrier
  __shared__ bf16u Vt[64][72];
  __shared__ bf16u Ebs[128][72];
  __shared__ float padv[64];
  bf16u (*Ps)[72] = Kb;                 // alias: disjoint lifetimes per step

  const int tid  = threadIdx.x;
  const int lane = tid & 63;
  const int wave = tid >> 6;
  const int quad = lane >> 4;
  const int l16  = lane & 15;

  const bf16u* qr = Q + ((size_t)(b * SEQ + i0 + wave * 16 + l16)) * DMODEL + h * DHEAD;
  s8frag q0 = *(const s8frag*)&qr[quad * 8];
  s8frag q1 = *(const s8frag*)&qr[32 + quad * 8];

  float m_run[4], l_run[4];
  f4frag acc[4];
#pragma unroll
  for (int r = 0; r < 4; r++) { m_run[r] = -1e30f; l_run[r] = 0.f; }
#pragma unroll
  for (int dt = 0; dt < 4; dt++) acc[dt] = (f4frag){0.f, 0.f, 0.f, 0.f};

  const int js0 = 8 * c;
  const int jsE = min(8 * c + 8, it + 1);
  const size_t vtbase = (size_t)(g * DHEAD) * SEQ;

  for (int js = js0; js < jsE; js++) {
    const int j0 = js * 64;
    const int m0 = 1984 - i0 + j0;   // E row of band col 0
    __syncthreads();

    // K tile (2 x uint4 / thread)
#pragma unroll
    for (int e = 0; e < 2; e++) {
      int cc = e * 256 + tid;
      int jr = cc >> 3, doff = (cc & 7) * 8;
      *(uint4*)&Kb[jr][doff] =
          *(const uint4*)&K[((size_t)(b * SEQ + j0 + jr)) * DMODEL + h * DHEAD + doff];
    }
    // V^T tile from pre-transposed global (2 x uint4 / thread)
#pragma unroll
    for (int e = 0; e < 2; e++) {
      int cc = e * 256 + tid;
      int dr = cc >> 3, joff = (cc & 7) * 8;
      *(uint4*)&Vt[dr][joff] =
          *(const uint4*)&Vt_g[vtbase + (size_t)dr * SEQ + j0 + joff];
    }
    // E ring: first step fill 128 rows, then 64 new rows
    if (js == js0) {
#pragma unroll
      for (int e = 0; e < 4; e++) {
        int cc = e * 256 + tid;
        int er = cc >> 3, doff = (cc & 7) * 8;
        int m = m0 + er; int row = m > SEQ - 1 ? SEQ - 1 : m;
        *(uint4*)&Ebs[m & 127][doff] = *(const uint4*)&Eb16[(size_t)row * DHEAD + doff];
      }
    } else {
#pragma unroll
      for (int e = 0; e < 2; e++) {
        int cc = e * 256 + tid;
        int er = 64 + (cc >> 3), doff = (cc & 7) * 8;
        int m = m0 + er; int row = m > SEQ - 1 ? SEQ - 1 : m;
        *(uint4*)&Ebs[m & 127][doff] = *(const uint4*)&Eb16[(size_t)row * DHEAD + doff];
      }
    }
    if (tid < 64) {
      int j = j0 + tid;
      bool pad = (j >= NCOND) && (toks[b * S_TOK + j - NCOND] == 0);
      padv[tid] = pad ? -1e30f : 0.f;
    }
    __syncthreads();

    // QK^T (reads Kb)
    f4frag sc[4];
#pragma unroll
    for (int nt = 0; nt < 4; nt++) {
      s8frag k0 = *(const s8frag*)&Kb[nt * 16 + l16][quad * 8];
      s8frag k1 = *(const s8frag*)&Kb[nt * 16 + l16][32 + quad * 8];
      f4frag cc = (f4frag){0.f, 0.f, 0.f, 0.f};
      cc = __builtin_amdgcn_mfma_f32_16x16x32_bf16(q0, k0, cc, 0, 0, 0);
      cc = __builtin_amdgcn_mfma_f32_16x16x32_bf16(q1, k1, cc, 0, 0, 0);
      sc[nt] = cc;
    }

    // QE: 5 frags covering band cols [(3-wave)*16, (8-wave)*16)  (reads Ebs)
    f4frag qef[5];
#pragma unroll
    for (int f = 0; f < 5; f++) {
      int ct = f + 3 - wave;
      int m = m0 + ct * 16 + l16;
      const bf16u* erow = &Ebs[m & 127][0];
      s8frag e0 = *(const s8frag*)&erow[quad * 8];
      s8frag e1 = *(const s8frag*)&erow[32 + quad * 8];
      f4frag cc = (f4frag){0.f, 0.f, 0.f, 0.f};
      cc = __builtin_amdgcn_mfma_f32_16x16x32_bf16(q0, e0, cc, 0, 0, 0);
      cc = __builtin_amdgcn_mfma_f32_16x16x32_bf16(q1, e1, cc, 0, 0, 0);
      qef[f] = cc;
    }

    // All Kb/Ebs reads are drained by this barrier; Kb becomes the P buffer.
    __syncthreads();

    float pvv[4];
#pragma unroll
    for (int nt = 0; nt < 4; nt++) pvv[nt] = padv[nt * 16 + l16];

    // scores + online softmax; QE gathered by ONE shuffle (select at source).
    float s[4][4], mx[4];
#pragma unroll
    for (int r = 0; r < 4; r++) {
      int rloc = wave * 16 + quad * 4 + r;
      int ig = i0 + rloc;
      int t2 = quad * 4 + r;
      int v = 63 - 16 * wave + l16 - t2;
      int srcl = (lane & 48) | (v & 15);
      bool hiSrc = (l16 < 15 - t2);    // target hi <=> this at source lane
#pragma unroll
      for (int nt = 0; nt < 4; nt++) {
        float pre = hiSrc ? qef[nt + 1][r] : qef[nt][r];
        float qe = __shfl(pre, srcl);
        int jl = nt * 16 + l16;
        float sv = (sc[nt][r] + qe) * 0.125f + pvv[nt];
        if (j0 + jl > ig) sv = -1e30f;
        s[nt][r] = sv;
      }
      float m = fmaxf(fmaxf(s[0][r], s[1][r]), fmaxf(s[2][r], s[3][r]));
      float tr;
      DPP_ROR(tr, m, 1); m = fmaxf(m, tr);
      DPP_ROR(tr, m, 2); m = fmaxf(m, tr);
      DPP_ROR(tr, m, 4); m = fmaxf(m, tr);
      DPP_ROR(tr, m, 8); m = fmaxf(m, tr);
      mx[r] = m;
    }
    float alpha[4];
#pragma unroll
    for (int r = 0; r < 4; r++) {
      float m_new = fmaxf(m_run[r], mx[r]);
      alpha[r] = __expf(m_run[r] - m_new);
      float psum = 0.f;
      int rloc = wave * 16 + quad * 4 + r;
#pragma unroll
      for (int nt = 0; nt < 4; nt++) {
        float p = __expf(s[nt][r] - m_new);
        Ps[rloc][(nt * 16 + l16) ^ PS_SWZ(rloc)] = f2b(p);
        psum += p;
      }
      float tr;
      DPP_ROR(tr, psum, 1); psum += tr;
      DPP_ROR(tr, psum, 2); psum += tr;
      DPP_ROR(tr, psum, 4); psum += tr;
      DPP_ROR(tr, psum, 8); psum += tr;
      l_run[r] = l_run[r] * alpha[r] + psum;
      m_run[r] = m_new;
    }
#pragma unroll
    for (int dt = 0; dt < 4; dt++)
#pragma unroll
      for (int r = 0; r < 4; r++) acc[dt][r] *= alpha[r];

    // P @ V  (Ps rows are wave-local; swizzled reads match swizzled writes)
    {
      int prow = wave * 16 + l16;
      int psw = PS_SWZ(prow);
      s8frag p0 = *(const s8frag*)&Ps[prow][(quad * 8) ^ psw];
      s8frag p1 = *(const s8frag*)&Ps[prow][(32 + quad * 8) ^ psw];
#pragma unroll
      for (int dt = 0; dt < 4; dt++) {
        s8frag v0 = *(const s8frag*)&Vt[dt * 16 + l16][quad * 8];
        s8frag v1 = *(const s8frag*)&Vt[dt * 16 + l16][32 + quad * 8];
        acc[dt] = __builtin_amdgcn_mfma_f32_16x16x32_bf16(p0, v0, acc[dt], 0, 0, 0);
        acc[dt] = __builtin_amdgcn_mfma_f32_16x16x32_bf16(p1, v1, acc[dt], 0, 0, 0);
      }
    }
  }

  // write partials (indexed by logical slot, not blockIdx)
#pragma unroll
  for (int r = 0; r < 4; r++) {
    int rloc = wave * 16 + quad * 4 + r;
    if (l16 == 0) {
      pstat[(size_t)slot * 128 + rloc]      = m_run[r];
      pstat[(size_t)slot * 128 + 64 + rloc] = l_run[r];
    }
#pragma unroll
    for (int dt = 0; dt < 4; dt++)
      pacc[(size_t)slot * 4096 + rloc * 64 + dt * 16 + l16] = f2b(acc[dt][r]);
  }
}

// ---------------------------------------------------------------------------
// Merge <=4 chunk partials per (b,h,q-tile); write O (bf16) into qb.
// ---------------------------------------------------------------------------
__global__ __launch_bounds__(256) void attn_combine(
    const bf16u* __restrict__ pacc, const float* __restrict__ pstat,
    bf16u* __restrict__ O)
{
  int bid = blockIdx.x;             // g*32 + it
  int g = bid >> 5, it = bid & 31;
  int b = g >> 3, h = g & 7;
  int i0 = it * 64;
  int nc = (it >> 3) + 1;
  int tid = threadIdx.x;
  int row = tid >> 2, ql = tid & 3;

  float m_tot = -1e30f;
  float mc[4], lc[4];
#pragma unroll
  for (int c = 0; c < 4; c++) {
    if (c < nc) {
      size_t pb = (size_t)(bid * 4 + c) * 128;
      mc[c] = pstat[pb + row];
      lc[c] = pstat[pb + 64 + row];
      m_tot = fmaxf(m_tot, mc[c]);
    }
  }
  float l_tot = 0.f, w[4];
#pragma unroll
  for (int c = 0; c < 4; c++) {
    if (c < nc) { w[c] = __expf(mc[c] - m_tot); l_tot += w[c] * lc[c]; }
    else w[c] = 0.f;
  }
  float inv = 1.0f / l_tot;

  float out[16];
#pragma unroll
  for (int k = 0; k < 16; k++) out[k] = 0.f;
#pragma unroll
  for (int c = 0; c < 4; c++) {
    if (c >= nc) break;
    const bf16u* pa = pacc + (size_t)(bid * 4 + c) * 4096 + row * 64 + ql * 16;
#pragma unroll
    for (int k = 0; k < 16; k++) out[k] += w[c] * b2f(pa[k]);
  }
  bf16u* ob = O + ((size_t)(b * SEQ + i0 + row)) * DMODEL + h * DHEAD + ql * 16;
#pragma unroll
  for (int k = 0; k < 16; k++) ob[k] = f2b(out[k] * inv);
}

// ---------------------------------------------------------------------------
extern "C" void kernel_launch(void* const* d_in, const int* in_sizes, int n_in,
                              void* d_out, int out_size, void* d_ws, size_t ws_size,
                              hipStream_t stream) {
  const int*   toks  = (const int*)  d_in[0];
  const float* conds = (const float*)d_in[1];
  const float* ttc   = (const float*)d_in[2];
  const float* emb   = (const float*)d_in[3];
  const float* pos   = (const float*)d_in[4];
  const float* cW1   = (const float*)d_in[5];
  const float* cb1   = (const float*)d_in[6];
  const float* cW2   = (const float*)d_in[7];
  const float* cb2   = (const float*)d_in[8];
  const float* nullc = (const float*)d_in[9];
  const float* ttcW  = (const float*)d_in[10];
  const float* ttcb  = (const float*)d_in[11];
  const float* Wq    = (const float*)d_in[12];
  const float* Wk    = (const float*)d_in[13];
  const float* Wv    = (const float*)d_in[14];
  const float* Wo    = (const float*)d_in[15];
  const float* bq    = (const float*)d_in[16];
  const float* bk    = (const float*)d_in[17];
  const float* bv    = (const float*)d_in[18];
  const float* bo    = (const float*)d_in[19];
  const float* E     = (const float*)d_in[20];
  const float* fW1   = (const float*)d_in[21];
  const float* fb1   = (const float*)d_in[22];
  const float* fW2   = (const float*)d_in[23];
  const float* fb2   = (const float*)d_in[24];
  const float* ln1g  = (const float*)d_in[25];
  const float* ln1b  = (const float*)d_in[26];
  const float* ln2g  = (const float*)d_in[27];
  const float* ln2b  = (const float*)d_in[28];
  const float* fcW   = (const float*)d_in[29];
  const float* fcb   = (const float*)d_in[30];

  const size_t MB1 = 1024 * 1024;
  const size_t MD = (size_t)MROWS * DMODEL;
  char* p = (char*)d_ws;
  bf16u* xb    = (bf16u*)p; p += 4 * MB1;
  bf16u* qkvb  = (bf16u*)p; p += 12 * MB1;   // qb | kb | vb
  bf16u* hidb  = (bf16u*)p; p += 16 * MB1;   // FFN hidden / pacc alias
  float* pstat = (float*)p; p += 1 * MB1;
  bf16u* vbt   = (bf16u*)p; p += 4 * MB1;    // V transposed
  bf16u* ebf   = (bf16u*)p; p += 1536 * 1024;   // E bf16, 6 layers
  bf16u* WqkvT = (bf16u*)p; p += 9 * MB1;
  bf16u* WoT   = (bf16u*)p; p += 3 * MB1;
  bf16u* W1T   = (bf16u*)p; p += 12 * MB1;
  bf16u* W2T   = (bf16u*)p; p += 12 * MB1;
  bf16u* fcT   = (bf16u*)p; p += 512 * 1024;    // total 75 MB
  bf16u* qb = qkvb;
  bf16u* kb = qkvb + MD;        // out1b aliases kb (disjoint lifetimes)
  bf16u* vb = qkvb + 2 * MD;    // t1b aliases vb (disjoint lifetimes)
  bf16u* out1b = kb;
  bf16u* t1b   = vb;
  bf16u* pacc  = hidb;

  // ---- setup: embeds + all-layer weight transposes + E conversion ----
  cond_embed_kernel<<<dim3(NCOND, BATCH), 256, 0, stream>>>(
      conds, cW1, cb1, cW2, cb2, nullc, pos, xb);
  tok_embed_kernel<<<dim3(S_TOK, BATCH), 256, 0, stream>>>(toks, emb, pos, xb);
  wt_all_kernel<<<6 * 768 + 64, 256, 0, stream>>>(Wq, Wk, Wv, Wo, fW1, fW2, fcW,
      WqkvT, WoT, W1T, W2T, fcT);
  e_conv_kernel<<<(NLAYER * SEQ * DHEAD) / 1024, 256, 0, stream>>>(E, ebf);

  dim3 gQKV(MROWS / 128, 1536 / 128);      // (32,12)
  dim3 gFF1(MROWS / 128, DINNER / 128);    // (32,16)
  dim3 gN512(MROWS / 32, DMODEL / 128);    // (128,4): 512 blocks, RB=1

  for (int l = 0; l < NLAYER; l++) {
    // fused QKV
    mgemm<4><<<gQKV, 256, 0, stream>>>(xb, WqkvT + (size_t)l * 786432,
        bq + l * DMODEL, bk + l * DMODEL, bv + l * DMODEL, nullptr,
        nullptr, qkvb, MROWS, 1536, DMODEL, 4, nullptr, nullptr, nullptr);

    vt_kernel<<<512, 256, 0, stream>>>(vb, vbt);
    attn_part<<<2048, 256, 0, stream>>>(qb, kb, vbt,
        ebf + (size_t)l * SEQ * DHEAD, toks, pacc, pstat);
    attn_combine<<<512, 256, 0, stream>>>(pacc, pstat, qb);

    // t1 = attn @ Wo + bo + x
    mgemm<1><<<gN512, 256, 0, stream>>>(qb, WoT + (size_t)l * 262144,
        bo + l * DMODEL, nullptr, nullptr, xb,
        nullptr, t1b, MROWS, DMODEL, DMODEL, 1, nullptr, nullptr, nullptr);
    ln_kernel<<<MROWS, 256, 0, stream>>>(t1b, ln1g + l * DMODEL, ln1b + l * DMODEL,
        out1b);

    // hid = relu(out1 @ W1 + b1) + chord
    mgemm<4><<<gFF1, 256, 0, stream>>>(out1b, W1T + (size_t)l * 1048576,
        fb1 + l * DINNER, nullptr, nullptr, nullptr,
        nullptr, hidb, MROWS, DINNER, DMODEL, 2, ttc, ttcW, ttcb);
    // t1 = hid @ W2 + b2 + out1
    mgemm<1><<<gN512, 256, 0, stream>>>(hidb, W2T + (size_t)l * 1048576,
        fb2 + l * DMODEL, nullptr, nullptr, out1b,
        nullptr, t1b, MROWS, DMODEL, DINNER, 1, nullptr, nullptr, nullptr);
    ln_kernel<<<MROWS, 256, 0, stream>>>(t1b, ln2g + l * DMODEL, ln2b + l * DMODEL,
        xb);
  }

  // logits = x @ fc_W + fc_b (fp32 out)
  mgemm<1><<<gN512, 256, 0, stream>>>(xb, fcT,
      fcb, nullptr, nullptr, nullptr,
      (float*)d_out, nullptr, MROWS, VOCAB, DMODEL, 3, nullptr, nullptr, nullptr);
}

// Round 9
// 1337.294 us; speedup vs baseline: 1.1785x; 1.0367x over previous
//
#include <hip/hip_runtime.h>
#include <hip/hip_bf16.h>
#include <math.h>

// ---- problem constants ----
#define BATCH  2
#define S_TOK  2046
#define NCOND  2
#define SEQ    2048
#define DMODEL 512
#define DINNER 2048
#define NHEAD  8
#define DHEAD  64
#define NLAYER 6
#define VOCAB  512
#define MROWS  (BATCH*SEQ)   // 4096 rows

// split-K attention: 8 chunks of 4 steps; packed slots (144 per (b,h) group)
#define NSLOT_G 144
#define NSLOTS  (16 * NSLOT_G)   // 2304

typedef unsigned short bf16u;
typedef __attribute__((ext_vector_type(8))) short s8frag;   // 8 bf16 (4 VGPRs)
typedef __attribute__((ext_vector_type(4))) float f4frag;   // 4 fp32 acc

__device__ __forceinline__ float b2f(bf16u u) {
  union { unsigned int i; float f; } v; v.i = ((unsigned int)u) << 16; return v.f;
}
__device__ __forceinline__ bf16u f2b(float f) {
  union { float f; unsigned int i; } v; v.f = f;
  unsigned int x = v.i;
  return (bf16u)((x + 0x7fffu + ((x >> 16) & 1u)) >> 16);
}
__device__ __forceinline__ unsigned int pack2(float a, float b) {
  return (unsigned int)f2b(a) | ((unsigned int)f2b(b) << 16);
}

// async global->LDS, 16B per lane. LDS dest must be wave-uniform base +
// lane*16 (we pass per-lane ptrs that satisfy exactly that).
__device__ __forceinline__ void gld16(const bf16u* g, bf16u* l) {
  __builtin_amdgcn_global_load_lds(
      (const __attribute__((address_space(1))) unsigned int*)g,
      (__attribute__((address_space(3))) unsigned int*)l,
      16, 0, 0);
}

// DPP row-rotate (within 16-lane row) — VALU-pipe lane exchange, not LDS.
#define DPP_ROR(dst, src, N)                                              \
  dst = __int_as_float(__builtin_amdgcn_update_dpp(                       \
      0, __float_as_int(src), 0x120 + (N), 0xF, 0xF, true))

// packed slot offset: Sum_{j<it} ((j>>2)+1) = it + 2a(a-1) + a*b, a=it>>2,b=it&3
__device__ __forceinline__ int slot_off(int it) {
  int a = it >> 2, b = it & 3;
  return it + 2 * a * (a - 1) + a * b;
}

// ---------------------------------------------------------------------------
// All-layer weight transpose + bf16: dst[N][K] = src[K][N]. One launch.
// blocks: 6 layers x 768 (q64|k64|v64|o64|W1 256|W2 256) + 64 (fc) = 4672.
// ---------------------------------------------------------------------------
__global__ __launch_bounds__(256) void wt_all_kernel(
    const float* __restrict__ Wq, const float* __restrict__ Wk,
    const float* __restrict__ Wv, const float* __restrict__ Wo,
    const float* __restrict__ W1, const float* __restrict__ W2,
    const float* __restrict__ fcW,
    bf16u* __restrict__ qkvT, bf16u* __restrict__ oT,
    bf16u* __restrict__ w1T, bf16u* __restrict__ w2T, bf16u* __restrict__ fcT)
{
  int bid = blockIdx.x;
  const float* src; bf16u* dst; int N, K, kt, nt;
  if (bid < 6 * 768) {
    int L = bid / 768, t = bid - L * 768;
    if (t < 256) {
      int mat = t >> 6, tt = t & 63;
      const float* s4[4] = {Wq, Wk, Wv, Wo};
      src = s4[mat] + (size_t)L * DMODEL * DMODEL;
      dst = (mat < 3) ? (qkvT + (size_t)L * 786432 + (size_t)mat * 262144)
                      : (oT + (size_t)L * 262144);
      K = DMODEL; N = DMODEL; kt = tt >> 3; nt = tt & 7;
    } else if (t < 512) {
      int tt = t - 256;
      src = W1 + (size_t)L * DMODEL * DINNER; dst = w1T + (size_t)L * 1048576;
      K = DMODEL; N = DINNER; kt = tt >> 5; nt = tt & 31;
    } else {
      int tt = t - 512;
      src = W2 + (size_t)L * DINNER * DMODEL; dst = w2T + (size_t)L * 1048576;
      K = DINNER; N = DMODEL; kt = tt >> 3; nt = tt & 7;
    }
  } else {
    int tt = bid - 6 * 768;
    src = fcW; dst = fcT;
    K = DMODEL; N = VOCAB; kt = tt >> 3; nt = tt & 7;
  }
  __shared__ bf16u Ls[64][66];
  int tid = threadIdx.x;
  int c = tid & 63, r4 = tid >> 6;
#pragma unroll
  for (int i = 0; i < 16; i++) {
    int r = i * 4 + r4;
    Ls[r][c] = f2b(src[(size_t)(kt * 64 + r) * N + nt * 64 + c]);
  }
  __syncthreads();
#pragma unroll
  for (int i = 0; i < 16; i++) {
    int rr = i * 4 + r4;
    dst[(size_t)(nt * 64 + rr) * K + kt * 64 + c] = Ls[c][rr];
  }
}

// ---------------------------------------------------------------------------
// V transpose (bf16): vb[(b,i)][h*64+d] -> vbt[(b*8+h)*64+d][i]. 512 blocks.
// ---------------------------------------------------------------------------
__global__ __launch_bounds__(256) void vt_kernel(
    const bf16u* __restrict__ vb, bf16u* __restrict__ vbt)
{
  int bid = blockIdx.x;
  int b = bid >> 8, t = bid & 255;
  int it = t >> 3, h = t & 7;
  __shared__ bf16u Ls[64][66];
  int tid = threadIdx.x;
  int c = tid & 63, r4 = tid >> 6;
#pragma unroll
  for (int i = 0; i < 16; i++) {
    int r = i * 4 + r4;
    Ls[r][c] = vb[(size_t)(b * SEQ + it * 64 + r) * DMODEL + h * DHEAD + c];
  }
  __syncthreads();
#pragma unroll
  for (int i = 0; i < 16; i++) {
    int rr = i * 4 + r4;
    vbt[(size_t)((b * 8 + h) * DHEAD + rr) * SEQ + it * 64 + c] = Ls[c][rr];
  }
}

// ---------------------------------------------------------------------------
// MFMA GEMM, RB m-tiles/wave (4 -> 128x128, 2 -> 64x128, 1 -> 32x128).
// Staging via global_load_lds; LINEAR LDS tiles; XCD-chunked tile swizzle
// (validated R8: -80us). modes: 0 +bias->bf16 ; 1 +bias+Rb ; 2 relu+chord ;
// 3 +bias->fp32 ; 4 fused-QKV routing.
// ---------------------------------------------------------------------------
template <int RB>
__global__ __launch_bounds__(256) void mgemm(
    const bf16u* __restrict__ A, const bf16u* __restrict__ Wt,
    const float* __restrict__ b0, const float* __restrict__ b1,
    const float* __restrict__ b2, const bf16u* __restrict__ Rb,
    float* __restrict__ Cf, bf16u* __restrict__ Cb,
    int M, int N, int K, int mode,
    const float* __restrict__ ttc, const float* __restrict__ ttcW,
    const float* __restrict__ ttcb)
{
  __shared__ bf16u Ab[RB * 32][32];
  __shared__ bf16u Bb[128][32];
  const int tid = threadIdx.x;
  const int lane = tid & 63, wave = tid >> 6;
  const int quad = lane >> 4, l16 = lane & 15;
  const int wm = wave >> 1, wn = wave & 1;

  // XCD-chunked swizzle (bijective; nwg % 8 == 0 for all launches)
  const int nwg = gridDim.x * gridDim.y;
  const int lin = blockIdx.y * gridDim.x + blockIdx.x;
  const int swz = (lin & 7) * (nwg >> 3) + (lin >> 3);
  const int bx = swz % gridDim.x, by = swz / gridDim.x;
  const int row0 = bx * (RB * 32), col0 = by * 128;

  f4frag acc[RB][4];
#pragma unroll
  for (int i = 0; i < RB; i++)
#pragma unroll
    for (int j = 0; j < 4; j++) acc[i][j] = (f4frag){0.f, 0.f, 0.f, 0.f};

  for (int k0 = 0; k0 < K; k0 += 32) {
    if (k0) __syncthreads();
    if constexpr (RB >= 2) {
#pragma unroll
      for (int i = 0; i < RB / 2; i++) {
        int chunk = i * 256 + tid;
        int r = chunk >> 2, q = chunk & 3;
        gld16(&A[(size_t)(row0 + r) * K + k0 + q * 8], &Ab[0][0] + chunk * 8);
      }
    } else {
      if (tid < 128) {
        int r = tid >> 2, q = tid & 3;
        gld16(&A[(size_t)(row0 + r) * K + k0 + q * 8], &Ab[0][0] + tid * 8);
      }
    }
#pragma unroll
    for (int i = 0; i < 2; i++) {
      int chunk = i * 256 + tid;
      int r = chunk >> 2, q = chunk & 3;
      gld16(&Wt[(size_t)(col0 + r) * K + k0 + q * 8], &Bb[0][0] + chunk * 8);
    }
    __syncthreads();   // compiler drains vmcnt before s_barrier
    s8frag af[RB], bfr[4];
#pragma unroll
    for (int t = 0; t < RB; t++)
      af[t] = *(const s8frag*)&Ab[wm * (RB * 16) + t * 16 + l16][quad * 8];
#pragma unroll
    for (int t = 0; t < 4; t++)
      bfr[t] = *(const s8frag*)&Bb[wn * 64 + t * 16 + l16][quad * 8];
#pragma unroll
    for (int mt = 0; mt < RB; mt++)
#pragma unroll
      for (int nt = 0; nt < 4; nt++)
        acc[mt][nt] = __builtin_amdgcn_mfma_f32_16x16x32_bf16(
            af[mt], bfr[nt], acc[mt][nt], 0, 0, 0);
  }

#pragma unroll
  for (int mt = 0; mt < RB; mt++) {
#pragma unroll
    for (int r = 0; r < 4; r++) {
      int m = row0 + wm * (RB * 16) + mt * 16 + quad * 4 + r;
      float tval = 0.f;
      if (mode == 2) {
        int bb = m >> 11, s = m & (SEQ - 1);
        int sp = (s < NCOND) ? 0 : (s - NCOND);
        tval = 8.0f - ttc[bb * S_TOK + sp];
      }
#pragma unroll
      for (int nt = 0; nt < 4; nt++) {
        int n = col0 + wn * 64 + nt * 16 + l16;
        if (mode == 4) {
          int sel = n >> 9, nn = n & 511;
          float bv = (sel == 0) ? b0[nn] : ((sel == 1) ? b1[nn] : b2[nn]);
          Cb[(size_t)sel * MROWS * DMODEL + (size_t)m * DMODEL + nn]
              = f2b(acc[mt][nt][r] + bv);
        } else {
          float v = acc[mt][nt][r] + b0[n];
          if (mode == 1)      v += b2f(Rb[(size_t)m * N + n]);
          else if (mode == 2) v = fmaxf(v, 0.f) + tval * ttcW[n] + ttcb[n];
          if (mode == 3) Cf[(size_t)m * N + n] = v;
          else           Cb[(size_t)m * N + n] = f2b(v);
        }
      }
    }
  }
}

// ---------------------------------------------------------------------------
// LayerNorm over D=512 (bf16 in -> bf16 out), one row per block.
// ---------------------------------------------------------------------------
__global__ __launch_bounds__(256) void ln_kernel(
    const bf16u* __restrict__ X, const float* __restrict__ g,
    const float* __restrict__ bta, bf16u* __restrict__ Y)
{
  int row = blockIdx.x, tid = threadIdx.x;
  unsigned int pr = *(const unsigned int*)&X[(size_t)row * DMODEL + 2 * tid];
  float x0 = b2f((bf16u)(pr & 0xffff)), x1 = b2f((bf16u)(pr >> 16));
  __shared__ float red[8];
  int wv = tid >> 6, ln = tid & 63;
  float s = x0 + x1;
  for (int off = 32; off; off >>= 1) s += __shfl_xor(s, off);
  if (ln == 0) red[wv] = s;
  __syncthreads();
  float mu = (red[0] + red[1] + red[2] + red[3]) * (1.0f / DMODEL);
  float d0 = x0 - mu, d1 = x1 - mu;
  float vs = d0 * d0 + d1 * d1;
  for (int off = 32; off; off >>= 1) vs += __shfl_xor(vs, off);
  if (ln == 0) red[4 + wv] = vs;
  __syncthreads();
  float var = (red[4] + red[5] + red[6] + red[7]) * (1.0f / DMODEL);
  float rstd = rsqrtf(var + 1e-6f);
  float y0 = d0 * rstd * g[2 * tid]     + bta[2 * tid];
  float y1 = d1 * rstd * g[2 * tid + 1] + bta[2 * tid + 1];
  *(unsigned int*)&Y[(size_t)row * DMODEL + 2 * tid] = pack2(y0, y1);
}

// ---------------------------------------------------------------------------
__global__ __launch_bounds__(256) void tok_embed_kernel(
    const int* __restrict__ toks, const float* __restrict__ emb,
    const float* __restrict__ pos, bf16u* __restrict__ xb)
{
  int sp = blockIdx.x, b = blockIdx.y;
  int s = sp + NCOND;
  int tok = toks[b * S_TOK + sp];
  const float* er = emb + (size_t)tok * DMODEL;
  const float* pr = pos + (size_t)s * DMODEL;
  size_t ro = ((size_t)b * SEQ + s) * DMODEL;
  int d = threadIdx.x * 2;
  float v0 = er[d]     * 22.62741699796952f + pr[d];
  float v1 = er[d + 1] * 22.62741699796952f + pr[d + 1];
  *(unsigned int*)&xb[ro + d] = pack2(v0, v1);
}

// ---------------------------------------------------------------------------
__global__ __launch_bounds__(256) void cond_embed_kernel(
    const float* __restrict__ conds, const float* __restrict__ W1,
    const float* __restrict__ b1, const float* __restrict__ W2w,
    const float* __restrict__ b2, const float* __restrict__ nullc,
    const float* __restrict__ pos, bf16u* __restrict__ xb)
{
  int ci = blockIdx.x, b = blockIdx.y, tid = threadIdx.x;
  float c = conds[b * NCOND + ci];
  bool cn = isnan(c);
  float cm = cn ? 0.f : c;
  __shared__ float h1[DMODEL / 2];
  h1[tid] = fmaxf(cm * W1[ci * (DMODEL/2) + tid] + b1[ci * (DMODEL/2) + tid], 0.f);
  __syncthreads();
  for (int d = tid; d < DMODEL; d += 256) {
    float acc = b2[ci * DMODEL + d];
    for (int i = 0; i < DMODEL / 2; i++)
      acc = fmaf(h1[i], W2w[((size_t)ci * (DMODEL/2) + i) * DMODEL + d], acc);
    float ce = cn ? nullc[ci * DMODEL + d] : acc;
    xb[((size_t)b * SEQ + ci) * DMODEL + d] = f2b(ce + pos[(size_t)ci * DMODEL + d]);
  }
}

// ---------------------------------------------------------------------------
// E (fp32, all 6 layers) -> bf16.
// ---------------------------------------------------------------------------
__global__ __launch_bounds__(256) void e_conv_kernel(
    const float* __restrict__ E, bf16u* __restrict__ Eb)
{
  int i = (blockIdx.x * 256 + threadIdx.x) * 4;
  float4 v = *(const float4*)&E[i];
  ushort4 o;
  o.x = f2b(v.x); o.y = f2b(v.y); o.z = f2b(v.z); o.w = f2b(v.w);
  *(ushort4*)&Eb[i] = o;
}

// ---------------------------------------------------------------------------
// Split-K MFMA flash attention, 8 chunks x <=4 steps (was 4 x 8).
// R8 counters: FETCH halved by XCD-clustering but dur flat at 17% occupancy
// -> concurrency-bound. Deeper split: working blocks 1088 -> 2304, critical
// path halves. Partials packed (144 slots per g) into the vb+hidb span.
// XCD clustering (2 g per XCD) + LPT (heavy it first) preserved.
// ---------------------------------------------------------------------------
#define PS_SWZ(row) ((((row) >> 2) & 7) << 3)

__global__ __launch_bounds__(256) void attn_part(
    const bf16u* __restrict__ Q, const bf16u* __restrict__ K,
    const bf16u* __restrict__ Vt_g, const bf16u* __restrict__ Eb16,
    const int* __restrict__ toks, bf16u* __restrict__ pacc,
    float* __restrict__ pstat)
{
  const int d = blockIdx.x;
  const int xcd = d & 7, rank = d >> 3;
  const int g  = xcd * 2 + (rank >> 8);   // (b,h) group, clustered per XCD
  const int t  = rank & 255;
  const int it = 31 - (t >> 3);           // q-tile, heavy-first (LPT)
  const int c  = t & 7;                   // key chunk (4 steps each)
  if (4 * c > it) return;
  const int slot = g * NSLOT_G + slot_off(it) + c;   // packed partial index
  const int b = g >> 3, h = g & 7;
  const int i0 = it * 64;

  __shared__ bf16u Kb[64][72];          // K tile; becomes P after mid barrier
  __shared__ bf16u Vt[64][72];
  __shared__ bf16u Ebs[128][72];
  __shared__ float padv[64];
  bf16u (*Ps)[72] = Kb;                 // alias: disjoint lifetimes per step

  const int tid  = threadIdx.x;
  const int lane = tid & 63;
  const int wave = tid >> 6;
  const int quad = lane >> 4;
  const int l16  = lane & 15;

  const bf16u* qr = Q + ((size_t)(b * SEQ + i0 + wave * 16 + l16)) * DMODEL + h * DHEAD;
  s8frag q0 = *(const s8frag*)&qr[quad * 8];
  s8frag q1 = *(const s8frag*)&qr[32 + quad * 8];

  float m_run[4], l_run[4];
  f4frag acc[4];
#pragma unroll
  for (int r = 0; r < 4; r++) { m_run[r] = -1e30f; l_run[r] = 0.f; }
#pragma unroll
  for (int dt = 0; dt < 4; dt++) acc[dt] = (f4frag){0.f, 0.f, 0.f, 0.f};

  const int js0 = 4 * c;
  const int jsE = min(4 * c + 4, it + 1);
  const size_t vtbase = (size_t)(g * DHEAD) * SEQ;

  for (int js = js0; js < jsE; js++) {
    const int j0 = js * 64;
    const int m0 = 1984 - i0 + j0;   // E row of band col 0
    __syncthreads();

    // K tile (2 x uint4 / thread)
#pragma unroll
    for (int e = 0; e < 2; e++) {
      int cc = e * 256 + tid;
      int jr = cc >> 3, doff = (cc & 7) * 8;
      *(uint4*)&Kb[jr][doff] =
          *(const uint4*)&K[((size_t)(b * SEQ + j0 + jr)) * DMODEL + h * DHEAD + doff];
    }
    // V^T tile from pre-transposed global (2 x uint4 / thread)
#pragma unroll
    for (int e = 0; e < 2; e++) {
      int cc = e * 256 + tid;
      int dr = cc >> 3, joff = (cc & 7) * 8;
      *(uint4*)&Vt[dr][joff] =
          *(const uint4*)&Vt_g[vtbase + (size_t)dr * SEQ + j0 + joff];
    }
    // E ring: first step fill 128 rows, then 64 new rows
    if (js == js0) {
#pragma unroll
      for (int e = 0; e < 4; e++) {
        int cc = e * 256 + tid;
        int er = cc >> 3, doff = (cc & 7) * 8;
        int m = m0 + er; int row = m > SEQ - 1 ? SEQ - 1 : m;
        *(uint4*)&Ebs[m & 127][doff] = *(const uint4*)&Eb16[(size_t)row * DHEAD + doff];
      }
    } else {
#pragma unroll
      for (int e = 0; e < 2; e++) {
        int cc = e * 256 + tid;
        int er = 64 + (cc >> 3), doff = (cc & 7) * 8;
        int m = m0 + er; int row = m > SEQ - 1 ? SEQ - 1 : m;
        *(uint4*)&Ebs[m & 127][doff] = *(const uint4*)&Eb16[(size_t)row * DHEAD + doff];
      }
    }
    if (tid < 64) {
      int j = j0 + tid;
      bool pad = (j >= NCOND) && (toks[b * S_TOK + j - NCOND] == 0);
      padv[tid] = pad ? -1e30f : 0.f;
    }
    __syncthreads();

    // QK^T (reads Kb)
    f4frag sc[4];
#pragma unroll
    for (int nt = 0; nt < 4; nt++) {
      s8frag k0 = *(const s8frag*)&Kb[nt * 16 + l16][quad * 8];
      s8frag k1 = *(const s8frag*)&Kb[nt * 16 + l16][32 + quad * 8];
      f4frag cc = (f4frag){0.f, 0.f, 0.f, 0.f};
      cc = __builtin_amdgcn_mfma_f32_16x16x32_bf16(q0, k0, cc, 0, 0, 0);
      cc = __builtin_amdgcn_mfma_f32_16x16x32_bf16(q1, k1, cc, 0, 0, 0);
      sc[nt] = cc;
    }

    // QE: 5 frags covering band cols [(3-wave)*16, (8-wave)*16)  (reads Ebs)
    f4frag qef[5];
#pragma unroll
    for (int f = 0; f < 5; f++) {
      int ct = f + 3 - wave;
      int m = m0 + ct * 16 + l16;
      const bf16u* erow = &Ebs[m & 127][0];
      s8frag e0 = *(const s8frag*)&erow[quad * 8];
      s8frag e1 = *(const s8frag*)&erow[32 + quad * 8];
      f4frag cc = (f4frag){0.f, 0.f, 0.f, 0.f};
      cc = __builtin_amdgcn_mfma_f32_16x16x32_bf16(q0, e0, cc, 0, 0, 0);
      cc = __builtin_amdgcn_mfma_f32_16x16x32_bf16(q1, e1, cc, 0, 0, 0);
      qef[f] = cc;
    }

    // All Kb/Ebs reads are drained by this barrier; Kb becomes the P buffer.
    __syncthreads();

    float pvv[4];
#pragma unroll
    for (int nt = 0; nt < 4; nt++) pvv[nt] = padv[nt * 16 + l16];

    // scores + online softmax; QE gathered by ONE shuffle (select at source).
    float s[4][4], mx[4];
#pragma unroll
    for (int r = 0; r < 4; r++) {
      int rloc = wave * 16 + quad * 4 + r;
      int ig = i0 + rloc;
      int t2 = quad * 4 + r;
      int v = 63 - 16 * wave + l16 - t2;
      int srcl = (lane & 48) | (v & 15);
      bool hiSrc = (l16 < 15 - t2);    // target hi <=> this at source lane
#pragma unroll
      for (int nt = 0; nt < 4; nt++) {
        float pre = hiSrc ? qef[nt + 1][r] : qef[nt][r];
        float qe = __shfl(pre, srcl);
        int jl = nt * 16 + l16;
        float sv = (sc[nt][r] + qe) * 0.125f + pvv[nt];
        if (j0 + jl > ig) sv = -1e30f;
        s[nt][r] = sv;
      }
      float m = fmaxf(fmaxf(s[0][r], s[1][r]), fmaxf(s[2][r], s[3][r]));
      float tr;
      DPP_ROR(tr, m, 1); m = fmaxf(m, tr);
      DPP_ROR(tr, m, 2); m = fmaxf(m, tr);
      DPP_ROR(tr, m, 4); m = fmaxf(m, tr);
      DPP_ROR(tr, m, 8); m = fmaxf(m, tr);
      mx[r] = m;
    }
    float alpha[4];
#pragma unroll
    for (int r = 0; r < 4; r++) {
      float m_new = fmaxf(m_run[r], mx[r]);
      alpha[r] = __expf(m_run[r] - m_new);
      float psum = 0.f;
      int rloc = wave * 16 + quad * 4 + r;
#pragma unroll
      for (int nt = 0; nt < 4; nt++) {
        float p = __expf(s[nt][r] - m_new);
        Ps[rloc][(nt * 16 + l16) ^ PS_SWZ(rloc)] = f2b(p);
        psum += p;
      }
      float tr;
      DPP_ROR(tr, psum, 1); psum += tr;
      DPP_ROR(tr, psum, 2); psum += tr;
      DPP_ROR(tr, psum, 4); psum += tr;
      DPP_ROR(tr, psum, 8); psum += tr;
      l_run[r] = l_run[r] * alpha[r] + psum;
      m_run[r] = m_new;
    }
#pragma unroll
    for (int dt = 0; dt < 4; dt++)
#pragma unroll
      for (int r = 0; r < 4; r++) acc[dt][r] *= alpha[r];

    // P @ V  (Ps rows are wave-local; swizzled reads match swizzled writes)
    {
      int prow = wave * 16 + l16;
      int psw = PS_SWZ(prow);
      s8frag p0 = *(const s8frag*)&Ps[prow][(quad * 8) ^ psw];
      s8frag p1 = *(const s8frag*)&Ps[prow][(32 + quad * 8) ^ psw];
#pragma unroll
      for (int dt = 0; dt < 4; dt++) {
        s8frag v0 = *(const s8frag*)&Vt[dt * 16 + l16][quad * 8];
        s8frag v1 = *(const s8frag*)&Vt[dt * 16 + l16][32 + quad * 8];
        acc[dt] = __builtin_amdgcn_mfma_f32_16x16x32_bf16(p0, v0, acc[dt], 0, 0, 0);
        acc[dt] = __builtin_amdgcn_mfma_f32_16x16x32_bf16(p1, v1, acc[dt], 0, 0, 0);
      }
    }
  }

  // write partials (packed slot)
#pragma unroll
  for (int r = 0; r < 4; r++) {
    int rloc = wave * 16 + quad * 4 + r;
    if (l16 == 0) {
      pstat[(size_t)slot * 128 + rloc]      = m_run[r];
      pstat[(size_t)slot * 128 + 64 + rloc] = l_run[r];
    }
#pragma unroll
    for (int dt = 0; dt < 4; dt++)
      pacc[(size_t)slot * 4096 + rloc * 64 + dt * 16 + l16] = f2b(acc[dt][r]);
  }
}

// ---------------------------------------------------------------------------
// Merge <=8 chunk partials per (b,h,q-tile); write O (bf16) into qb.
// ---------------------------------------------------------------------------
__global__ __launch_bounds__(256) void attn_combine(
    const bf16u* __restrict__ pacc, const float* __restrict__ pstat,
    bf16u* __restrict__ O)
{
  int bid = blockIdx.x;             // g*32 + it
  int g = bid >> 5, it = bid & 31;
  int b = g >> 3, h = g & 7;
  int i0 = it * 64;
  int nc = (it >> 2) + 1;           // chunks of 4 steps
  int base = g * NSLOT_G + slot_off(it);
  int tid = threadIdx.x;
  int row = tid >> 2, ql = tid & 3;

  float m_tot = -1e30f;
  float mc[8], lc[8];
#pragma unroll
  for (int c = 0; c < 8; c++) {
    if (c < nc) {
      size_t pb = (size_t)(base + c) * 128;
      mc[c] = pstat[pb + row];
      lc[c] = pstat[pb + 64 + row];
      m_tot = fmaxf(m_tot, mc[c]);
    }
  }
  float l_tot = 0.f, w[8];
#pragma unroll
  for (int c = 0; c < 8; c++) {
    if (c < nc) { w[c] = __expf(mc[c] - m_tot); l_tot += w[c] * lc[c]; }
    else w[c] = 0.f;
  }
  float inv = 1.0f / l_tot;

  float out[16];
#pragma unroll
  for (int k = 0; k < 16; k++) out[k] = 0.f;
#pragma unroll
  for (int c = 0; c < 8; c++) {
    if (c >= nc) break;
    const bf16u* pa = pacc + (size_t)(base + c) * 4096 + row * 64 + ql * 16;
#pragma unroll
    for (int k = 0; k < 16; k++) out[k] += w[c] * b2f(pa[k]);
  }
  bf16u* ob = O + ((size_t)(b * SEQ + i0 + row)) * DMODEL + h * DHEAD + ql * 16;
#pragma unroll
  for (int k = 0; k < 16; k++) ob[k] = f2b(out[k] * inv);
}

// ---------------------------------------------------------------------------
extern "C" void kernel_launch(void* const* d_in, const int* in_sizes, int n_in,
                              void* d_out, int out_size, void* d_ws, size_t ws_size,
                              hipStream_t stream) {
  const int*   toks  = (const int*)  d_in[0];
  const float* conds = (const float*)d_in[1];
  const float* ttc   = (const float*)d_in[2];
  const float* emb   = (const float*)d_in[3];
  const float* pos   = (const float*)d_in[4];
  const float* cW1   = (const float*)d_in[5];
  const float* cb1   = (const float*)d_in[6];
  const float* cW2   = (const float*)d_in[7];
  const float* cb2   = (const float*)d_in[8];
  const float* nullc = (const float*)d_in[9];
  const float* ttcW  = (const float*)d_in[10];
  const float* ttcb  = (const float*)d_in[11];
  const float* Wq    = (const float*)d_in[12];
  const float* Wk    = (const float*)d_in[13];
  const float* Wv    = (const float*)d_in[14];
  const float* Wo    = (const float*)d_in[15];
  const float* bq    = (const float*)d_in[16];
  const float* bk    = (const float*)d_in[17];
  const float* bv    = (const float*)d_in[18];
  const float* bo    = (const float*)d_in[19];
  const float* E     = (const float*)d_in[20];
  const float* fW1   = (const float*)d_in[21];
  const float* fb1   = (const float*)d_in[22];
  const float* fW2   = (const float*)d_in[23];
  const float* fb2   = (const float*)d_in[24];
  const float* ln1g  = (const float*)d_in[25];
  const float* ln1b  = (const float*)d_in[26];
  const float* ln2g  = (const float*)d_in[27];
  const float* ln2b  = (const float*)d_in[28];
  const float* fcW   = (const float*)d_in[29];
  const float* fcb   = (const float*)d_in[30];

  const size_t MB1 = 1024 * 1024;
  const size_t MD = (size_t)MROWS * DMODEL;
  char* p = (char*)d_ws;
  bf16u* xb    = (bf16u*)p; p += 4 * MB1;
  bf16u* qkvb  = (bf16u*)p; p += 12 * MB1;   // qb | kb | vb
  bf16u* hidb  = (bf16u*)p; p += 16 * MB1;   // FFN hidden
  float* pstat_old = (float*)p; p += 1 * MB1; // (unused; kept for layout)
  bf16u* vbt   = (bf16u*)p; p += 4 * MB1;    // V transposed
  bf16u* ebf   = (bf16u*)p; p += 1536 * 1024;   // E bf16, 6 layers
  bf16u* WqkvT = (bf16u*)p; p += 9 * MB1;
  bf16u* WoT   = (bf16u*)p; p += 3 * MB1;
  bf16u* W1T   = (bf16u*)p; p += 12 * MB1;
  bf16u* W2T   = (bf16u*)p; p += 12 * MB1;
  bf16u* fcT   = (bf16u*)p; p += 512 * 1024;    // total 75 MB
  (void)pstat_old;
  bf16u* qb = qkvb;
  bf16u* kb = qkvb + MD;        // out1b aliases kb (disjoint lifetimes)
  bf16u* vb = qkvb + 2 * MD;    // t1b aliases vb (disjoint lifetimes)
  bf16u* out1b = kb;
  bf16u* t1b   = vb;
  // Partials live in the contiguous vb+hidb span (20MB): vb is dead after
  // vt_kernel; hidb's FFN lifetime starts after attn_combine.
  // pacc 2304*8KB = 18MB, pstat 2304*512B = 1.15MB -> 19.15MB <= 20MB.
  bf16u* pacc  = vb;
  float* pstat = (float*)(pacc + (size_t)NSLOTS * 4096);

  // ---- setup: embeds + all-layer weight transposes + E conversion ----
  cond_embed_kernel<<<dim3(NCOND, BATCH), 256, 0, stream>>>(
      conds, cW1, cb1, cW2, cb2, nullc, pos, xb);
  tok_embed_kernel<<<dim3(S_TOK, BATCH), 256, 0, stream>>>(toks, emb, pos, xb);
  wt_all_kernel<<<6 * 768 + 64, 256, 0, stream>>>(Wq, Wk, Wv, Wo, fW1, fW2, fcW,
      WqkvT, WoT, W1T, W2T, fcT);
  e_conv_kernel<<<(NLAYER * SEQ * DHEAD) / 1024, 256, 0, stream>>>(E, ebf);

  dim3 gQKV(MROWS / 128, 1536 / 128);      // (32,12)
  dim3 gFF1(MROWS / 128, DINNER / 128);    // (32,16)
  dim3 gN512(MROWS / 32, DMODEL / 128);    // (128,4): 512 blocks, RB=1

  for (int l = 0; l < NLAYER; l++) {
    // fused QKV
    mgemm<4><<<gQKV, 256, 0, stream>>>(xb, WqkvT + (size_t)l * 786432,
        bq + l * DMODEL, bk + l * DMODEL, bv + l * DMODEL, nullptr,
        nullptr, qkvb, MROWS, 1536, DMODEL, 4, nullptr, nullptr, nullptr);

    vt_kernel<<<512, 256, 0, stream>>>(vb, vbt);
    attn_part<<<4096, 256, 0, stream>>>(qb, kb, vbt,
        ebf + (size_t)l * SEQ * DHEAD, toks, pacc, pstat);
    attn_combine<<<512, 256, 0, stream>>>(pacc, pstat, qb);

    // t1 = attn @ Wo + bo + x
    mgemm<1><<<gN512, 256, 0, stream>>>(qb, WoT + (size_t)l * 262144,
        bo + l * DMODEL, nullptr, nullptr, xb,
        nullptr, t1b, MROWS, DMODEL, DMODEL, 1, nullptr, nullptr, nullptr);
    ln_kernel<<<MROWS, 256, 0, stream>>>(t1b, ln1g + l * DMODEL, ln1b + l * DMODEL,
        out1b);

    // hid = relu(out1 @ W1 + b1) + chord
    mgemm<4><<<gFF1, 256, 0, stream>>>(out1b, W1T + (size_t)l * 1048576,
        fb1 + l * DINNER, nullptr, nullptr, nullptr,
        nullptr, hidb, MROWS, DINNER, DMODEL, 2, ttc, ttcW, ttcb);
    // t1 = hid @ W2 + b2 + out1
    mgemm<1><<<gN512, 256, 0, stream>>>(hidb, W2T + (size_t)l * 1048576,
        fb2 + l * DMODEL, nullptr, nullptr, out1b,
        nullptr, t1b, MROWS, DMODEL, DINNER, 1, nullptr, nullptr, nullptr);
    ln_kernel<<<MROWS, 256, 0, stream>>>(t1b, ln2g + l * DMODEL, ln2b + l * DMODEL,
        xb);
  }

  // logits = x @ fc_W + fc_b (fp32 out)
  mgemm<1><<<gN512, 256, 0, stream>>>(xb, fcT,
      fcb, nullptr, nullptr, nullptr,
      (float*)d_out, nullptr, MROWS, VOCAB, DMODEL, 3, nullptr, nullptr, nullptr);
}

// Round 10
// 1226.300 us; speedup vs baseline: 1.2852x; 1.0905x over previous
//
#include <hip/hip_runtime.h>
#include <hip/hip_bf16.h>
#include <math.h>

// ---- problem constants ----
#define BATCH  2
#define S_TOK  2046
#define NCOND  2
#define SEQ    2048
#define DMODEL 512
#define DINNER 2048
#define NHEAD  8
#define DHEAD  64
#define NLAYER 6
#define VOCAB  512
#define MROWS  (BATCH*SEQ)   // 4096 rows

// split-K attention: 8 chunks of 4 steps; packed slots (144 per (b,h) group)
#define NSLOT_G 144
#define NSLOTS  (16 * NSLOT_G)   // 2304

typedef unsigned short bf16u;
typedef __attribute__((ext_vector_type(8))) short s8frag;   // 8 bf16 (4 VGPRs)
typedef __attribute__((ext_vector_type(4))) float f4frag;   // 4 fp32 acc

__device__ __forceinline__ float b2f(bf16u u) {
  union { unsigned int i; float f; } v; v.i = ((unsigned int)u) << 16; return v.f;
}
__device__ __forceinline__ bf16u f2b(float f) {
  union { float f; unsigned int i; } v; v.f = f;
  unsigned int x = v.i;
  return (bf16u)((x + 0x7fffu + ((x >> 16) & 1u)) >> 16);
}
__device__ __forceinline__ unsigned int pack2(float a, float b) {
  return (unsigned int)f2b(a) | ((unsigned int)f2b(b) << 16);
}

// async global->LDS, 16B per lane. LDS dest must be wave-uniform base +
// lane*16 (we pass per-lane ptrs that satisfy exactly that).
__device__ __forceinline__ void gld16(const bf16u* g, bf16u* l) {
  __builtin_amdgcn_global_load_lds(
      (const __attribute__((address_space(1))) unsigned int*)g,
      (__attribute__((address_space(3))) unsigned int*)l,
      16, 0, 0);
}

// DPP row-rotate (within 16-lane row) — VALU-pipe lane exchange, not LDS.
#define DPP_ROR(dst, src, N)                                              \
  dst = __int_as_float(__builtin_amdgcn_update_dpp(                       \
      0, __float_as_int(src), 0x120 + (N), 0xF, 0xF, true))

// packed slot offset: Sum_{j<it} ((j>>2)+1) = it + 2a(a-1) + a*b, a=it>>2,b=it&3
__device__ __forceinline__ int slot_off(int it) {
  int a = it >> 2, b = it & 3;
  return it + 2 * a * (a - 1) + a * b;
}

// ---------------------------------------------------------------------------
// All-layer weight transpose + bf16: dst[N][K] = src[K][N]. One launch.
// blocks: 6 layers x 768 (q64|k64|v64|o64|W1 256|W2 256) + 64 (fc) = 4672.
// ---------------------------------------------------------------------------
__global__ __launch_bounds__(256) void wt_all_kernel(
    const float* __restrict__ Wq, const float* __restrict__ Wk,
    const float* __restrict__ Wv, const float* __restrict__ Wo,
    const float* __restrict__ W1, const float* __restrict__ W2,
    const float* __restrict__ fcW,
    bf16u* __restrict__ qkvT, bf16u* __restrict__ oT,
    bf16u* __restrict__ w1T, bf16u* __restrict__ w2T, bf16u* __restrict__ fcT)
{
  int bid = blockIdx.x;
  const float* src; bf16u* dst; int N, K, kt, nt;
  if (bid < 6 * 768) {
    int L = bid / 768, t = bid - L * 768;
    if (t < 256) {
      int mat = t >> 6, tt = t & 63;
      const float* s4[4] = {Wq, Wk, Wv, Wo};
      src = s4[mat] + (size_t)L * DMODEL * DMODEL;
      dst = (mat < 3) ? (qkvT + (size_t)L * 786432 + (size_t)mat * 262144)
                      : (oT + (size_t)L * 262144);
      K = DMODEL; N = DMODEL; kt = tt >> 3; nt = tt & 7;
    } else if (t < 512) {
      int tt = t - 256;
      src = W1 + (size_t)L * DMODEL * DINNER; dst = w1T + (size_t)L * 1048576;
      K = DMODEL; N = DINNER; kt = tt >> 5; nt = tt & 31;
    } else {
      int tt = t - 512;
      src = W2 + (size_t)L * DINNER * DMODEL; dst = w2T + (size_t)L * 1048576;
      K = DINNER; N = DMODEL; kt = tt >> 3; nt = tt & 7;
    }
  } else {
    int tt = bid - 6 * 768;
    src = fcW; dst = fcT;
    K = DMODEL; N = VOCAB; kt = tt >> 3; nt = tt & 7;
  }
  __shared__ bf16u Ls[64][66];
  int tid = threadIdx.x;
  int c = tid & 63, r4 = tid >> 6;
#pragma unroll
  for (int i = 0; i < 16; i++) {
    int r = i * 4 + r4;
    Ls[r][c] = f2b(src[(size_t)(kt * 64 + r) * N + nt * 64 + c]);
  }
  __syncthreads();
#pragma unroll
  for (int i = 0; i < 16; i++) {
    int rr = i * 4 + r4;
    dst[(size_t)(nt * 64 + rr) * K + kt * 64 + c] = Ls[c][rr];
  }
}

// ---------------------------------------------------------------------------
// V transpose (bf16): vb[(b,i)][h*64+d] -> vbt[(b*8+h)*64+d][i]. 512 blocks.
// ---------------------------------------------------------------------------
__global__ __launch_bounds__(256) void vt_kernel(
    const bf16u* __restrict__ vb, bf16u* __restrict__ vbt)
{
  int bid = blockIdx.x;
  int b = bid >> 8, t = bid & 255;
  int it = t >> 3, h = t & 7;
  __shared__ bf16u Ls[64][66];
  int tid = threadIdx.x;
  int c = tid & 63, r4 = tid >> 6;
#pragma unroll
  for (int i = 0; i < 16; i++) {
    int r = i * 4 + r4;
    Ls[r][c] = vb[(size_t)(b * SEQ + it * 64 + r) * DMODEL + h * DHEAD + c];
  }
  __syncthreads();
#pragma unroll
  for (int i = 0; i < 16; i++) {
    int rr = i * 4 + r4;
    vbt[(size_t)((b * 8 + h) * DHEAD + rr) * SEQ + it * 64 + c] = Ls[c][rr];
  }
}

// ---------------------------------------------------------------------------
// MFMA GEMM, RB m-tiles/wave (4 -> 128x128, 1 -> 32x128), BK=64.
// BK=32 had 16 barrier-pairs per K=512 (the ~20% drain tax); BK=64 halves
// them. Linear BK=64 tiles would 16-way bank-conflict (128B row stride), so
// per rule #21: LINEAR gld16 dest + INVERSE-SWIZZLED global source + swizzled
// read. Involution: phys_oct = global_oct ^ (row&7). Read spreads 16 lanes
// over 8 octets x 4 banks = 32 banks, 2 lanes/bank (free, m136).
// XCD-chunked tile swizzle retained (validated R8: -80us).
// modes: 0 +bias->bf16 ; 1 +bias+Rb ; 2 relu+chord ; 3 +bias->fp32 ;
// 4 fused-QKV routing.
// ---------------------------------------------------------------------------
template <int RB>
__global__ __launch_bounds__(256) void mgemm(
    const bf16u* __restrict__ A, const bf16u* __restrict__ Wt,
    const float* __restrict__ b0, const float* __restrict__ b1,
    const float* __restrict__ b2, const bf16u* __restrict__ Rb,
    float* __restrict__ Cf, bf16u* __restrict__ Cb,
    int M, int N, int K, int mode,
    const float* __restrict__ ttc, const float* __restrict__ ttcW,
    const float* __restrict__ ttcb)
{
  __shared__ bf16u Ab[RB * 32][64];
  __shared__ bf16u Bb[128][64];
  const int tid = threadIdx.x;
  const int lane = tid & 63, wave = tid >> 6;
  const int quad = lane >> 4, l16 = lane & 15;
  const int wm = wave >> 1, wn = wave & 1;

  // XCD-chunked swizzle (bijective; nwg % 8 == 0 for all launches)
  const int nwg = gridDim.x * gridDim.y;
  const int lin = blockIdx.y * gridDim.x + blockIdx.x;
  const int swz = (lin & 7) * (nwg >> 3) + (lin >> 3);
  const int bx = swz % gridDim.x, by = swz / gridDim.x;
  const int row0 = bx * (RB * 32), col0 = by * 128;

  f4frag acc[RB][4];
#pragma unroll
  for (int i = 0; i < RB; i++)
#pragma unroll
    for (int j = 0; j < 4; j++) acc[i][j] = (f4frag){0.f, 0.f, 0.f, 0.f};

  for (int k0 = 0; k0 < K; k0 += 64) {
    if (k0) __syncthreads();
    // A tile: RB*32 rows x 8 oct-chunks; source octet = phys ^ (row&7)
#pragma unroll
    for (int i = 0; i < RB; i++) {
      int c = i * 256 + tid;
      int r = c >> 3, goct = (c & 7) ^ (r & 7);
      gld16(&A[(size_t)(row0 + r) * K + k0 + goct * 8], &Ab[0][0] + c * 8);
    }
    // B tile: 128 rows x 8 oct-chunks
#pragma unroll
    for (int i = 0; i < 4; i++) {
      int c = i * 256 + tid;
      int r = c >> 3, goct = (c & 7) ^ (r & 7);
      gld16(&Wt[(size_t)(col0 + r) * K + k0 + goct * 8], &Bb[0][0] + c * 8);
    }
    __syncthreads();   // compiler drains vmcnt before s_barrier
#pragma unroll
    for (int kk = 0; kk < 2; kk++) {
      s8frag af[RB], bfr[4];
#pragma unroll
      for (int t = 0; t < RB; t++) {
        int ar = wm * (RB * 16) + t * 16 + l16;
        int aoct = ((kk << 2) | quad) ^ (ar & 7);
        af[t] = *(const s8frag*)&Ab[ar][aoct * 8];
      }
#pragma unroll
      for (int t = 0; t < 4; t++) {
        int br = wn * 64 + t * 16 + l16;
        int boct = ((kk << 2) | quad) ^ (br & 7);
        bfr[t] = *(const s8frag*)&Bb[br][boct * 8];
      }
#pragma unroll
      for (int mt = 0; mt < RB; mt++)
#pragma unroll
        for (int nt = 0; nt < 4; nt++)
          acc[mt][nt] = __builtin_amdgcn_mfma_f32_16x16x32_bf16(
              af[mt], bfr[nt], acc[mt][nt], 0, 0, 0);
    }
  }

#pragma unroll
  for (int mt = 0; mt < RB; mt++) {
#pragma unroll
    for (int r = 0; r < 4; r++) {
      int m = row0 + wm * (RB * 16) + mt * 16 + quad * 4 + r;
      float tval = 0.f;
      if (mode == 2) {
        int bb = m >> 11, s = m & (SEQ - 1);
        int sp = (s < NCOND) ? 0 : (s - NCOND);
        tval = 8.0f - ttc[bb * S_TOK + sp];
      }
#pragma unroll
      for (int nt = 0; nt < 4; nt++) {
        int n = col0 + wn * 64 + nt * 16 + l16;
        if (mode == 4) {
          int sel = n >> 9, nn = n & 511;
          float bv = (sel == 0) ? b0[nn] : ((sel == 1) ? b1[nn] : b2[nn]);
          Cb[(size_t)sel * MROWS * DMODEL + (size_t)m * DMODEL + nn]
              = f2b(acc[mt][nt][r] + bv);
        } else {
          float v = acc[mt][nt][r] + b0[n];
          if (mode == 1)      v += b2f(Rb[(size_t)m * N + n]);
          else if (mode == 2) v = fmaxf(v, 0.f) + tval * ttcW[n] + ttcb[n];
          if (mode == 3) Cf[(size_t)m * N + n] = v;
          else           Cb[(size_t)m * N + n] = f2b(v);
        }
      }
    }
  }
}

// ---------------------------------------------------------------------------
// LayerNorm over D=512 (bf16 in -> bf16 out), one row per block.
// ---------------------------------------------------------------------------
__global__ __launch_bounds__(256) void ln_kernel(
    const bf16u* __restrict__ X, const float* __restrict__ g,
    const float* __restrict__ bta, bf16u* __restrict__ Y)
{
  int row = blockIdx.x, tid = threadIdx.x;
  unsigned int pr = *(const unsigned int*)&X[(size_t)row * DMODEL + 2 * tid];
  float x0 = b2f((bf16u)(pr & 0xffff)), x1 = b2f((bf16u)(pr >> 16));
  __shared__ float red[8];
  int wv = tid >> 6, ln = tid & 63;
  float s = x0 + x1;
  for (int off = 32; off; off >>= 1) s += __shfl_xor(s, off);
  if (ln == 0) red[wv] = s;
  __syncthreads();
  float mu = (red[0] + red[1] + red[2] + red[3]) * (1.0f / DMODEL);
  float d0 = x0 - mu, d1 = x1 - mu;
  float vs = d0 * d0 + d1 * d1;
  for (int off = 32; off; off >>= 1) vs += __shfl_xor(vs, off);
  if (ln == 0) red[4 + wv] = vs;
  __syncthreads();
  float var = (red[4] + red[5] + red[6] + red[7]) * (1.0f / DMODEL);
  float rstd = rsqrtf(var + 1e-6f);
  float y0 = d0 * rstd * g[2 * tid]     + bta[2 * tid];
  float y1 = d1 * rstd * g[2 * tid + 1] + bta[2 * tid + 1];
  *(unsigned int*)&Y[(size_t)row * DMODEL + 2 * tid] = pack2(y0, y1);
}

// ---------------------------------------------------------------------------
__global__ __launch_bounds__(256) void tok_embed_kernel(
    const int* __restrict__ toks, const float* __restrict__ emb,
    const float* __restrict__ pos, bf16u* __restrict__ xb)
{
  int sp = blockIdx.x, b = blockIdx.y;
  int s = sp + NCOND;
  int tok = toks[b * S_TOK + sp];
  const float* er = emb + (size_t)tok * DMODEL;
  const float* pr = pos + (size_t)s * DMODEL;
  size_t ro = ((size_t)b * SEQ + s) * DMODEL;
  int d = threadIdx.x * 2;
  float v0 = er[d]     * 22.62741699796952f + pr[d];
  float v1 = er[d + 1] * 22.62741699796952f + pr[d + 1];
  *(unsigned int*)&xb[ro + d] = pack2(v0, v1);
}

// ---------------------------------------------------------------------------
__global__ __launch_bounds__(256) void cond_embed_kernel(
    const float* __restrict__ conds, const float* __restrict__ W1,
    const float* __restrict__ b1, const float* __restrict__ W2w,
    const float* __restrict__ b2, const float* __restrict__ nullc,
    const float* __restrict__ pos, bf16u* __restrict__ xb)
{
  int ci = blockIdx.x, b = blockIdx.y, tid = threadIdx.x;
  float c = conds[b * NCOND + ci];
  bool cn = isnan(c);
  float cm = cn ? 0.f : c;
  __shared__ float h1[DMODEL / 2];
  h1[tid] = fmaxf(cm * W1[ci * (DMODEL/2) + tid] + b1[ci * (DMODEL/2) + tid], 0.f);
  __syncthreads();
  for (int d = tid; d < DMODEL; d += 256) {
    float acc = b2[ci * DMODEL + d];
    for (int i = 0; i < DMODEL / 2; i++)
      acc = fmaf(h1[i], W2w[((size_t)ci * (DMODEL/2) + i) * DMODEL + d], acc);
    float ce = cn ? nullc[ci * DMODEL + d] : acc;
    xb[((size_t)b * SEQ + ci) * DMODEL + d] = f2b(ce + pos[(size_t)ci * DMODEL + d]);
  }
}

// ---------------------------------------------------------------------------
// E (fp32, all 6 layers) -> bf16.
// ---------------------------------------------------------------------------
__global__ __launch_bounds__(256) void e_conv_kernel(
    const float* __restrict__ E, bf16u* __restrict__ Eb)
{
  int i = (blockIdx.x * 256 + threadIdx.x) * 4;
  float4 v = *(const float4*)&E[i];
  ushort4 o;
  o.x = f2b(v.x); o.y = f2b(v.y); o.z = f2b(v.z); o.w = f2b(v.w);
  *(ushort4*)&Eb[i] = o;
}

// ---------------------------------------------------------------------------
// Split-K MFMA flash attention, 8 chunks x <=4 steps. COMPACT grid (2304 =
// exactly the working blocks; was 4096 with 1792 dead dispatches). Rank ->
// (it,c) via inverse of slot_off (scalar loop, once per block). XCD
// clustering (2 g per XCD) + LPT (heavy it first per XCD stream) preserved.
// ---------------------------------------------------------------------------
#define PS_SWZ(row) ((((row) >> 2) & 7) << 3)

__global__ __launch_bounds__(256) void attn_part(
    const bf16u* __restrict__ Q, const bf16u* __restrict__ K,
    const bf16u* __restrict__ Vt_g, const bf16u* __restrict__ Eb16,
    const int* __restrict__ toks, bf16u* __restrict__ pacc,
    float* __restrict__ pstat)
{
  const int d = blockIdx.x;
  const int xcd = d & 7, rank = d >> 3;        // rank in [0, 288)
  const int g = xcd * 2 + (rank >= NSLOT_G);   // (b,h) group, clustered per XCD
  int rem = (rank >= NSLOT_G) ? rank - NSLOT_G : rank;
  int it = 31;
  for (;;) { int ch = (it >> 2) + 1; if (rem < ch) break; rem -= ch; --it; }
  const int c = rem;                           // 4c <= it by construction
  const int slot = g * NSLOT_G + slot_off(it) + c;   // packed partial index
  const int b = g >> 3, h = g & 7;
  const int i0 = it * 64;

  __shared__ bf16u Kb[64][72];          // K tile; becomes P after mid barrier
  __shared__ bf16u Vt[64][72];
  __shared__ bf16u Ebs[128][72];
  __shared__ float padv[64];
  bf16u (*Ps)[72] = Kb;                 // alias: disjoint lifetimes per step

  const int tid  = threadIdx.x;
  const int lane = tid & 63;
  const int wave = tid >> 6;
  const int quad = lane >> 4;
  const int l16  = lane & 15;

  const bf16u* qr = Q + ((size_t)(b * SEQ + i0 + wave * 16 + l16)) * DMODEL + h * DHEAD;
  s8frag q0 = *(const s8frag*)&qr[quad * 8];
  s8frag q1 = *(const s8frag*)&qr[32 + quad * 8];

  float m_run[4], l_run[4];
  f4frag acc[4];
#pragma unroll
  for (int r = 0; r < 4; r++) { m_run[r] = -1e30f; l_run[r] = 0.f; }
#pragma unroll
  for (int dt = 0; dt < 4; dt++) acc[dt] = (f4frag){0.f, 0.f, 0.f, 0.f};

  const int js0 = 4 * c;
  const int jsE = min(4 * c + 4, it + 1);
  const size_t vtbase = (size_t)(g * DHEAD) * SEQ;

  for (int js = js0; js < jsE; js++) {
    const int j0 = js * 64;
    const int m0 = 1984 - i0 + j0;   // E row of band col 0
    __syncthreads();

    // K tile (2 x uint4 / thread)
#pragma unroll
    for (int e = 0; e < 2; e++) {
      int cc = e * 256 + tid;
      int jr = cc >> 3, doff = (cc & 7) * 8;
      *(uint4*)&Kb[jr][doff] =
          *(const uint4*)&K[((size_t)(b * SEQ + j0 + jr)) * DMODEL + h * DHEAD + doff];
    }
    // V^T tile from pre-transposed global (2 x uint4 / thread)
#pragma unroll
    for (int e = 0; e < 2; e++) {
      int cc = e * 256 + tid;
      int dr = cc >> 3, joff = (cc & 7) * 8;
      *(uint4*)&Vt[dr][joff] =
          *(const uint4*)&Vt_g[vtbase + (size_t)dr * SEQ + j0 + joff];
    }
    // E ring: first step fill 128 rows, then 64 new rows
    if (js == js0) {
#pragma unroll
      for (int e = 0; e < 4; e++) {
        int cc = e * 256 + tid;
        int er = cc >> 3, doff = (cc & 7) * 8;
        int m = m0 + er; int row = m > SEQ - 1 ? SEQ - 1 : m;
        *(uint4*)&Ebs[m & 127][doff] = *(const uint4*)&Eb16[(size_t)row * DHEAD + doff];
      }
    } else {
#pragma unroll
      for (int e = 0; e < 2; e++) {
        int cc = e * 256 + tid;
        int er = 64 + (cc >> 3), doff = (cc & 7) * 8;
        int m = m0 + er; int row = m > SEQ - 1 ? SEQ - 1 : m;
        *(uint4*)&Ebs[m & 127][doff] = *(const uint4*)&Eb16[(size_t)row * DHEAD + doff];
      }
    }
    if (tid < 64) {
      int j = j0 + tid;
      bool pad = (j >= NCOND) && (toks[b * S_TOK + j - NCOND] == 0);
      padv[tid] = pad ? -1e30f : 0.f;
    }
    __syncthreads();

    // QK^T (reads Kb)
    f4frag sc[4];
#pragma unroll
    for (int nt = 0; nt < 4; nt++) {
      s8frag k0 = *(const s8frag*)&Kb[nt * 16 + l16][quad * 8];
      s8frag k1 = *(const s8frag*)&Kb[nt * 16 + l16][32 + quad * 8];
      f4frag cc = (f4frag){0.f, 0.f, 0.f, 0.f};
      cc = __builtin_amdgcn_mfma_f32_16x16x32_bf16(q0, k0, cc, 0, 0, 0);
      cc = __builtin_amdgcn_mfma_f32_16x16x32_bf16(q1, k1, cc, 0, 0, 0);
      sc[nt] = cc;
    }

    // QE: 5 frags covering band cols [(3-wave)*16, (8-wave)*16)  (reads Ebs)
    f4frag qef[5];
#pragma unroll
    for (int f = 0; f < 5; f++) {
      int ct = f + 3 - wave;
      int m = m0 + ct * 16 + l16;
      const bf16u* erow = &Ebs[m & 127][0];
      s8frag e0 = *(const s8frag*)&erow[quad * 8];
      s8frag e1 = *(const s8frag*)&erow[32 + quad * 8];
      f4frag cc = (f4frag){0.f, 0.f, 0.f, 0.f};
      cc = __builtin_amdgcn_mfma_f32_16x16x32_bf16(q0, e0, cc, 0, 0, 0);
      cc = __builtin_amdgcn_mfma_f32_16x16x32_bf16(q1, e1, cc, 0, 0, 0);
      qef[f] = cc;
    }

    // All Kb/Ebs reads are drained by this barrier; Kb becomes the P buffer.
    __syncthreads();

    float pvv[4];
#pragma unroll
    for (int nt = 0; nt < 4; nt++) pvv[nt] = padv[nt * 16 + l16];

    // scores + online softmax; QE gathered by ONE shuffle (select at source).
    float s[4][4], mx[4];
#pragma unroll
    for (int r = 0; r < 4; r++) {
      int rloc = wave * 16 + quad * 4 + r;
      int ig = i0 + rloc;
      int t2 = quad * 4 + r;
      int v = 63 - 16 * wave + l16 - t2;
      int srcl = (lane & 48) | (v & 15);
      bool hiSrc = (l16 < 15 - t2);    // target hi <=> this at source lane
#pragma unroll
      for (int nt = 0; nt < 4; nt++) {
        float pre = hiSrc ? qef[nt + 1][r] : qef[nt][r];
        float qe = __shfl(pre, srcl);
        int jl = nt * 16 + l16;
        float sv = (sc[nt][r] + qe) * 0.125f + pvv[nt];
        if (j0 + jl > ig) sv = -1e30f;
        s[nt][r] = sv;
      }
      float m = fmaxf(fmaxf(s[0][r], s[1][r]), fmaxf(s[2][r], s[3][r]));
      float tr;
      DPP_ROR(tr, m, 1); m = fmaxf(m, tr);
      DPP_ROR(tr, m, 2); m = fmaxf(m, tr);
      DPP_ROR(tr, m, 4); m = fmaxf(m, tr);
      DPP_ROR(tr, m, 8); m = fmaxf(m, tr);
      mx[r] = m;
    }
    float alpha[4];
#pragma unroll
    for (int r = 0; r < 4; r++) {
      float m_new = fmaxf(m_run[r], mx[r]);
      alpha[r] = __expf(m_run[r] - m_new);
      float psum = 0.f;
      int rloc = wave * 16 + quad * 4 + r;
#pragma unroll
      for (int nt = 0; nt < 4; nt++) {
        float p = __expf(s[nt][r] - m_new);
        Ps[rloc][(nt * 16 + l16) ^ PS_SWZ(rloc)] = f2b(p);
        psum += p;
      }
      float tr;
      DPP_ROR(tr, psum, 1); psum += tr;
      DPP_ROR(tr, psum, 2); psum += tr;
      DPP_ROR(tr, psum, 4); psum += tr;
      DPP_ROR(tr, psum, 8); psum += tr;
      l_run[r] = l_run[r] * alpha[r] + psum;
      m_run[r] = m_new;
    }
#pragma unroll
    for (int dt = 0; dt < 4; dt++)
#pragma unroll
      for (int r = 0; r < 4; r++) acc[dt][r] *= alpha[r];

    // P @ V  (Ps rows are wave-local; swizzled reads match swizzled writes)
    {
      int prow = wave * 16 + l16;
      int psw = PS_SWZ(prow);
      s8frag p0 = *(const s8frag*)&Ps[prow][(quad * 8) ^ psw];
      s8frag p1 = *(const s8frag*)&Ps[prow][(32 + quad * 8) ^ psw];
#pragma unroll
      for (int dt = 0; dt < 4; dt++) {
        s8frag v0 = *(const s8frag*)&Vt[dt * 16 + l16][quad * 8];
        s8frag v1 = *(const s8frag*)&Vt[dt * 16 + l16][32 + quad * 8];
        acc[dt] = __builtin_amdgcn_mfma_f32_16x16x32_bf16(p0, v0, acc[dt], 0, 0, 0);
        acc[dt] = __builtin_amdgcn_mfma_f32_16x16x32_bf16(p1, v1, acc[dt], 0, 0, 0);
      }
    }
  }

  // write partials (packed slot)
#pragma unroll
  for (int r = 0; r < 4; r++) {
    int rloc = wave * 16 + quad * 4 + r;
    if (l16 == 0) {
      pstat[(size_t)slot * 128 + rloc]      = m_run[r];
      pstat[(size_t)slot * 128 + 64 + rloc] = l_run[r];
    }
#pragma unroll
    for (int dt = 0; dt < 4; dt++)
      pacc[(size_t)slot * 4096 + rloc * 64 + dt * 16 + l16] = f2b(acc[dt][r]);
  }
}

// ---------------------------------------------------------------------------
// Merge <=8 chunk partials per (b,h,q-tile); write O (bf16) into qb.
// ---------------------------------------------------------------------------
__global__ __launch_bounds__(256) void attn_combine(
    const bf16u* __restrict__ pacc, const float* __restrict__ pstat,
    bf16u* __restrict__ O)
{
  int bid = blockIdx.x;             // g*32 + it
  int g = bid >> 5, it = bid & 31;
  int b = g >> 3, h = g & 7;
  int i0 = it * 64;
  int nc = (it >> 2) + 1;           // chunks of 4 steps
  int base = g * NSLOT_G + slot_off(it);
  int tid = threadIdx.x;
  int row = tid >> 2, ql = tid & 3;

  float m_tot = -1e30f;
  float mc[8], lc[8];
#pragma unroll
  for (int c = 0; c < 8; c++) {
    if (c < nc) {
      size_t pb = (size_t)(base + c) * 128;
      mc[c] = pstat[pb + row];
      lc[c] = pstat[pb + 64 + row];
      m_tot = fmaxf(m_tot, mc[c]);
    }
  }
  float l_tot = 0.f, w[8];
#pragma unroll
  for (int c = 0; c < 8; c++) {
    if (c < nc) { w[c] = __expf(mc[c] - m_tot); l_tot += w[c] * lc[c]; }
    else w[c] = 0.f;
  }
  float inv = 1.0f / l_tot;

  float out[16];
#pragma unroll
  for (int k = 0; k < 16; k++) out[k] = 0.f;
#pragma unroll
  for (int c = 0; c < 8; c++) {
    if (c >= nc) break;
    const bf16u* pa = pacc + (size_t)(base + c) * 4096 + row * 64 + ql * 16;
#pragma unroll
    for (int k = 0; k < 16; k++) out[k] += w[c] * b2f(pa[k]);
  }
  bf16u* ob = O + ((size_t)(b * SEQ + i0 + row)) * DMODEL + h * DHEAD + ql * 16;
#pragma unroll
  for (int k = 0; k < 16; k++) ob[k] = f2b(out[k] * inv);
}

// ---------------------------------------------------------------------------
extern "C" void kernel_launch(void* const* d_in, const int* in_sizes, int n_in,
                              void* d_out, int out_size, void* d_ws, size_t ws_size,
                              hipStream_t stream) {
  const int*   toks  = (const int*)  d_in[0];
  const float* conds = (const float*)d_in[1];
  const float* ttc   = (const float*)d_in[2];
  const float* emb   = (const float*)d_in[3];
  const float* pos   = (const float*)d_in[4];
  const float* cW1   = (const float*)d_in[5];
  const float* cb1   = (const float*)d_in[6];
  const float* cW2   = (const float*)d_in[7];
  const float* cb2   = (const float*)d_in[8];
  const float* nullc = (const float*)d_in[9];
  const float* ttcW  = (const float*)d_in[10];
  const float* ttcb  = (const float*)d_in[11];
  const float* Wq    = (const float*)d_in[12];
  const float* Wk    = (const float*)d_in[13];
  const float* Wv    = (const float*)d_in[14];
  const float* Wo    = (const float*)d_in[15];
  const float* bq    = (const float*)d_in[16];
  const float* bk    = (const float*)d_in[17];
  const float* bv    = (const float*)d_in[18];
  const float* bo    = (const float*)d_in[19];
  const float* E     = (const float*)d_in[20];
  const float* fW1   = (const float*)d_in[21];
  const float* fb1   = (const float*)d_in[22];
  const float* fW2   = (const float*)d_in[23];
  const float* fb2   = (const float*)d_in[24];
  const float* ln1g  = (const float*)d_in[25];
  const float* ln1b  = (const float*)d_in[26];
  const float* ln2g  = (const float*)d_in[27];
  const float* ln2b  = (const float*)d_in[28];
  const float* fcW   = (const float*)d_in[29];
  const float* fcb   = (const float*)d_in[30];

  const size_t MB1 = 1024 * 1024;
  const size_t MD = (size_t)MROWS * DMODEL;
  char* p = (char*)d_ws;
  bf16u* xb    = (bf16u*)p; p += 4 * MB1;
  bf16u* qkvb  = (bf16u*)p; p += 12 * MB1;   // qb | kb | vb
  bf16u* hidb  = (bf16u*)p; p += 16 * MB1;   // FFN hidden
  float* pstat_old = (float*)p; p += 1 * MB1; // (unused; kept for layout)
  bf16u* vbt   = (bf16u*)p; p += 4 * MB1;    // V transposed
  bf16u* ebf   = (bf16u*)p; p += 1536 * 1024;   // E bf16, 6 layers
  bf16u* WqkvT = (bf16u*)p; p += 9 * MB1;
  bf16u* WoT   = (bf16u*)p; p += 3 * MB1;
  bf16u* W1T   = (bf16u*)p; p += 12 * MB1;
  bf16u* W2T   = (bf16u*)p; p += 12 * MB1;
  bf16u* fcT   = (bf16u*)p; p += 512 * 1024;    // total 75 MB
  (void)pstat_old;
  bf16u* qb = qkvb;
  bf16u* kb = qkvb + MD;        // out1b aliases kb (disjoint lifetimes)
  bf16u* vb = qkvb + 2 * MD;    // t1b aliases vb (disjoint lifetimes)
  bf16u* out1b = kb;
  bf16u* t1b   = vb;
  // Partials live in the contiguous vb+hidb span (20MB): vb is dead after
  // vt_kernel; hidb's FFN lifetime starts after attn_combine.
  // pacc 2304*8KB = 18MB, pstat 2304*512B = 1.15MB -> 19.15MB <= 20MB.
  bf16u* pacc  = vb;
  float* pstat = (float*)(pacc + (size_t)NSLOTS * 4096);

  // ---- setup: embeds + all-layer weight transposes + E conversion ----
  cond_embed_kernel<<<dim3(NCOND, BATCH), 256, 0, stream>>>(
      conds, cW1, cb1, cW2, cb2, nullc, pos, xb);
  tok_embed_kernel<<<dim3(S_TOK, BATCH), 256, 0, stream>>>(toks, emb, pos, xb);
  wt_all_kernel<<<6 * 768 + 64, 256, 0, stream>>>(Wq, Wk, Wv, Wo, fW1, fW2, fcW,
      WqkvT, WoT, W1T, W2T, fcT);
  e_conv_kernel<<<(NLAYER * SEQ * DHEAD) / 1024, 256, 0, stream>>>(E, ebf);

  dim3 gQKV(MROWS / 128, 1536 / 128);      // (32,12)
  dim3 gFF1(MROWS / 128, DINNER / 128);    // (32,16)
  dim3 gN512(MROWS / 32, DMODEL / 128);    // (128,4): 512 blocks, RB=1

  for (int l = 0; l < NLAYER; l++) {
    // fused QKV
    mgemm<4><<<gQKV, 256, 0, stream>>>(xb, WqkvT + (size_t)l * 786432,
        bq + l * DMODEL, bk + l * DMODEL, bv + l * DMODEL, nullptr,
        nullptr, qkvb, MROWS, 1536, DMODEL, 4, nullptr, nullptr, nullptr);

    vt_kernel<<<512, 256, 0, stream>>>(vb, vbt);
    attn_part<<<NSLOTS, 256, 0, stream>>>(qb, kb, vbt,
        ebf + (size_t)l * SEQ * DHEAD, toks, pacc, pstat);
    attn_combine<<<512, 256, 0, stream>>>(pacc, pstat, qb);

    // t1 = attn @ Wo + bo + x
    mgemm<1><<<gN512, 256, 0, stream>>>(qb, WoT + (size_t)l * 262144,
        bo + l * DMODEL, nullptr, nullptr, xb,
        nullptr, t1b, MROWS, DMODEL, DMODEL, 1, nullptr, nullptr, nullptr);
    ln_kernel<<<MROWS, 256, 0, stream>>>(t1b, ln1g + l * DMODEL, ln1b + l * DMODEL,
        out1b);

    // hid = relu(out1 @ W1 + b1) + chord
    mgemm<4><<<gFF1, 256, 0, stream>>>(out1b, W1T + (size_t)l * 1048576,
        fb1 + l * DINNER, nullptr, nullptr, nullptr,
        nullptr, hidb, MROWS, DINNER, DMODEL, 2, ttc, ttcW, ttcb);
    // t1 = hid @ W2 + b2 + out1
    mgemm<1><<<gN512, 256, 0, stream>>>(hidb, W2T + (size_t)l * 1048576,
        fb2 + l * DMODEL, nullptr, nullptr, out1b,
        nullptr, t1b, MROWS, DMODEL, DINNER, 1, nullptr, nullptr, nullptr);
    ln_kernel<<<MROWS, 256, 0, stream>>>(t1b, ln2g + l * DMODEL, ln2b + l * DMODEL,
        xb);
  }

  // logits = x @ fc_W + fc_b (fp32 out)
  mgemm<1><<<gN512, 256, 0, stream>>>(xb, fcT,
      fcb, nullptr, nullptr, nullptr,
      (float*)d_out, nullptr, MROWS, VOCAB, DMODEL, 3, nullptr, nullptr, nullptr);
}

// Round 11
// 1128.267 us; speedup vs baseline: 1.3969x; 1.0869x over previous
//
#include <hip/hip_runtime.h>
#include <hip/hip_bf16.h>
#include <math.h>

// ---- problem constants ----
#define BATCH  2
#define S_TOK  2046
#define NCOND  2
#define SEQ    2048
#define DMODEL 512
#define DINNER 2048
#define NHEAD  8
#define DHEAD  64
#define NLAYER 6
#define VOCAB  512
#define MROWS  (BATCH*SEQ)   // 4096 rows

// split-K attention: 8 chunks of 4 steps; packed slots (144 per (b,h) group)
#define NSLOT_G 144
#define NSLOTS  (16 * NSLOT_G)   // 2304

typedef unsigned short bf16u;
typedef __attribute__((ext_vector_type(8))) short s8frag;   // 8 bf16 (4 VGPRs)
typedef __attribute__((ext_vector_type(4))) float f4frag;   // 4 fp32 acc

__device__ __forceinline__ float b2f(bf16u u) {
  union { unsigned int i; float f; } v; v.i = ((unsigned int)u) << 16; return v.f;
}
__device__ __forceinline__ bf16u f2b(float f) {
  union { float f; unsigned int i; } v; v.f = f;
  unsigned int x = v.i;
  return (bf16u)((x + 0x7fffu + ((x >> 16) & 1u)) >> 16);
}
__device__ __forceinline__ unsigned int pack2(float a, float b) {
  return (unsigned int)f2b(a) | ((unsigned int)f2b(b) << 16);
}

// async global->LDS, 16B per lane. LDS dest must be wave-uniform base +
// lane*16 (we pass per-lane ptrs that satisfy exactly that).
__device__ __forceinline__ void gld16(const bf16u* g, bf16u* l) {
  __builtin_amdgcn_global_load_lds(
      (const __attribute__((address_space(1))) unsigned int*)g,
      (__attribute__((address_space(3))) unsigned int*)l,
      16, 0, 0);
}

// DPP row-rotate (within 16-lane row) — VALU-pipe lane exchange, not LDS.
#define DPP_ROR(dst, src, N)                                              \
  dst = __int_as_float(__builtin_amdgcn_update_dpp(                       \
      0, __float_as_int(src), 0x120 + (N), 0xF, 0xF, true))

// packed slot offset: Sum_{j<it} ((j>>2)+1) = it + 2a(a-1) + a*b, a=it>>2,b=it&3
__device__ __forceinline__ int slot_off(int it) {
  int a = it >> 2, b = it & 3;
  return it + 2 * a * (a - 1) + a * b;
}

// ---------------------------------------------------------------------------
// All-layer weight transpose + bf16: dst[N][K] = src[K][N]. One launch.
// blocks: 6 layers x 768 (q64|k64|v64|o64|W1 256|W2 256) + 64 (fc) = 4672.
// ---------------------------------------------------------------------------
__global__ __launch_bounds__(256) void wt_all_kernel(
    const float* __restrict__ Wq, const float* __restrict__ Wk,
    const float* __restrict__ Wv, const float* __restrict__ Wo,
    const float* __restrict__ W1, const float* __restrict__ W2,
    const float* __restrict__ fcW,
    bf16u* __restrict__ qkvT, bf16u* __restrict__ oT,
    bf16u* __restrict__ w1T, bf16u* __restrict__ w2T, bf16u* __restrict__ fcT)
{
  int bid = blockIdx.x;
  const float* src; bf16u* dst; int N, K, kt, nt;
  if (bid < 6 * 768) {
    int L = bid / 768, t = bid - L * 768;
    if (t < 256) {
      int mat = t >> 6, tt = t & 63;
      const float* s4[4] = {Wq, Wk, Wv, Wo};
      src = s4[mat] + (size_t)L * DMODEL * DMODEL;
      dst = (mat < 3) ? (qkvT + (size_t)L * 786432 + (size_t)mat * 262144)
                      : (oT + (size_t)L * 262144);
      K = DMODEL; N = DMODEL; kt = tt >> 3; nt = tt & 7;
    } else if (t < 512) {
      int tt = t - 256;
      src = W1 + (size_t)L * DMODEL * DINNER; dst = w1T + (size_t)L * 1048576;
      K = DMODEL; N = DINNER; kt = tt >> 5; nt = tt & 31;
    } else {
      int tt = t - 512;
      src = W2 + (size_t)L * DINNER * DMODEL; dst = w2T + (size_t)L * 1048576;
      K = DINNER; N = DMODEL; kt = tt >> 3; nt = tt & 7;
    }
  } else {
    int tt = bid - 6 * 768;
    src = fcW; dst = fcT;
    K = DMODEL; N = VOCAB; kt = tt >> 3; nt = tt & 7;
  }
  __shared__ bf16u Ls[64][66];
  int tid = threadIdx.x;
  int c = tid & 63, r4 = tid >> 6;
#pragma unroll
  for (int i = 0; i < 16; i++) {
    int r = i * 4 + r4;
    Ls[r][c] = f2b(src[(size_t)(kt * 64 + r) * N + nt * 64 + c]);
  }
  __syncthreads();
#pragma unroll
  for (int i = 0; i < 16; i++) {
    int rr = i * 4 + r4;
    dst[(size_t)(nt * 64 + rr) * K + kt * 64 + c] = Ls[c][rr];
  }
}

// ---------------------------------------------------------------------------
// V transpose (bf16): vb[(b,i)][h*64+d] -> vbt[(b*8+h)*64+d][i]. 512 blocks.
// ---------------------------------------------------------------------------
__global__ __launch_bounds__(256) void vt_kernel(
    const bf16u* __restrict__ vb, bf16u* __restrict__ vbt)
{
  int bid = blockIdx.x;
  int b = bid >> 8, t = bid & 255;
  int it = t >> 3, h = t & 7;
  __shared__ bf16u Ls[64][66];
  int tid = threadIdx.x;
  int c = tid & 63, r4 = tid >> 6;
#pragma unroll
  for (int i = 0; i < 16; i++) {
    int r = i * 4 + r4;
    Ls[r][c] = vb[(size_t)(b * SEQ + it * 64 + r) * DMODEL + h * DHEAD + c];
  }
  __syncthreads();
#pragma unroll
  for (int i = 0; i < 16; i++) {
    int rr = i * 4 + r4;
    vbt[(size_t)((b * 8 + h) * DHEAD + rr) * SEQ + it * 64 + c] = Ls[c][rr];
  }
}

// ---------------------------------------------------------------------------
// MFMA GEMM, RB m-tiles/wave (4 -> 128x128, 2 -> 64x128, 1 -> 32x128), BK=64.
// Rule-#21 LDS swizzle: linear gld16 dest + inverse-swizzled global source +
// swizzled read (phys_oct = global_oct ^ (row&7)); bank conflicts = 0 (R10).
// XCD chunking Y-MAJOR (new): each XCD owns a contiguous bx span x all by ->
// per-XCD footprint = small A panel (reused by all by, L2-resident) +
// streamed B, instead of x-major's all-of-A (L2 overflow).
// modes: 0 +bias->bf16 ; 1 +bias+Rb ; 2 relu+chord ; 3 +bias->fp32 ;
// 4 fused-QKV routing.
// ---------------------------------------------------------------------------
template <int RB>
__global__ __launch_bounds__(256) void mgemm(
    const bf16u* __restrict__ A, const bf16u* __restrict__ Wt,
    const float* __restrict__ b0, const float* __restrict__ b1,
    const float* __restrict__ b2, const bf16u* __restrict__ Rb,
    float* __restrict__ Cf, bf16u* __restrict__ Cb,
    int M, int N, int K, int mode,
    const float* __restrict__ ttc, const float* __restrict__ ttcW,
    const float* __restrict__ ttcb)
{
  __shared__ bf16u Ab[RB * 32][64];
  __shared__ bf16u Bb[128][64];
  const int tid = threadIdx.x;
  const int lane = tid & 63, wave = tid >> 6;
  const int quad = lane >> 4, l16 = lane & 15;
  const int wm = wave >> 1, wn = wave & 1;

  // XCD-chunked swizzle, y-major decode (bijective; nwg % 8 == 0 always)
  const int nwg = gridDim.x * gridDim.y;
  const int lin = blockIdx.y * gridDim.x + blockIdx.x;
  const int swz = (lin & 7) * (nwg >> 3) + (lin >> 3);
  const int bx = swz / gridDim.y, by = swz % gridDim.y;
  const int row0 = bx * (RB * 32), col0 = by * 128;

  f4frag acc[RB][4];
#pragma unroll
  for (int i = 0; i < RB; i++)
#pragma unroll
    for (int j = 0; j < 4; j++) acc[i][j] = (f4frag){0.f, 0.f, 0.f, 0.f};

  for (int k0 = 0; k0 < K; k0 += 64) {
    if (k0) __syncthreads();
    // A tile: RB*32 rows x 8 oct-chunks; source octet = phys ^ (row&7)
#pragma unroll
    for (int i = 0; i < RB; i++) {
      int c = i * 256 + tid;
      int r = c >> 3, goct = (c & 7) ^ (r & 7);
      gld16(&A[(size_t)(row0 + r) * K + k0 + goct * 8], &Ab[0][0] + c * 8);
    }
    // B tile: 128 rows x 8 oct-chunks
#pragma unroll
    for (int i = 0; i < 4; i++) {
      int c = i * 256 + tid;
      int r = c >> 3, goct = (c & 7) ^ (r & 7);
      gld16(&Wt[(size_t)(col0 + r) * K + k0 + goct * 8], &Bb[0][0] + c * 8);
    }
    __syncthreads();   // compiler drains vmcnt before s_barrier
#pragma unroll
    for (int kk = 0; kk < 2; kk++) {
      s8frag af[RB], bfr[4];
#pragma unroll
      for (int t = 0; t < RB; t++) {
        int ar = wm * (RB * 16) + t * 16 + l16;
        int aoct = ((kk << 2) | quad) ^ (ar & 7);
        af[t] = *(const s8frag*)&Ab[ar][aoct * 8];
      }
#pragma unroll
      for (int t = 0; t < 4; t++) {
        int br = wn * 64 + t * 16 + l16;
        int boct = ((kk << 2) | quad) ^ (br & 7);
        bfr[t] = *(const s8frag*)&Bb[br][boct * 8];
      }
#pragma unroll
      for (int mt = 0; mt < RB; mt++)
#pragma unroll
        for (int nt = 0; nt < 4; nt++)
          acc[mt][nt] = __builtin_amdgcn_mfma_f32_16x16x32_bf16(
              af[mt], bfr[nt], acc[mt][nt], 0, 0, 0);
    }
  }

#pragma unroll
  for (int mt = 0; mt < RB; mt++) {
#pragma unroll
    for (int r = 0; r < 4; r++) {
      int m = row0 + wm * (RB * 16) + mt * 16 + quad * 4 + r;
      float tval = 0.f;
      if (mode == 2) {
        int bb = m >> 11, s = m & (SEQ - 1);
        int sp = (s < NCOND) ? 0 : (s - NCOND);
        tval = 8.0f - ttc[bb * S_TOK + sp];
      }
#pragma unroll
      for (int nt = 0; nt < 4; nt++) {
        int n = col0 + wn * 64 + nt * 16 + l16;
        if (mode == 4) {
          int sel = n >> 9, nn = n & 511;
          float bv = (sel == 0) ? b0[nn] : ((sel == 1) ? b1[nn] : b2[nn]);
          Cb[(size_t)sel * MROWS * DMODEL + (size_t)m * DMODEL + nn]
              = f2b(acc[mt][nt][r] + bv);
        } else {
          float v = acc[mt][nt][r] + b0[n];
          if (mode == 1)      v += b2f(Rb[(size_t)m * N + n]);
          else if (mode == 2) v = fmaxf(v, 0.f) + tval * ttcW[n] + ttcb[n];
          if (mode == 3) Cf[(size_t)m * N + n] = v;
          else           Cb[(size_t)m * N + n] = f2b(v);
        }
      }
    }
  }
}

// ---------------------------------------------------------------------------
// LayerNorm over D=512 (bf16 in -> bf16 out), one row per block.
// ---------------------------------------------------------------------------
__global__ __launch_bounds__(256) void ln_kernel(
    const bf16u* __restrict__ X, const float* __restrict__ g,
    const float* __restrict__ bta, bf16u* __restrict__ Y)
{
  int row = blockIdx.x, tid = threadIdx.x;
  unsigned int pr = *(const unsigned int*)&X[(size_t)row * DMODEL + 2 * tid];
  float x0 = b2f((bf16u)(pr & 0xffff)), x1 = b2f((bf16u)(pr >> 16));
  __shared__ float red[8];
  int wv = tid >> 6, ln = tid & 63;
  float s = x0 + x1;
  for (int off = 32; off; off >>= 1) s += __shfl_xor(s, off);
  if (ln == 0) red[wv] = s;
  __syncthreads();
  float mu = (red[0] + red[1] + red[2] + red[3]) * (1.0f / DMODEL);
  float d0 = x0 - mu, d1 = x1 - mu;
  float vs = d0 * d0 + d1 * d1;
  for (int off = 32; off; off >>= 1) vs += __shfl_xor(vs, off);
  if (ln == 0) red[4 + wv] = vs;
  __syncthreads();
  float var = (red[4] + red[5] + red[6] + red[7]) * (1.0f / DMODEL);
  float rstd = rsqrtf(var + 1e-6f);
  float y0 = d0 * rstd * g[2 * tid]     + bta[2 * tid];
  float y1 = d1 * rstd * g[2 * tid + 1] + bta[2 * tid + 1];
  *(unsigned int*)&Y[(size_t)row * DMODEL + 2 * tid] = pack2(y0, y1);
}

// ---------------------------------------------------------------------------
__global__ __launch_bounds__(256) void tok_embed_kernel(
    const int* __restrict__ toks, const float* __restrict__ emb,
    const float* __restrict__ pos, bf16u* __restrict__ xb)
{
  int sp = blockIdx.x, b = blockIdx.y;
  int s = sp + NCOND;
  int tok = toks[b * S_TOK + sp];
  const float* er = emb + (size_t)tok * DMODEL;
  const float* pr = pos + (size_t)s * DMODEL;
  size_t ro = ((size_t)b * SEQ + s) * DMODEL;
  int d = threadIdx.x * 2;
  float v0 = er[d]     * 22.62741699796952f + pr[d];
  float v1 = er[d + 1] * 22.62741699796952f + pr[d + 1];
  *(unsigned int*)&xb[ro + d] = pack2(v0, v1);
}

// ---------------------------------------------------------------------------
__global__ __launch_bounds__(256) void cond_embed_kernel(
    const float* __restrict__ conds, const float* __restrict__ W1,
    const float* __restrict__ b1, const float* __restrict__ W2w,
    const float* __restrict__ b2, const float* __restrict__ nullc,
    const float* __restrict__ pos, bf16u* __restrict__ xb)
{
  int ci = blockIdx.x, b = blockIdx.y, tid = threadIdx.x;
  float c = conds[b * NCOND + ci];
  bool cn = isnan(c);
  float cm = cn ? 0.f : c;
  __shared__ float h1[DMODEL / 2];
  h1[tid] = fmaxf(cm * W1[ci * (DMODEL/2) + tid] + b1[ci * (DMODEL/2) + tid], 0.f);
  __syncthreads();
  for (int d = tid; d < DMODEL; d += 256) {
    float acc = b2[ci * DMODEL + d];
    for (int i = 0; i < DMODEL / 2; i++)
      acc = fmaf(h1[i], W2w[((size_t)ci * (DMODEL/2) + i) * DMODEL + d], acc);
    float ce = cn ? nullc[ci * DMODEL + d] : acc;
    xb[((size_t)b * SEQ + ci) * DMODEL + d] = f2b(ce + pos[(size_t)ci * DMODEL + d]);
  }
}

// ---------------------------------------------------------------------------
// E (fp32, all 6 layers) -> bf16.
// ---------------------------------------------------------------------------
__global__ __launch_bounds__(256) void e_conv_kernel(
    const float* __restrict__ E, bf16u* __restrict__ Eb)
{
  int i = (blockIdx.x * 256 + threadIdx.x) * 4;
  float4 v = *(const float4*)&E[i];
  ushort4 o;
  o.x = f2b(v.x); o.y = f2b(v.y); o.z = f2b(v.z); o.w = f2b(v.w);
  *(ushort4*)&Eb[i] = o;
}

// ---------------------------------------------------------------------------
// Split-K MFMA flash attention, 8 chunks x <=4 steps, compact 2304-block grid.
// Rank -> (it,c) via inverse of slot_off. XCD clustering (2 g per XCD) + LPT.
// ---------------------------------------------------------------------------
#define PS_SWZ(row) ((((row) >> 2) & 7) << 3)

__global__ __launch_bounds__(256) void attn_part(
    const bf16u* __restrict__ Q, const bf16u* __restrict__ K,
    const bf16u* __restrict__ Vt_g, const bf16u* __restrict__ Eb16,
    const int* __restrict__ toks, bf16u* __restrict__ pacc,
    float* __restrict__ pstat)
{
  const int d = blockIdx.x;
  const int xcd = d & 7, rank = d >> 3;        // rank in [0, 288)
  const int g = xcd * 2 + (rank >= NSLOT_G);   // (b,h) group, clustered per XCD
  int rem = (rank >= NSLOT_G) ? rank - NSLOT_G : rank;
  int it = 31;
  for (;;) { int ch = (it >> 2) + 1; if (rem < ch) break; rem -= ch; --it; }
  const int c = rem;                           // 4c <= it by construction
  const int slot = g * NSLOT_G + slot_off(it) + c;   // packed partial index
  const int b = g >> 3, h = g & 7;
  const int i0 = it * 64;

  __shared__ bf16u Kb[64][72];          // K tile; becomes P after mid barrier
  __shared__ bf16u Vt[64][72];
  __shared__ bf16u Ebs[128][72];
  __shared__ float padv[64];
  bf16u (*Ps)[72] = Kb;                 // alias: disjoint lifetimes per step

  const int tid  = threadIdx.x;
  const int lane = tid & 63;
  const int wave = tid >> 6;
  const int quad = lane >> 4;
  const int l16  = lane & 15;

  const bf16u* qr = Q + ((size_t)(b * SEQ + i0 + wave * 16 + l16)) * DMODEL + h * DHEAD;
  s8frag q0 = *(const s8frag*)&qr[quad * 8];
  s8frag q1 = *(const s8frag*)&qr[32 + quad * 8];

  float m_run[4], l_run[4];
  f4frag acc[4];
#pragma unroll
  for (int r = 0; r < 4; r++) { m_run[r] = -1e30f; l_run[r] = 0.f; }
#pragma unroll
  for (int dt = 0; dt < 4; dt++) acc[dt] = (f4frag){0.f, 0.f, 0.f, 0.f};

  const int js0 = 4 * c;
  const int jsE = min(4 * c + 4, it + 1);
  const size_t vtbase = (size_t)(g * DHEAD) * SEQ;

  for (int js = js0; js < jsE; js++) {
    const int j0 = js * 64;
    const int m0 = 1984 - i0 + j0;   // E row of band col 0
    __syncthreads();

    // K tile (2 x uint4 / thread)
#pragma unroll
    for (int e = 0; e < 2; e++) {
      int cc = e * 256 + tid;
      int jr = cc >> 3, doff = (cc & 7) * 8;
      *(uint4*)&Kb[jr][doff] =
          *(const uint4*)&K[((size_t)(b * SEQ + j0 + jr)) * DMODEL + h * DHEAD + doff];
    }
    // V^T tile from pre-transposed global (2 x uint4 / thread)
#pragma unroll
    for (int e = 0; e < 2; e++) {
      int cc = e * 256 + tid;
      int dr = cc >> 3, joff = (cc & 7) * 8;
      *(uint4*)&Vt[dr][joff] =
          *(const uint4*)&Vt_g[vtbase + (size_t)dr * SEQ + j0 + joff];
    }
    // E ring: first step fill 128 rows, then 64 new rows
    if (js == js0) {
#pragma unroll
      for (int e = 0; e < 4; e++) {
        int cc = e * 256 + tid;
        int er = cc >> 3, doff = (cc & 7) * 8;
        int m = m0 + er; int row = m > SEQ - 1 ? SEQ - 1 : m;
        *(uint4*)&Ebs[m & 127][doff] = *(const uint4*)&Eb16[(size_t)row * DHEAD + doff];
      }
    } else {
#pragma unroll
      for (int e = 0; e < 2; e++) {
        int cc = e * 256 + tid;
        int er = 64 + (cc >> 3), doff = (cc & 7) * 8;
        int m = m0 + er; int row = m > SEQ - 1 ? SEQ - 1 : m;
        *(uint4*)&Ebs[m & 127][doff] = *(const uint4*)&Eb16[(size_t)row * DHEAD + doff];
      }
    }
    if (tid < 64) {
      int j = j0 + tid;
      bool pad = (j >= NCOND) && (toks[b * S_TOK + j - NCOND] == 0);
      padv[tid] = pad ? -1e30f : 0.f;
    }
    __syncthreads();

    // QK^T (reads Kb)
    f4frag sc[4];
#pragma unroll
    for (int nt = 0; nt < 4; nt++) {
      s8frag k0 = *(const s8frag*)&Kb[nt * 16 + l16][quad * 8];
      s8frag k1 = *(const s8frag*)&Kb[nt * 16 + l16][32 + quad * 8];
      f4frag cc = (f4frag){0.f, 0.f, 0.f, 0.f};
      cc = __builtin_amdgcn_mfma_f32_16x16x32_bf16(q0, k0, cc, 0, 0, 0);
      cc = __builtin_amdgcn_mfma_f32_16x16x32_bf16(q1, k1, cc, 0, 0, 0);
      sc[nt] = cc;
    }

    // QE: 5 frags covering band cols [(3-wave)*16, (8-wave)*16)  (reads Ebs)
    f4frag qef[5];
#pragma unroll
    for (int f = 0; f < 5; f++) {
      int ct = f + 3 - wave;
      int m = m0 + ct * 16 + l16;
      const bf16u* erow = &Ebs[m & 127][0];
      s8frag e0 = *(const s8frag*)&erow[quad * 8];
      s8frag e1 = *(const s8frag*)&erow[32 + quad * 8];
      f4frag cc = (f4frag){0.f, 0.f, 0.f, 0.f};
      cc = __builtin_amdgcn_mfma_f32_16x16x32_bf16(q0, e0, cc, 0, 0, 0);
      cc = __builtin_amdgcn_mfma_f32_16x16x32_bf16(q1, e1, cc, 0, 0, 0);
      qef[f] = cc;
    }

    // All Kb/Ebs reads are drained by this barrier; Kb becomes the P buffer.
    __syncthreads();

    float pvv[4];
#pragma unroll
    for (int nt = 0; nt < 4; nt++) pvv[nt] = padv[nt * 16 + l16];

    // scores + online softmax; QE gathered by ONE shuffle (select at source).
    float s[4][4], mx[4];
#pragma unroll
    for (int r = 0; r < 4; r++) {
      int rloc = wave * 16 + quad * 4 + r;
      int ig = i0 + rloc;
      int t2 = quad * 4 + r;
      int v = 63 - 16 * wave + l16 - t2;
      int srcl = (lane & 48) | (v & 15);
      bool hiSrc = (l16 < 15 - t2);    // target hi <=> this at source lane
#pragma unroll
      for (int nt = 0; nt < 4; nt++) {
        float pre = hiSrc ? qef[nt + 1][r] : qef[nt][r];
        float qe = __shfl(pre, srcl);
        int jl = nt * 16 + l16;
        float sv = (sc[nt][r] + qe) * 0.125f + pvv[nt];
        if (j0 + jl > ig) sv = -1e30f;
        s[nt][r] = sv;
      }
      float m = fmaxf(fmaxf(s[0][r], s[1][r]), fmaxf(s[2][r], s[3][r]));
      float tr;
      DPP_ROR(tr, m, 1); m = fmaxf(m, tr);
      DPP_ROR(tr, m, 2); m = fmaxf(m, tr);
      DPP_ROR(tr, m, 4); m = fmaxf(m, tr);
      DPP_ROR(tr, m, 8); m = fmaxf(m, tr);
      mx[r] = m;
    }
    float alpha[4];
#pragma unroll
    for (int r = 0; r < 4; r++) {
      float m_new = fmaxf(m_run[r], mx[r]);
      alpha[r] = __expf(m_run[r] - m_new);
      float psum = 0.f;
      int rloc = wave * 16 + quad * 4 + r;
#pragma unroll
      for (int nt = 0; nt < 4; nt++) {
        float p = __expf(s[nt][r] - m_new);
        Ps[rloc][(nt * 16 + l16) ^ PS_SWZ(rloc)] = f2b(p);
        psum += p;
      }
      float tr;
      DPP_ROR(tr, psum, 1); psum += tr;
      DPP_ROR(tr, psum, 2); psum += tr;
      DPP_ROR(tr, psum, 4); psum += tr;
      DPP_ROR(tr, psum, 8); psum += tr;
      l_run[r] = l_run[r] * alpha[r] + psum;
      m_run[r] = m_new;
    }
#pragma unroll
    for (int dt = 0; dt < 4; dt++)
#pragma unroll
      for (int r = 0; r < 4; r++) acc[dt][r] *= alpha[r];

    // P @ V  (Ps rows are wave-local; swizzled reads match swizzled writes)
    {
      int prow = wave * 16 + l16;
      int psw = PS_SWZ(prow);
      s8frag p0 = *(const s8frag*)&Ps[prow][(quad * 8) ^ psw];
      s8frag p1 = *(const s8frag*)&Ps[prow][(32 + quad * 8) ^ psw];
#pragma unroll
      for (int dt = 0; dt < 4; dt++) {
        s8frag v0 = *(const s8frag*)&Vt[dt * 16 + l16][quad * 8];
        s8frag v1 = *(const s8frag*)&Vt[dt * 16 + l16][32 + quad * 8];
        acc[dt] = __builtin_amdgcn_mfma_f32_16x16x32_bf16(p0, v0, acc[dt], 0, 0, 0);
        acc[dt] = __builtin_amdgcn_mfma_f32_16x16x32_bf16(p1, v1, acc[dt], 0, 0, 0);
      }
    }
  }

  // write partials (packed slot)
#pragma unroll
  for (int r = 0; r < 4; r++) {
    int rloc = wave * 16 + quad * 4 + r;
    if (l16 == 0) {
      pstat[(size_t)slot * 128 + rloc]      = m_run[r];
      pstat[(size_t)slot * 128 + 64 + rloc] = l_run[r];
    }
#pragma unroll
    for (int dt = 0; dt < 4; dt++)
      pacc[(size_t)slot * 4096 + rloc * 64 + dt * 16 + l16] = f2b(acc[dt][r]);
  }
}

// ---------------------------------------------------------------------------
// Merge <=8 chunk partials per (b,h,q-tile); write O (bf16) into qb.
// ---------------------------------------------------------------------------
__global__ __launch_bounds__(256) void attn_combine(
    const bf16u* __restrict__ pacc, const float* __restrict__ pstat,
    bf16u* __restrict__ O)
{
  int bid = blockIdx.x;             // g*32 + it
  int g = bid >> 5, it = bid & 31;
  int b = g >> 3, h = g & 7;
  int i0 = it * 64;
  int nc = (it >> 2) + 1;           // chunks of 4 steps
  int base = g * NSLOT_G + slot_off(it);
  int tid = threadIdx.x;
  int row = tid >> 2, ql = tid & 3;

  float m_tot = -1e30f;
  float mc[8], lc[8];
#pragma unroll
  for (int c = 0; c < 8; c++) {
    if (c < nc) {
      size_t pb = (size_t)(base + c) * 128;
      mc[c] = pstat[pb + row];
      lc[c] = pstat[pb + 64 + row];
      m_tot = fmaxf(m_tot, mc[c]);
    }
  }
  float l_tot = 0.f, w[8];
#pragma unroll
  for (int c = 0; c < 8; c++) {
    if (c < nc) { w[c] = __expf(mc[c] - m_tot); l_tot += w[c] * lc[c]; }
    else w[c] = 0.f;
  }
  float inv = 1.0f / l_tot;

  float out[16];
#pragma unroll
  for (int k = 0; k < 16; k++) out[k] = 0.f;
#pragma unroll
  for (int c = 0; c < 8; c++) {
    if (c >= nc) break;
    const bf16u* pa = pacc + (size_t)(base + c) * 4096 + row * 64 + ql * 16;
#pragma unroll
    for (int k = 0; k < 16; k++) out[k] += w[c] * b2f(pa[k]);
  }
  bf16u* ob = O + ((size_t)(b * SEQ + i0 + row)) * DMODEL + h * DHEAD + ql * 16;
#pragma unroll
  for (int k = 0; k < 16; k++) ob[k] = f2b(out[k] * inv);
}

// ---------------------------------------------------------------------------
extern "C" void kernel_launch(void* const* d_in, const int* in_sizes, int n_in,
                              void* d_out, int out_size, void* d_ws, size_t ws_size,
                              hipStream_t stream) {
  const int*   toks  = (const int*)  d_in[0];
  const float* conds = (const float*)d_in[1];
  const float* ttc   = (const float*)d_in[2];
  const float* emb   = (const float*)d_in[3];
  const float* pos   = (const float*)d_in[4];
  const float* cW1   = (const float*)d_in[5];
  const float* cb1   = (const float*)d_in[6];
  const float* cW2   = (const float*)d_in[7];
  const float* cb2   = (const float*)d_in[8];
  const float* nullc = (const float*)d_in[9];
  const float* ttcW  = (const float*)d_in[10];
  const float* ttcb  = (const float*)d_in[11];
  const float* Wq    = (const float*)d_in[12];
  const float* Wk    = (const float*)d_in[13];
  const float* Wv    = (const float*)d_in[14];
  const float* Wo    = (const float*)d_in[15];
  const float* bq    = (const float*)d_in[16];
  const float* bk    = (const float*)d_in[17];
  const float* bv    = (const float*)d_in[18];
  const float* bo    = (const float*)d_in[19];
  const float* E     = (const float*)d_in[20];
  const float* fW1   = (const float*)d_in[21];
  const float* fb1   = (const float*)d_in[22];
  const float* fW2   = (const float*)d_in[23];
  const float* fb2   = (const float*)d_in[24];
  const float* ln1g  = (const float*)d_in[25];
  const float* ln1b  = (const float*)d_in[26];
  const float* ln2g  = (const float*)d_in[27];
  const float* ln2b  = (const float*)d_in[28];
  const float* fcW   = (const float*)d_in[29];
  const float* fcb   = (const float*)d_in[30];

  const size_t MB1 = 1024 * 1024;
  const size_t MD = (size_t)MROWS * DMODEL;
  char* p = (char*)d_ws;
  bf16u* xb    = (bf16u*)p; p += 4 * MB1;
  bf16u* qkvb  = (bf16u*)p; p += 12 * MB1;   // qb | kb | vb
  bf16u* hidb  = (bf16u*)p; p += 16 * MB1;   // FFN hidden
  float* pstat_old = (float*)p; p += 1 * MB1; // (unused; kept for layout)
  bf16u* vbt   = (bf16u*)p; p += 4 * MB1;    // V transposed
  bf16u* ebf   = (bf16u*)p; p += 1536 * 1024;   // E bf16, 6 layers
  bf16u* WqkvT = (bf16u*)p; p += 9 * MB1;
  bf16u* WoT   = (bf16u*)p; p += 3 * MB1;
  bf16u* W1T   = (bf16u*)p; p += 12 * MB1;
  bf16u* W2T   = (bf16u*)p; p += 12 * MB1;
  bf16u* fcT   = (bf16u*)p; p += 512 * 1024;    // total 75 MB
  (void)pstat_old;
  bf16u* qb = qkvb;
  bf16u* kb = qkvb + MD;        // out1b aliases kb (disjoint lifetimes)
  bf16u* vb = qkvb + 2 * MD;    // t1b aliases vb (disjoint lifetimes)
  bf16u* out1b = kb;
  bf16u* t1b   = vb;
  // Partials live in the contiguous vb+hidb span (20MB): vb is dead after
  // vt_kernel; hidb's FFN lifetime starts after attn_combine.
  // pacc 2304*8KB = 18MB, pstat 2304*512B = 1.15MB -> 19.15MB <= 20MB.
  bf16u* pacc  = vb;
  float* pstat = (float*)(pacc + (size_t)NSLOTS * 4096);

  // ---- setup: embeds + all-layer weight transposes + E conversion ----
  cond_embed_kernel<<<dim3(NCOND, BATCH), 256, 0, stream>>>(
      conds, cW1, cb1, cW2, cb2, nullc, pos, xb);
  tok_embed_kernel<<<dim3(S_TOK, BATCH), 256, 0, stream>>>(toks, emb, pos, xb);
  wt_all_kernel<<<6 * 768 + 64, 256, 0, stream>>>(Wq, Wk, Wv, Wo, fW1, fW2, fcW,
      WqkvT, WoT, W1T, W2T, fcT);
  e_conv_kernel<<<(NLAYER * SEQ * DHEAD) / 1024, 256, 0, stream>>>(E, ebf);

  dim3 gQKV(MROWS / 64, 1536 / 128);       // (64,12): 768 blocks, RB=2
  dim3 gFF1(MROWS / 64, DINNER / 128);     // (64,16): 1024 blocks, RB=2
  dim3 gN512(MROWS / 32, DMODEL / 128);    // (128,4): 512 blocks, RB=1

  for (int l = 0; l < NLAYER; l++) {
    // fused QKV
    mgemm<2><<<gQKV, 256, 0, stream>>>(xb, WqkvT + (size_t)l * 786432,
        bq + l * DMODEL, bk + l * DMODEL, bv + l * DMODEL, nullptr,
        nullptr, qkvb, MROWS, 1536, DMODEL, 4, nullptr, nullptr, nullptr);

    vt_kernel<<<512, 256, 0, stream>>>(vb, vbt);
    attn_part<<<NSLOTS, 256, 0, stream>>>(qb, kb, vbt,
        ebf + (size_t)l * SEQ * DHEAD, toks, pacc, pstat);
    attn_combine<<<512, 256, 0, stream>>>(pacc, pstat, qb);

    // t1 = attn @ Wo + bo + x
    mgemm<1><<<gN512, 256, 0, stream>>>(qb, WoT + (size_t)l * 262144,
        bo + l * DMODEL, nullptr, nullptr, xb,
        nullptr, t1b, MROWS, DMODEL, DMODEL, 1, nullptr, nullptr, nullptr);
    ln_kernel<<<MROWS, 256, 0, stream>>>(t1b, ln1g + l * DMODEL, ln1b + l * DMODEL,
        out1b);

    // hid = relu(out1 @ W1 + b1) + chord
    mgemm<2><<<gFF1, 256, 0, stream>>>(out1b, W1T + (size_t)l * 1048576,
        fb1 + l * DINNER, nullptr, nullptr, nullptr,
        nullptr, hidb, MROWS, DINNER, DMODEL, 2, ttc, ttcW, ttcb);
    // t1 = hid @ W2 + b2 + out1
    mgemm<1><<<gN512, 256, 0, stream>>>(hidb, W2T + (size_t)l * 1048576,
        fb2 + l * DMODEL, nullptr, nullptr, out1b,
        nullptr, t1b, MROWS, DMODEL, DINNER, 1, nullptr, nullptr, nullptr);
    ln_kernel<<<MROWS, 256, 0, stream>>>(t1b, ln2g + l * DMODEL, ln2b + l * DMODEL,
        xb);
  }

  // logits = x @ fc_W + fc_b (fp32 out)
  mgemm<1><<<gN512, 256, 0, stream>>>(xb, fcT,
      fcb, nullptr, nullptr, nullptr,
      (float*)d_out, nullptr, MROWS, VOCAB, DMODEL, 3, nullptr, nullptr, nullptr);
}

// Round 13
// 1088.534 us; speedup vs baseline: 1.4479x; 1.0365x over previous
//
#include <hip/hip_runtime.h>
#include <hip/hip_bf16.h>
#include <math.h>

// ---- problem constants ----
#define BATCH  2
#define S_TOK  2046
#define NCOND  2
#define SEQ    2048
#define DMODEL 512
#define DINNER 2048
#define NHEAD  8
#define DHEAD  64
#define NLAYER 6
#define VOCAB  512
#define MROWS  (BATCH*SEQ)   // 4096 rows

// split-K attention: 8 chunks of 4 steps; packed slots (144 per (b,h) group)
#define NSLOT_G 144
#define NSLOTS  (16 * NSLOT_G)   // 2304

typedef unsigned short bf16u;
typedef __attribute__((ext_vector_type(8))) short s8frag;   // 8 bf16 (4 VGPRs)
typedef __attribute__((ext_vector_type(4))) float f4frag;   // 4 fp32 acc

__device__ __forceinline__ float b2f(bf16u u) {
  union { unsigned int i; float f; } v; v.i = ((unsigned int)u) << 16; return v.f;
}
__device__ __forceinline__ bf16u f2b(float f) {
  union { float f; unsigned int i; } v; v.f = f;
  unsigned int x = v.i;
  return (bf16u)((x + 0x7fffu + ((x >> 16) & 1u)) >> 16);
}
__device__ __forceinline__ unsigned int pack2(float a, float b) {
  return (unsigned int)f2b(a) | ((unsigned int)f2b(b) << 16);
}

// async global->LDS, 16B per lane. LDS dest must be wave-uniform base +
// lane*16 (we pass per-lane ptrs that satisfy exactly that).
__device__ __forceinline__ void gld16(const bf16u* g, bf16u* l) {
  __builtin_amdgcn_global_load_lds(
      (const __attribute__((address_space(1))) unsigned int*)g,
      (__attribute__((address_space(3))) unsigned int*)l,
      16, 0, 0);
}

// DPP row-rotate (within 16-lane row) — VALU-pipe lane exchange, not LDS.
#define DPP_ROR(dst, src, N)                                              \
  dst = __int_as_float(__builtin_amdgcn_update_dpp(                       \
      0, __float_as_int(src), 0x120 + (N), 0xF, 0xF, true))

// packed slot offset: Sum_{j<it} ((j>>2)+1) = it + 2a(a-1) + a*b, a=it>>2,b=it&3
__device__ __forceinline__ int slot_off(int it) {
  int a = it >> 2, b = it & 3;
  return it + 2 * a * (a - 1) + a * b;
}

// ---------------------------------------------------------------------------
// All-layer weight transpose + bf16: dst[N][K] = src[K][N]. One launch.
// blocks: 6 layers x 768 (q64|k64|v64|o64|W1 256|W2 256) + 64 (fc) = 4672.
// ---------------------------------------------------------------------------
__global__ __launch_bounds__(256) void wt_all_kernel(
    const float* __restrict__ Wq, const float* __restrict__ Wk,
    const float* __restrict__ Wv, const float* __restrict__ Wo,
    const float* __restrict__ W1, const float* __restrict__ W2,
    const float* __restrict__ fcW,
    bf16u* __restrict__ qkvT, bf16u* __restrict__ oT,
    bf16u* __restrict__ w1T, bf16u* __restrict__ w2T, bf16u* __restrict__ fcT)
{
  int bid = blockIdx.x;
  const float* src; bf16u* dst; int N, K, kt, nt;
  if (bid < 6 * 768) {
    int L = bid / 768, t = bid - L * 768;
    if (t < 256) {
      int mat = t >> 6, tt = t & 63;
      const float* s4[4] = {Wq, Wk, Wv, Wo};
      src = s4[mat] + (size_t)L * DMODEL * DMODEL;
      dst = (mat < 3) ? (qkvT + (size_t)L * 786432 + (size_t)mat * 262144)
                      : (oT + (size_t)L * 262144);
      K = DMODEL; N = DMODEL; kt = tt >> 3; nt = tt & 7;
    } else if (t < 512) {
      int tt = t - 256;
      src = W1 + (size_t)L * DMODEL * DINNER; dst = w1T + (size_t)L * 1048576;
      K = DMODEL; N = DINNER; kt = tt >> 5; nt = tt & 31;
    } else {
      int tt = t - 512;
      src = W2 + (size_t)L * DINNER * DMODEL; dst = w2T + (size_t)L * 1048576;
      K = DINNER; N = DMODEL; kt = tt >> 3; nt = tt & 7;
    }
  } else {
    int tt = bid - 6 * 768;
    src = fcW; dst = fcT;
    K = DMODEL; N = VOCAB; kt = tt >> 3; nt = tt & 7;
  }
  __shared__ bf16u Ls[64][66];
  int tid = threadIdx.x;
  int c = tid & 63, r4 = tid >> 6;
#pragma unroll
  for (int i = 0; i < 16; i++) {
    int r = i * 4 + r4;
    Ls[r][c] = f2b(src[(size_t)(kt * 64 + r) * N + nt * 64 + c]);
  }
  __syncthreads();
#pragma unroll
  for (int i = 0; i < 16; i++) {
    int rr = i * 4 + r4;
    dst[(size_t)(nt * 64 + rr) * K + kt * 64 + c] = Ls[c][rr];
  }
}

// ---------------------------------------------------------------------------
// MFMA GEMM, RB m-tiles/wave (4 -> 128x128, 2 -> 64x128, 1 -> 32x128), BK=64.
// Rule-#21 LDS swizzle: linear gld16 dest + inverse-swizzled global source +
// swizzled read (phys_oct = global_oct ^ (row&7)); bank conflicts = 0 (R10).
// XCD chunking y-major (R11: A panel L2-resident per XCD).
// modes: 0 +bias->bf16 ; 1 +bias+Rb ; 2 relu+chord ; 3 +bias->fp32 ;
// 4 fused-QKV routing. Mode-4 V blocks (col0>=1024, RB=2): output tile is
// TRANSPOSED through LDS (reusing Bb, XOR-swizzled) and stored as coalesced
// 16B chunks into vbt[(b*8+h)*64+d][i] — fuses the old vt_kernel.
// ---------------------------------------------------------------------------
template <int RB>
__global__ __launch_bounds__(256) void mgemm(
    const bf16u* __restrict__ A, const bf16u* __restrict__ Wt,
    const float* __restrict__ b0, const float* __restrict__ b1,
    const float* __restrict__ b2, const bf16u* __restrict__ Rb,
    float* __restrict__ Cf, bf16u* __restrict__ Cb,
    int M, int N, int K, int mode,
    const float* __restrict__ ttc, const float* __restrict__ ttcW,
    const float* __restrict__ ttcb)
{
  __shared__ bf16u Ab[RB * 32][64];
  __shared__ bf16u Bb[128][64];
  const int tid = threadIdx.x;
  const int lane = tid & 63, wave = tid >> 6;
  const int quad = lane >> 4, l16 = lane & 15;
  const int wm = wave >> 1, wn = wave & 1;

  // XCD-chunked swizzle, y-major decode (bijective; nwg % 8 == 0 always)
  const int nwg = gridDim.x * gridDim.y;
  const int lin = blockIdx.y * gridDim.x + blockIdx.x;
  const int swz = (lin & 7) * (nwg >> 3) + (lin >> 3);
  const int bx = swz / gridDim.y, by = swz % gridDim.y;
  const int row0 = bx * (RB * 32), col0 = by * 128;

  f4frag acc[RB][4];
#pragma unroll
  for (int i = 0; i < RB; i++)
#pragma unroll
    for (int j = 0; j < 4; j++) acc[i][j] = (f4frag){0.f, 0.f, 0.f, 0.f};

  for (int k0 = 0; k0 < K; k0 += 64) {
    if (k0) __syncthreads();
    // A tile: RB*32 rows x 8 oct-chunks; source octet = phys ^ (row&7)
#pragma unroll
    for (int i = 0; i < RB; i++) {
      int c = i * 256 + tid;
      int r = c >> 3, goct = (c & 7) ^ (r & 7);
      gld16(&A[(size_t)(row0 + r) * K + k0 + goct * 8], &Ab[0][0] + c * 8);
    }
    // B tile: 128 rows x 8 oct-chunks
#pragma unroll
    for (int i = 0; i < 4; i++) {
      int c = i * 256 + tid;
      int r = c >> 3, goct = (c & 7) ^ (r & 7);
      gld16(&Wt[(size_t)(col0 + r) * K + k0 + goct * 8], &Bb[0][0] + c * 8);
    }
    __syncthreads();   // compiler drains vmcnt before s_barrier
#pragma unroll
    for (int kk = 0; kk < 2; kk++) {
      s8frag af[RB], bfr[4];
#pragma unroll
      for (int t = 0; t < RB; t++) {
        int ar = wm * (RB * 16) + t * 16 + l16;
        int aoct = ((kk << 2) | quad) ^ (ar & 7);
        af[t] = *(const s8frag*)&Ab[ar][aoct * 8];
      }
#pragma unroll
      for (int t = 0; t < 4; t++) {
        int br = wn * 64 + t * 16 + l16;
        int boct = ((kk << 2) | quad) ^ (br & 7);
        bfr[t] = *(const s8frag*)&Bb[br][boct * 8];
      }
#pragma unroll
      for (int mt = 0; mt < RB; mt++)
#pragma unroll
        for (int nt = 0; nt < 4; nt++)
          acc[mt][nt] = __builtin_amdgcn_mfma_f32_16x16x32_bf16(
              af[mt], bfr[nt], acc[mt][nt], 0, 0, 0);
    }
  }

  if constexpr (RB == 2) {
    if (mode == 4 && col0 >= 1024) {
      // ---- V slice: transpose via LDS (reuse Bb) + coalesced vbt stores ----
      __syncthreads();                 // all waves done reading Bb
      bf16u* Ls = &Bb[0][0];           // viewed as [128 n][64 m], m XOR-swz
#pragma unroll
      for (int mt = 0; mt < 2; mt++)
#pragma unroll
        for (int r = 0; r < 4; r++) {
          int m = wm * 32 + mt * 16 + quad * 4 + r;   // local row (seq)
#pragma unroll
          for (int nt = 0; nt < 4; nt++) {
            int n = wn * 64 + nt * 16 + l16;          // local col (dim)
            float v = acc[mt][nt][r] + b2[(col0 + n) & 511];
            Ls[n * 64 + (m ^ ((n & 7) << 3))] = f2b(v);
          }
        }
      __syncthreads();
      bf16u* vbt_g = (bf16u*)Cf;
      int bb = row0 >> 11, i0g = row0 & (SEQ - 1);
#pragma unroll
      for (int e = 0; e < 4; e++) {
        int chunk = e * 256 + tid;                    // 1024 chunks
        int dloc = chunk >> 3, j8 = chunk & 7;
        int nn = (col0 + dloc) & 511;
        int h = nn >> 6, dd = nn & 63;
        uint4 val = *(const uint4*)&Ls[dloc * 64 + ((j8 * 8) ^ ((dloc & 7) << 3))];
        *(uint4*)&vbt_g[((size_t)((bb * 8 + h) * DHEAD + dd)) * SEQ + i0g + j8 * 8]
            = val;
      }
      return;
    }
  }

#pragma unroll
  for (int mt = 0; mt < RB; mt++) {
#pragma unroll
    for (int r = 0; r < 4; r++) {
      int m = row0 + wm * (RB * 16) + mt * 16 + quad * 4 + r;
      float tval = 0.f;
      if (mode == 2) {
        int bb = m >> 11, s = m & (SEQ - 1);
        int sp = (s < NCOND) ? 0 : (s - NCOND);
        tval = 8.0f - ttc[bb * S_TOK + sp];
      }
#pragma unroll
      for (int nt = 0; nt < 4; nt++) {
        int n = col0 + wn * 64 + nt * 16 + l16;
        if (mode == 4) {
          int sel = n >> 9, nn = n & 511;
          float bv = (sel == 0) ? b0[nn] : b1[nn];
          Cb[(size_t)sel * MROWS * DMODEL + (size_t)m * DMODEL + nn]
              = f2b(acc[mt][nt][r] + bv);
        } else {
          float v = acc[mt][nt][r] + b0[n];
          if (mode == 1)      v += b2f(Rb[(size_t)m * N + n]);
          else if (mode == 2) v = fmaxf(v, 0.f) + tval * ttcW[n] + ttcb[n];
          if (mode == 3) Cf[(size_t)m * N + n] = v;
          else           Cb[(size_t)m * N + n] = f2b(v);
        }
      }
    }
  }
}

// ---------------------------------------------------------------------------
// LayerNorm over D=512 (bf16 in -> bf16 out), one row per block.
// ---------------------------------------------------------------------------
__global__ __launch_bounds__(256) void ln_kernel(
    const bf16u* __restrict__ X, const float* __restrict__ g,
    const float* __restrict__ bta, bf16u* __restrict__ Y)
{
  int row = blockIdx.x, tid = threadIdx.x;
  unsigned int pr = *(const unsigned int*)&X[(size_t)row * DMODEL + 2 * tid];
  float x0 = b2f((bf16u)(pr & 0xffff)), x1 = b2f((bf16u)(pr >> 16));
  __shared__ float red[8];
  int wv = tid >> 6, ln = tid & 63;
  float s = x0 + x1;
  for (int off = 32; off; off >>= 1) s += __shfl_xor(s, off);
  if (ln == 0) red[wv] = s;
  __syncthreads();
  float mu = (red[0] + red[1] + red[2] + red[3]) * (1.0f / DMODEL);
  float d0 = x0 - mu, d1 = x1 - mu;
  float vs = d0 * d0 + d1 * d1;
  for (int off = 32; off; off >>= 1) vs += __shfl_xor(vs, off);
  if (ln == 0) red[4 + wv] = vs;
  __syncthreads();
  float var = (red[4] + red[5] + red[6] + red[7]) * (1.0f / DMODEL);
  float rstd = rsqrtf(var + 1e-6f);
  float y0 = d0 * rstd * g[2 * tid]     + bta[2 * tid];
  float y1 = d1 * rstd * g[2 * tid + 1] + bta[2 * tid + 1];
  *(unsigned int*)&Y[(size_t)row * DMODEL + 2 * tid] = pack2(y0, y1);
}

// ---------------------------------------------------------------------------
__global__ __launch_bounds__(256) void tok_embed_kernel(
    const int* __restrict__ toks, const float* __restrict__ emb,
    const float* __restrict__ pos, bf16u* __restrict__ xb)
{
  int sp = blockIdx.x, b = blockIdx.y;
  int s = sp + NCOND;
  int tok = toks[b * S_TOK + sp];
  const float* er = emb + (size_t)tok * DMODEL;
  const float* pr = pos + (size_t)s * DMODEL;
  size_t ro = ((size_t)b * SEQ + s) * DMODEL;
  int d = threadIdx.x * 2;
  float v0 = er[d]     * 22.62741699796952f + pr[d];
  float v1 = er[d + 1] * 22.62741699796952f + pr[d + 1];
  *(unsigned int*)&xb[ro + d] = pack2(v0, v1);
}

// ---------------------------------------------------------------------------
__global__ __launch_bounds__(256) void cond_embed_kernel(
    const float* __restrict__ conds, const float* __restrict__ W1,
    const float* __restrict__ b1, const float* __restrict__ W2w,
    const float* __restrict__ b2, const float* __restrict__ nullc,
    const float* __restrict__ pos, bf16u* __restrict__ xb)
{
  int ci = blockIdx.x, b = blockIdx.y, tid = threadIdx.x;
  float c = conds[b * NCOND + ci];
  bool cn = isnan(c);
  float cm = cn ? 0.f : c;
  __shared__ float h1[DMODEL / 2];
  h1[tid] = fmaxf(cm * W1[ci * (DMODEL/2) + tid] + b1[ci * (DMODEL/2) + tid], 0.f);
  __syncthreads();
  for (int d = tid; d < DMODEL; d += 256) {
    float acc = b2[ci * DMODEL + d];
    for (int i = 0; i < DMODEL / 2; i++)
      acc = fmaf(h1[i], W2w[((size_t)ci * (DMODEL/2) + i) * DMODEL + d], acc);
    float ce = cn ? nullc[ci * DMODEL + d] : acc;
    xb[((size_t)b * SEQ + ci) * DMODEL + d] = f2b(ce + pos[(size_t)ci * DMODEL + d]);
  }
}

// ---------------------------------------------------------------------------
// E (fp32, all 6 layers) -> bf16.
// ---------------------------------------------------------------------------
__global__ __launch_bounds__(256) void e_conv_kernel(
    const float* __restrict__ E, bf16u* __restrict__ Eb)
{
  int i = (blockIdx.x * 256 + threadIdx.x) * 4;
  float4 v = *(const float4*)&E[i];
  ushort4 o;
  o.x = f2b(v.x); o.y = f2b(v.y); o.z = f2b(v.z); o.w = f2b(v.w);
  *(ushort4*)&Eb[i] = o;
}

// ---------------------------------------------------------------------------
// Split-K MFMA flash attention, 8 chunks x <=4 steps, compact 2304-block grid.
// EXACTLY the R11-verified version (f2b conversions; cvt_pk dropped per m240
// and R12's correctness failure). Rank -> (it,c) via inverse of slot_off.
// XCD clustering (2 g per XCD) + LPT.
// ---------------------------------------------------------------------------
#define PS_SWZ(row) ((((row) >> 2) & 7) << 3)

__global__ __launch_bounds__(256) void attn_part(
    const bf16u* __restrict__ Q, const bf16u* __restrict__ K,
    const bf16u* __restrict__ Vt_g, const bf16u* __restrict__ Eb16,
    const int* __restrict__ toks, bf16u* __restrict__ pacc,
    float* __restrict__ pstat)
{
  const int d = blockIdx.x;
  const int xcd = d & 7, rank = d >> 3;        // rank in [0, 288)
  const int g = xcd * 2 + (rank >= NSLOT_G);   // (b,h) group, clustered per XCD
  int rem = (rank >= NSLOT_G) ? rank - NSLOT_G : rank;
  int it = 31;
  for (;;) { int ch = (it >> 2) + 1; if (rem < ch) break; rem -= ch; --it; }
  const int c = rem;                           // 4c <= it by construction
  const int slot = g * NSLOT_G + slot_off(it) + c;   // packed partial index
  const int b = g >> 3, h = g & 7;
  const int i0 = it * 64;

  __shared__ bf16u Kb[64][72];          // K tile; becomes P after mid barrier
  __shared__ bf16u Vt[64][72];
  __shared__ bf16u Ebs[128][72];
  __shared__ float padv[64];
  bf16u (*Ps)[72] = Kb;                 // alias: disjoint lifetimes per step

  const int tid  = threadIdx.x;
  const int lane = tid & 63;
  const int wave = tid >> 6;
  const int quad = lane >> 4;
  const int l16  = lane & 15;

  const bf16u* qr = Q + ((size_t)(b * SEQ + i0 + wave * 16 + l16)) * DMODEL + h * DHEAD;
  s8frag q0 = *(const s8frag*)&qr[quad * 8];
  s8frag q1 = *(const s8frag*)&qr[32 + quad * 8];

  float m_run[4], l_run[4];
  f4frag acc[4];
#pragma unroll
  for (int r = 0; r < 4; r++) { m_run[r] = -1e30f; l_run[r] = 0.f; }
#pragma unroll
  for (int dt = 0; dt < 4; dt++) acc[dt] = (f4frag){0.f, 0.f, 0.f, 0.f};

  const int js0 = 4 * c;
  const int jsE = min(4 * c + 4, it + 1);
  const size_t vtbase = (size_t)(g * DHEAD) * SEQ;

  for (int js = js0; js < jsE; js++) {
    const int j0 = js * 64;
    const int m0 = 1984 - i0 + j0;   // E row of band col 0
    __syncthreads();

    // K tile (2 x uint4 / thread)
#pragma unroll
    for (int e = 0; e < 2; e++) {
      int cc = e * 256 + tid;
      int jr = cc >> 3, doff = (cc & 7) * 8;
      *(uint4*)&Kb[jr][doff] =
          *(const uint4*)&K[((size_t)(b * SEQ + j0 + jr)) * DMODEL + h * DHEAD + doff];
    }
    // V^T tile from pre-transposed global (2 x uint4 / thread)
#pragma unroll
    for (int e = 0; e < 2; e++) {
      int cc = e * 256 + tid;
      int dr = cc >> 3, joff = (cc & 7) * 8;
      *(uint4*)&Vt[dr][joff] =
          *(const uint4*)&Vt_g[vtbase + (size_t)dr * SEQ + j0 + joff];
    }
    // E ring: first step fill 128 rows, then 64 new rows
    if (js == js0) {
#pragma unroll
      for (int e = 0; e < 4; e++) {
        int cc = e * 256 + tid;
        int er = cc >> 3, doff = (cc & 7) * 8;
        int m = m0 + er; int row = m > SEQ - 1 ? SEQ - 1 : m;
        *(uint4*)&Ebs[m & 127][doff] = *(const uint4*)&Eb16[(size_t)row * DHEAD + doff];
      }
    } else {
#pragma unroll
      for (int e = 0; e < 2; e++) {
        int cc = e * 256 + tid;
        int er = 64 + (cc >> 3), doff = (cc & 7) * 8;
        int m = m0 + er; int row = m > SEQ - 1 ? SEQ - 1 : m;
        *(uint4*)&Ebs[m & 127][doff] = *(const uint4*)&Eb16[(size_t)row * DHEAD + doff];
      }
    }
    if (tid < 64) {
      int j = j0 + tid;
      bool pad = (j >= NCOND) && (toks[b * S_TOK + j - NCOND] == 0);
      padv[tid] = pad ? -1e30f : 0.f;
    }
    __syncthreads();

    // QK^T (reads Kb)
    f4frag sc[4];
#pragma unroll
    for (int nt = 0; nt < 4; nt++) {
      s8frag k0 = *(const s8frag*)&Kb[nt * 16 + l16][quad * 8];
      s8frag k1 = *(const s8frag*)&Kb[nt * 16 + l16][32 + quad * 8];
      f4frag cc = (f4frag){0.f, 0.f, 0.f, 0.f};
      cc = __builtin_amdgcn_mfma_f32_16x16x32_bf16(q0, k0, cc, 0, 0, 0);
      cc = __builtin_amdgcn_mfma_f32_16x16x32_bf16(q1, k1, cc, 0, 0, 0);
      sc[nt] = cc;
    }

    // QE: 5 frags covering band cols [(3-wave)*16, (8-wave)*16)  (reads Ebs)
    f4frag qef[5];
#pragma unroll
    for (int f = 0; f < 5; f++) {
      int ct = f + 3 - wave;
      int m = m0 + ct * 16 + l16;
      const bf16u* erow = &Ebs[m & 127][0];
      s8frag e0 = *(const s8frag*)&erow[quad * 8];
      s8frag e1 = *(const s8frag*)&erow[32 + quad * 8];
      f4frag cc = (f4frag){0.f, 0.f, 0.f, 0.f};
      cc = __builtin_amdgcn_mfma_f32_16x16x32_bf16(q0, e0, cc, 0, 0, 0);
      cc = __builtin_amdgcn_mfma_f32_16x16x32_bf16(q1, e1, cc, 0, 0, 0);
      qef[f] = cc;
    }

    // All Kb/Ebs reads are drained by this barrier; Kb becomes the P buffer.
    __syncthreads();

    float pvv[4];
#pragma unroll
    for (int nt = 0; nt < 4; nt++) pvv[nt] = padv[nt * 16 + l16];

    // scores + online softmax; QE gathered by ONE shuffle (select at source).
    float s[4][4], mx[4];
#pragma unroll
    for (int r = 0; r < 4; r++) {
      int rloc = wave * 16 + quad * 4 + r;
      int ig = i0 + rloc;
      int t2 = quad * 4 + r;
      int v = 63 - 16 * wave + l16 - t2;
      int srcl = (lane & 48) | (v & 15);
      bool hiSrc = (l16 < 15 - t2);    // target hi <=> this at source lane
#pragma unroll
      for (int nt = 0; nt < 4; nt++) {
        float pre = hiSrc ? qef[nt + 1][r] : qef[nt][r];
        float qe = __shfl(pre, srcl);
        int jl = nt * 16 + l16;
        float sv = (sc[nt][r] + qe) * 0.125f + pvv[nt];
        if (j0 + jl > ig) sv = -1e30f;
        s[nt][r] = sv;
      }
      float m = fmaxf(fmaxf(s[0][r], s[1][r]), fmaxf(s[2][r], s[3][r]));
      float tr;
      DPP_ROR(tr, m, 1); m = fmaxf(m, tr);
      DPP_ROR(tr, m, 2); m = fmaxf(m, tr);
      DPP_ROR(tr, m, 4); m = fmaxf(m, tr);
      DPP_ROR(tr, m, 8); m = fmaxf(m, tr);
      mx[r] = m;
    }
    float alpha[4];
#pragma unroll
    for (int r = 0; r < 4; r++) {
      float m_new = fmaxf(m_run[r], mx[r]);
      alpha[r] = __expf(m_run[r] - m_new);
      float psum = 0.f;
      int rloc = wave * 16 + quad * 4 + r;
#pragma unroll
      for (int nt = 0; nt < 4; nt++) {
        float p = __expf(s[nt][r] - m_new);
        Ps[rloc][(nt * 16 + l16) ^ PS_SWZ(rloc)] = f2b(p);
        psum += p;
      }
      float tr;
      DPP_ROR(tr, psum, 1); psum += tr;
      DPP_ROR(tr, psum, 2); psum += tr;
      DPP_ROR(tr, psum, 4); psum += tr;
      DPP_ROR(tr, psum, 8); psum += tr;
      l_run[r] = l_run[r] * alpha[r] + psum;
      m_run[r] = m_new;
    }
#pragma unroll
    for (int dt = 0; dt < 4; dt++)
#pragma unroll
      for (int r = 0; r < 4; r++) acc[dt][r] *= alpha[r];

    // P @ V  (Ps rows are wave-local; swizzled reads match swizzled writes)
    {
      int prow = wave * 16 + l16;
      int psw = PS_SWZ(prow);
      s8frag p0 = *(const s8frag*)&Ps[prow][(quad * 8) ^ psw];
      s8frag p1 = *(const s8frag*)&Ps[prow][(32 + quad * 8) ^ psw];
#pragma unroll
      for (int dt = 0; dt < 4; dt++) {
        s8frag v0 = *(const s8frag*)&Vt[dt * 16 + l16][quad * 8];
        s8frag v1 = *(const s8frag*)&Vt[dt * 16 + l16][32 + quad * 8];
        acc[dt] = __builtin_amdgcn_mfma_f32_16x16x32_bf16(p0, v0, acc[dt], 0, 0, 0);
        acc[dt] = __builtin_amdgcn_mfma_f32_16x16x32_bf16(p1, v1, acc[dt], 0, 0, 0);
      }
    }
  }

  // write partials (packed slot)
#pragma unroll
  for (int r = 0; r < 4; r++) {
    int rloc = wave * 16 + quad * 4 + r;
    if (l16 == 0) {
      pstat[(size_t)slot * 128 + rloc]      = m_run[r];
      pstat[(size_t)slot * 128 + 64 + rloc] = l_run[r];
    }
#pragma unroll
    for (int dt = 0; dt < 4; dt++)
      pacc[(size_t)slot * 4096 + rloc * 64 + dt * 16 + l16] = f2b(acc[dt][r]);
  }
}

// ---------------------------------------------------------------------------
// Merge <=8 chunk partials per (b,h,q-tile); write O (bf16) into qb.
// ---------------------------------------------------------------------------
__global__ __launch_bounds__(256) void attn_combine(
    const bf16u* __restrict__ pacc, const float* __restrict__ pstat,
    bf16u* __restrict__ O)
{
  int bid = blockIdx.x;             // g*32 + it
  int g = bid >> 5, it = bid & 31;
  int b = g >> 3, h = g & 7;
  int i0 = it * 64;
  int nc = (it >> 2) + 1;           // chunks of 4 steps
  int base = g * NSLOT_G + slot_off(it);
  int tid = threadIdx.x;
  int row = tid >> 2, ql = tid & 3;

  float m_tot = -1e30f;
  float mc[8], lc[8];
#pragma unroll
  for (int c = 0; c < 8; c++) {
    if (c < nc) {
      size_t pb = (size_t)(base + c) * 128;
      mc[c] = pstat[pb + row];
      lc[c] = pstat[pb + 64 + row];
      m_tot = fmaxf(m_tot, mc[c]);
    }
  }
  float l_tot = 0.f, w[8];
#pragma unroll
  for (int c = 0; c < 8; c++) {
    if (c < nc) { w[c] = __expf(mc[c] - m_tot); l_tot += w[c] * lc[c]; }
    else w[c] = 0.f;
  }
  float inv = 1.0f / l_tot;

  float out[16];
#pragma unroll
  for (int k = 0; k < 16; k++) out[k] = 0.f;
#pragma unroll
  for (int c = 0; c < 8; c++) {
    if (c >= nc) break;
    const bf16u* pa = pacc + (size_t)(base + c) * 4096 + row * 64 + ql * 16;
#pragma unroll
    for (int k = 0; k < 16; k++) out[k] += w[c] * b2f(pa[k]);
  }
  bf16u* ob = O + ((size_t)(b * SEQ + i0 + row)) * DMODEL + h * DHEAD + ql * 16;
#pragma unroll
  for (int k = 0; k < 16; k++) ob[k] = f2b(out[k] * inv);
}

// ---------------------------------------------------------------------------
extern "C" void kernel_launch(void* const* d_in, const int* in_sizes, int n_in,
                              void* d_out, int out_size, void* d_ws, size_t ws_size,
                              hipStream_t stream) {
  const int*   toks  = (const int*)  d_in[0];
  const float* conds = (const float*)d_in[1];
  const float* ttc   = (const float*)d_in[2];
  const float* emb   = (const float*)d_in[3];
  const float* pos   = (const float*)d_in[4];
  const float* cW1   = (const float*)d_in[5];
  const float* cb1   = (const float*)d_in[6];
  const float* cW2   = (const float*)d_in[7];
  const float* cb2   = (const float*)d_in[8];
  const float* nullc = (const float*)d_in[9];
  const float* ttcW  = (const float*)d_in[10];
  const float* ttcb  = (const float*)d_in[11];
  const float* Wq    = (const float*)d_in[12];
  const float* Wk    = (const float*)d_in[13];
  const float* Wv    = (const float*)d_in[14];
  const float* Wo    = (const float*)d_in[15];
  const float* bq    = (const float*)d_in[16];
  const float* bk    = (const float*)d_in[17];
  const float* bv    = (const float*)d_in[18];
  const float* bo    = (const float*)d_in[19];
  const float* E     = (const float*)d_in[20];
  const float* fW1   = (const float*)d_in[21];
  const float* fb1   = (const float*)d_in[22];
  const float* fW2   = (const float*)d_in[23];
  const float* fb2   = (const float*)d_in[24];
  const float* ln1g  = (const float*)d_in[25];
  const float* ln1b  = (const float*)d_in[26];
  const float* ln2g  = (const float*)d_in[27];
  const float* ln2b  = (const float*)d_in[28];
  const float* fcW   = (const float*)d_in[29];
  const float* fcb   = (const float*)d_in[30];

  const size_t MB1 = 1024 * 1024;
  const size_t MD = (size_t)MROWS * DMODEL;
  char* p = (char*)d_ws;
  bf16u* xb    = (bf16u*)p; p += 4 * MB1;
  bf16u* qkvb  = (bf16u*)p; p += 12 * MB1;   // qb | kb | (pacc span)
  bf16u* hidb  = (bf16u*)p; p += 16 * MB1;   // FFN hidden
  float* pstat_old = (float*)p; p += 1 * MB1; // (unused; kept for layout)
  bf16u* vbt   = (bf16u*)p; p += 4 * MB1;    // V transposed (written by QKV)
  bf16u* ebf   = (bf16u*)p; p += 1536 * 1024;   // E bf16, 6 layers
  bf16u* WqkvT = (bf16u*)p; p += 9 * MB1;
  bf16u* WoT   = (bf16u*)p; p += 3 * MB1;
  bf16u* W1T   = (bf16u*)p; p += 12 * MB1;
  bf16u* W2T   = (bf16u*)p; p += 12 * MB1;
  bf16u* fcT   = (bf16u*)p; p += 512 * 1024;    // total 75 MB
  (void)pstat_old;
  bf16u* qb = qkvb;
  bf16u* kb = qkvb + MD;        // out1b aliases kb (disjoint lifetimes)
  bf16u* vb = qkvb + 2 * MD;    // now purely the partials span
  bf16u* out1b = kb;
  bf16u* t1b   = vb;
  // Partials live in the contiguous vb+hidb span (20MB): V goes straight to
  // vbt from the QKV GEMM, so vb is free; hidb's FFN lifetime starts after
  // attn_combine. pacc 18MB + pstat 1.15MB <= 20MB.
  bf16u* pacc  = vb;
  float* pstat = (float*)(pacc + (size_t)NSLOTS * 4096);

  // ---- setup: embeds + all-layer weight transposes + E conversion ----
  cond_embed_kernel<<<dim3(NCOND, BATCH), 256, 0, stream>>>(
      conds, cW1, cb1, cW2, cb2, nullc, pos, xb);
  tok_embed_kernel<<<dim3(S_TOK, BATCH), 256, 0, stream>>>(toks, emb, pos, xb);
  wt_all_kernel<<<6 * 768 + 64, 256, 0, stream>>>(Wq, Wk, Wv, Wo, fW1, fW2, fcW,
      WqkvT, WoT, W1T, W2T, fcT);
  e_conv_kernel<<<(NLAYER * SEQ * DHEAD) / 1024, 256, 0, stream>>>(E, ebf);

  dim3 gQKV(MROWS / 64, 1536 / 128);       // (64,12): 768 blocks, RB=2
  dim3 gFF1(MROWS / 64, DINNER / 128);     // (64,16): 1024 blocks, RB=2
  dim3 gN512(MROWS / 32, DMODEL / 128);    // (128,4): 512 blocks, RB=1

  for (int l = 0; l < NLAYER; l++) {
    // fused QKV; V written transposed to vbt in-epilogue (vt_kernel fused)
    mgemm<2><<<gQKV, 256, 0, stream>>>(xb, WqkvT + (size_t)l * 786432,
        bq + l * DMODEL, bk + l * DMODEL, bv + l * DMODEL, nullptr,
        (float*)vbt, qkvb, MROWS, 1536, DMODEL, 4, nullptr, nullptr, nullptr);

    attn_part<<<NSLOTS, 256, 0, stream>>>(qb, kb, vbt,
        ebf + (size_t)l * SEQ * DHEAD, toks, pacc, pstat);
    attn_combine<<<512, 256, 0, stream>>>(pacc, pstat, qb);

    // t1 = attn @ Wo + bo + x
    mgemm<1><<<gN512, 256, 0, stream>>>(qb, WoT + (size_t)l * 262144,
        bo + l * DMODEL, nullptr, nullptr, xb,
        nullptr, t1b, MROWS, DMODEL, DMODEL, 1, nullptr, nullptr, nullptr);
    ln_kernel<<<MROWS, 256, 0, stream>>>(t1b, ln1g + l * DMODEL, ln1b + l * DMODEL,
        out1b);

    // hid = relu(out1 @ W1 + b1) + chord
    mgemm<2><<<gFF1, 256, 0, stream>>>(out1b, W1T + (size_t)l * 1048576,
        fb1 + l * DINNER, nullptr, nullptr, nullptr,
        nullptr, hidb, MROWS, DINNER, DMODEL, 2, ttc, ttcW, ttcb);
    // t1 = hid @ W2 + b2 + out1
    mgemm<1><<<gN512, 256, 0, stream>>>(hidb, W2T + (size_t)l * 1048576,
        fb2 + l * DMODEL, nullptr, nullptr, out1b,
        nullptr, t1b, MROWS, DMODEL, DINNER, 1, nullptr, nullptr, nullptr);
    ln_kernel<<<MROWS, 256, 0, stream>>>(t1b, ln2g + l * DMODEL, ln2b + l * DMODEL,
        xb);
  }

  // logits = x @ fc_W + fc_b (fp32 out)
  mgemm<1><<<gN512, 256, 0, stream>>>(xb, fcT,
      fcb, nullptr, nullptr, nullptr,
      (float*)d_out, nullptr, MROWS, VOCAB, DMODEL, 3, nullptr, nullptr, nullptr);
}